// Round 1
// baseline (39668.674 us; speedup 1.0000x reference)
//
#include <hip/hip_runtime.h>
#include <math.h>

#define BSZ 16
#define NPTS 2048
#define NG 128
#define GS 32
#define NBRK 38

// ---------- helpers ----------
__device__ __forceinline__ unsigned fkey(float x) {
    unsigned u = __float_as_uint(x);
    return (u >> 31) ? ~u : (u | 0x80000000u);
}
__device__ __forceinline__ float fkey_inv(unsigned k) {
    unsigned u = (k >> 31) ? (k ^ 0x80000000u) : ~k;
    return __uint_as_float(u);
}

// ---------- FPS ----------
// one block per batch; reproduces jax scan: idxs[0]=0, then argmax(min_d) with
// first-index tie break (reduction picks max value, min index among equals).
__global__ void fps_kernel(const float* __restrict__ pts, float* __restrict__ center) {
    int b = blockIdx.x;
    __shared__ float mind[NPTS];
    __shared__ float rv[256];
    __shared__ int   ri[256];
    const float* P = pts + (size_t)b * NPTS * 3;
    for (int i = threadIdx.x; i < NPTS; i += 256) mind[i] = 1e10f;
    __syncthreads();
    int far = 0;
    for (int g = 0; g < NG; ++g) {
        float cx = P[far * 3 + 0], cy = P[far * 3 + 1], cz = P[far * 3 + 2];
        if (threadIdx.x == 0) {
            center[((size_t)b * NG + g) * 3 + 0] = cx;
            center[((size_t)b * NG + g) * 3 + 1] = cy;
            center[((size_t)b * NG + g) * 3 + 2] = cz;
        }
        float best = -1.0f; int bi = 0;
        for (int i = threadIdx.x; i < NPTS; i += 256) {
            float dx = P[i * 3 + 0] - cx;
            float dy = P[i * 3 + 1] - cy;
            float dz = P[i * 3 + 2] - cz;
            float d = dx * dx + dy * dy + dz * dz;
            float md = fminf(mind[i], d);
            mind[i] = md;
            if (md > best) { best = md; bi = i; }   // i ascending -> first max kept
        }
        rv[threadIdx.x] = best; ri[threadIdx.x] = bi;
        __syncthreads();
        for (int s = 128; s >= 1; s >>= 1) {
            if (threadIdx.x < s) {
                float v2 = rv[threadIdx.x + s]; int i2 = ri[threadIdx.x + s];
                if (v2 > rv[threadIdx.x] || (v2 == rv[threadIdx.x] && i2 < ri[threadIdx.x])) {
                    rv[threadIdx.x] = v2; ri[threadIdx.x] = i2;
                }
            }
            __syncthreads();
        }
        far = ri[0];
        __syncthreads();
    }
}

// ---------- KNN (brute force, insertion sorted top-k, ref formula aa+bb-2ab) ----------
__global__ void knn_kernel(const float* __restrict__ Q, int q_bstride, int q_off, int nq,
                           const float* __restrict__ DB, int db_bstride, int ndb,
                           int k, int* __restrict__ out, int nbatch) {
    int t = blockIdx.x * blockDim.x + threadIdx.x;
    if (t >= nbatch * nq) return;
    int b = t / nq, qi = t % nq;
    const float* q = Q + ((size_t)b * q_bstride + q_off + qi) * 3;
    float qx = q[0], qy = q[1], qz = q[2];
    float qq = qx * qx + qy * qy + qz * qz;
    const float* db = DB + (size_t)b * db_bstride * 3;
    float kd[NBRK]; int ki[NBRK];
    for (int i = 0; i < k; ++i) { kd[i] = 3e38f; ki[i] = 0; }
    for (int j = 0; j < ndb; ++j) {
        float bx = db[j * 3 + 0], by = db[j * 3 + 1], bz = db[j * 3 + 2];
        float bb = bx * bx + by * by + bz * bz;
        float d = qq + bb - 2.0f * (qx * bx + qy * by + qz * bz);
        if (d < kd[k - 1]) {
            int pos = k - 1;
            while (pos > 0 && kd[pos - 1] > d) {
                kd[pos] = kd[pos - 1]; ki[pos] = ki[pos - 1]; --pos;
            }
            kd[pos] = d; ki[pos] = j;
        }
    }
    int* o = out + (size_t)t * k;
    for (int i = 0; i < k; ++i) o[i] = ki[i];
}

// ---------- gather points via index array ----------
__global__ void gather_points_kernel(const float* __restrict__ pts, int db_bstride,
                                     const int* __restrict__ idx, int idx_bstride, int idx_off,
                                     int m, float* __restrict__ out, int nbatch) {
    int t = blockIdx.x * blockDim.x + threadIdx.x;
    if (t >= nbatch * m) return;
    int b = t / m, j = t % m;
    int s = idx[(size_t)b * idx_bstride + idx_off + j];
    const float* p = pts + ((size_t)b * db_bstride + s) * 3;
    out[(size_t)t * 3 + 0] = p[0];
    out[(size_t)t * 3 + 1] = p[1];
    out[(size_t)t * 3 + 2] = p[2];
}

// ---------- tiled GEMM: C[M,N] = A[M,K] @ W[N,K]^T + epilogue ----------
// epilogue options: bias per col, bias2d per (b,col), bn, relu, or max-reduce
// over rows into maxkey[b*N+col] (monotone-uint atomicMax).
__global__ void gemm_kernel(const float* __restrict__ A, int lda,
                            const float* __restrict__ W, int ldw, int woff,
                            const float* __restrict__ bias,
                            const float* __restrict__ bias2d,
                            const float* __restrict__ bng, const float* __restrict__ bnb,
                            const float* __restrict__ bnm, const float* __restrict__ bnv,
                            float* __restrict__ C, int ldc,
                            unsigned* __restrict__ maxkey,
                            int M, int N, int K, int rows_per_batch, int relu) {
    __shared__ float As[16][64];
    __shared__ float Ws[16][64];
    __shared__ float red[16][64];
    int bx = blockIdx.x, by = blockIdx.y;
    int tid = threadIdx.x;
    int tx = tid % 16, ty = tid / 16;
    int row0 = by * 64, col0 = bx * 64;
    float acc[4][4];
    for (int i = 0; i < 4; ++i) for (int j = 0; j < 4; ++j) acc[i][j] = 0.f;

    for (int k0 = 0; k0 < K; k0 += 16) {
        for (int i = 0; i < 4; ++i) {
            int idx = tid + i * 256;
            int m = idx / 16, kk = idx % 16;
            int gk = k0 + kk;
            As[kk][m] = (gk < K) ? A[(size_t)(row0 + m) * lda + gk] : 0.f;
        }
        for (int i = 0; i < 4; ++i) {
            int idx = tid + i * 256;
            int n = idx / 16, kk = idx % 16;
            int gk = k0 + kk;
            Ws[kk][n] = (gk < K) ? W[(size_t)(col0 + n) * ldw + woff + gk] : 0.f;
        }
        __syncthreads();
#pragma unroll
        for (int kk = 0; kk < 16; ++kk) {
            float a[4], w[4];
#pragma unroll
            for (int i = 0; i < 4; ++i) a[i] = As[kk][ty * 4 + i];
#pragma unroll
            for (int j = 0; j < 4; ++j) w[j] = Ws[kk][tx * 4 + j];
#pragma unroll
            for (int i = 0; i < 4; ++i)
#pragma unroll
                for (int j = 0; j < 4; ++j) acc[i][j] += a[i] * w[j];
        }
        __syncthreads();
    }

    int b = row0 / rows_per_batch;  // tile rows all in one batch (64 | rows_per_batch)
    if (maxkey) {
        for (int j = 0; j < 4; ++j) {
            int col = col0 + tx * 4 + j;
            float bv = bias ? bias[col] : 0.f;
            float m = acc[0][j] + bv;
            for (int i = 1; i < 4; ++i) m = fmaxf(m, acc[i][j] + bv);
            red[ty][tx * 4 + j] = m;
        }
        __syncthreads();
        if (tid < 64) {
            float m = red[0][tid];
            for (int y = 1; y < 16; ++y) m = fmaxf(m, red[y][tid]);
            atomicMax(&maxkey[(size_t)b * N + col0 + tid], fkey(m));
        }
    } else {
        for (int i = 0; i < 4; ++i) {
            int row = row0 + ty * 4 + i;
            for (int j = 0; j < 4; ++j) {
                int col = col0 + tx * 4 + j;
                float v = acc[i][j];
                if (bias)   v += bias[col];
                if (bias2d) v += bias2d[(size_t)b * N + col];
                if (bng)    v = (v - bnm[col]) * (1.0f / sqrtf(bnv[col] + 1e-5f)) * bng[col] + bnb[col];
                if (relu)   v = fmaxf(v, 0.f);
                C[(size_t)row * ldc + col] = v;
            }
        }
    }
}

// ---------- per-batch column max of H2 (B x n x 256) ----------
__global__ void colmax_kernel(const float* __restrict__ H, int n, float* __restrict__ out) {
    int b = blockIdx.x;
    int c = threadIdx.x;  // 256 channels
    const float* p = H + (size_t)b * n * 256 + c;
    float m = -3e38f;
    for (int i = 0; i < n; ++i) m = fmaxf(m, p[(size_t)i * 256]);
    out[b * 256 + c] = m;
}

// ---------- skinny GEMM: C[16,N] += A[16,K] @ W[N,K]^T (C pre-zeroed) ----------
__global__ void skinny16_kernel(const float* __restrict__ A, const float* __restrict__ W,
                                int ldw, int woff, float* __restrict__ C,
                                int K, int N, int nkchunks) {
    int col = blockIdx.x * 64 + (threadIdx.x & 63);
    int ks = threadIdx.x >> 6;  // 0..3
    int chunk = K / nkchunks;
    int sub = chunk >> 2;
    int k0 = blockIdx.y * chunk + ks * sub;
    const float* w = W + (size_t)col * ldw + woff;
    float acc[16];
#pragma unroll
    for (int m = 0; m < 16; ++m) acc[m] = 0.f;
    for (int k = k0; k < k0 + sub; ++k) {
        float wv = w[k];
#pragma unroll
        for (int m = 0; m < 16; ++m) acc[m] += A[(size_t)m * K + k] * wv;
    }
    for (int m = 0; m < 16; ++m) atomicAdd(&C[(size_t)m * N + col], acc[m]);
}

__global__ void bias_act_kernel(float* __restrict__ C, const float* __restrict__ bias,
                                int total, int N, int relu) {
    int t = blockIdx.x * blockDim.x + threadIdx.x;
    if (t >= total) return;
    int n = t % N;
    float v = C[t] + bias[n];
    if (relu) v = fmaxf(v, 0.f);
    C[t] = v;
}

__global__ void decode_kernel(const unsigned* __restrict__ k, float* __restrict__ f, int n) {
    int t = blockIdx.x * blockDim.x + threadIdx.x;
    if (t < n) f[t] = fkey_inv(k[t]);
}

// ---------- chamfer one direction: sum over A-points of sqrt(max(min_j d,1e-12)) ----------
__global__ void chamfer_min_kernel(const float* __restrict__ A, int na,
                                   const float* __restrict__ Bp, int nb,
                                   float* __restrict__ slot) {
    int t = blockIdx.x * blockDim.x + threadIdx.x;
    float val = 0.f;
    if (t < BSZ * na) {
        int b = t / na;
        const float* a = A + (size_t)t * 3;
        float ax = a[0], ay = a[1], az = a[2];
        float aa = ax * ax + ay * ay + az * az;
        const float* Bb = Bp + (size_t)b * nb * 3;
        float m = 3e38f;
        for (int j = 0; j < nb; ++j) {
            float bx = Bb[j * 3 + 0], by = Bb[j * 3 + 1], bz = Bb[j * 3 + 2];
            float d = aa + bx * bx + by * by + bz * bz - 2.0f * (ax * bx + ay * by + az * bz);
            m = fminf(m, d);
        }
        val = sqrtf(fmaxf(m, 1e-12f));
    }
    __shared__ float sdata[256];
    sdata[threadIdx.x] = val;
    __syncthreads();
    for (int s = 128; s > 0; s >>= 1) {
        if (threadIdx.x < s) sdata[threadIdx.x] += sdata[threadIdx.x + s];
        __syncthreads();
    }
    if (threadIdx.x == 0) atomicAdd(slot, sdata[0]);
}

// ---------- smooth-L1 latent loss sum ----------
__global__ void latent_kernel(const float* __restrict__ f1, const float* __restrict__ f2,
                              int n, float* __restrict__ slot) {
    int t = blockIdx.x * blockDim.x + threadIdx.x;
    float val = 0.f;
    if (t < n) {
        float d = f1[t] - f2[t];
        float ad = fabsf(d);
        val = (ad < 1.f) ? (0.5f * d * d) : (ad - 0.5f);
    }
    __shared__ float sdata[256];
    sdata[threadIdx.x] = val;
    __syncthreads();
    for (int s = 128; s > 0; s >>= 1) {
        if (threadIdx.x < s) sdata[threadIdx.x] += sdata[threadIdx.x + s];
        __syncthreads();
    }
    if (threadIdx.x == 0) atomicAdd(slot, sdata[0]);
}

// ---------- 3x3 symmetric smallest eigenvector (double, analytic) ----------
__device__ void smallest_evec(double cxx, double cxy, double cxz,
                              double cyy, double cyz, double czz, double ev[3]) {
    double p1 = cxy * cxy + cxz * cxz + cyz * cyz;
    double q = (cxx + cyy + czz) / 3.0;
    double p2 = (cxx - q) * (cxx - q) + (cyy - q) * (cyy - q) + (czz - q) * (czz - q) + 2.0 * p1;
    double lam = q;
    if (p2 > 0.0) {
        double p = sqrt(p2 / 6.0);
        double b00 = (cxx - q) / p, b11 = (cyy - q) / p, b22 = (czz - q) / p;
        double b01 = cxy / p, b02 = cxz / p, b12 = cyz / p;
        double detB = b00 * (b11 * b22 - b12 * b12) - b01 * (b01 * b22 - b12 * b02)
                    + b02 * (b01 * b12 - b11 * b02);
        double r = detB * 0.5;
        r = r < -1.0 ? -1.0 : (r > 1.0 ? 1.0 : r);
        double phi = acos(r) / 3.0;
        lam = q + 2.0 * p * cos(phi + 2.0943951023931953);  // smallest
    }
    double r0x = cxx - lam, r0y = cxy, r0z = cxz;
    double r1x = cxy, r1y = cyy - lam, r1z = cyz;
    double r2x = cxz, r2y = cyz, r2z = czz - lam;
    double c0x = r0y * r1z - r0z * r1y, c0y = r0z * r1x - r0x * r1z, c0z = r0x * r1y - r0y * r1x;
    double c1x = r0y * r2z - r0z * r2y, c1y = r0z * r2x - r0x * r2z, c1z = r0x * r2y - r0y * r2x;
    double c2x = r1y * r2z - r1z * r2y, c2y = r1z * r2x - r1x * r2z, c2z = r1x * r2y - r1y * r2x;
    double n0 = c0x * c0x + c0y * c0y + c0z * c0z;
    double n1 = c1x * c1x + c1y * c1y + c1z * c1z;
    double n2 = c2x * c2x + c2y * c2y + c2z * c2z;
    double bx = c0x, by = c0y, bz = c0z, bn = n0;
    if (n1 > bn) { bx = c1x; by = c1y; bz = c1z; bn = n1; }
    if (n2 > bn) { bx = c2x; by = c2y; bz = c2z; bn = n2; }
    if (bn < 1e-280) { ev[0] = 1.0; ev[1] = 0.0; ev[2] = 0.0; return; }
    double inv = 1.0 / sqrt(bn);
    ev[0] = bx * inv; ev[1] = by * inv; ev[2] = bz * inv;
}

// ---------- normals: covariance of 32-NN, smallest eigenvector, sign via proj ----------
__global__ void normals_kernel(const float* __restrict__ pred, const int* __restrict__ knn,
                               float* __restrict__ nrm) {
    int t = blockIdx.x * blockDim.x + threadIdx.x;
    if (t >= BSZ * NPTS) return;
    int b = t / NPTS, i = t % NPTS;
    const float* P = pred + (size_t)b * NPTS * 3;
    const int* id = knn + (size_t)t * 32;
    float px[32], py[32], pz[32];
    double sx = 0, sy = 0, sz = 0;
    for (int k = 0; k < 32; ++k) {
        int j = id[k];
        px[k] = P[j * 3 + 0]; py[k] = P[j * 3 + 1]; pz[k] = P[j * 3 + 2];
        sx += px[k]; sy += py[k]; sz += pz[k];
    }
    double mx = sx / 32.0, my = sy / 32.0, mz = sz / 32.0;
    double cxx = 0, cxy = 0, cxz = 0, cyy = 0, cyz = 0, czz = 0;
    for (int k = 0; k < 32; ++k) {
        double dx = px[k] - mx, dy = py[k] - my, dz = pz[k] - mz;
        cxx += dx * dx; cxy += dx * dy; cxz += dx * dz;
        cyy += dy * dy; cyz += dy * dz; czz += dz * dz;
    }
    cxx /= 32.0; cxy /= 32.0; cxz /= 32.0; cyy /= 32.0; cyz /= 32.0; czz /= 32.0;
    double ev[3];
    smallest_evec(cxx, cxy, cxz, cyy, cyz, czz, ev);
    float qx = P[i * 3 + 0], qy = P[i * 3 + 1], qz = P[i * 3 + 2];
    double proj = 0.0;
    for (int k = 0; k < 32; ++k)
        proj += (px[k] - qx) * ev[0] + (py[k] - qy) * ev[1] + (pz[k] - qz) * ev[2];
    double s = (proj >= 0.0) ? 1.0 : -1.0;
    nrm[(size_t)t * 3 + 0] = (float)(ev[0] * s);
    nrm[(size_t)t * 3 + 1] = (float)(ev[1] * s);
    nrm[(size_t)t * 3 + 2] = (float)(ev[2] * s);
}

// ---------- manifold loss: std(1-cos, ddof=1) over 8-NN normals ----------
__global__ void manifold_kernel(const float* __restrict__ nrm, const int* __restrict__ knn,
                                float* __restrict__ slot) {
    int t = blockIdx.x * blockDim.x + threadIdx.x;
    float val = 0.f;
    if (t < BSZ * NPTS) {
        int b = t / NPTS;
        const float* NB = nrm + (size_t)b * NPTS * 3;
        const int* id = knn + (size_t)t * 8;
        int j0 = id[0];
        float ax = NB[j0 * 3 + 0], ay = NB[j0 * 3 + 1], az = NB[j0 * 3 + 2];
        float an = fmaxf(sqrtf(ax * ax + ay * ay + az * az), 1e-6f);
        float x[8]; float s = 0.f;
        for (int k = 0; k < 8; ++k) {
            int j = id[k];
            float bx = NB[j * 3 + 0], by = NB[j * 3 + 1], bz = NB[j * 3 + 2];
            float bn_ = fmaxf(sqrtf(bx * bx + by * by + bz * bz), 1e-6f);
            float c = (ax * bx + ay * by + az * bz) / (an * bn_);
            x[k] = 1.f - c; s += x[k];
        }
        float mean = s / 8.f;
        float var = 0.f;
        for (int k = 0; k < 8; ++k) { float d = x[k] - mean; var += d * d; }
        val = sqrtf(var / 7.f);
    }
    __shared__ float sdata[256];
    sdata[threadIdx.x] = val;
    __syncthreads();
    for (int s2 = 128; s2 > 0; s2 >>= 1) {
        if (threadIdx.x < s2) sdata[threadIdx.x] += sdata[threadIdx.x + s2];
        __syncthreads();
    }
    if (threadIdx.x == 0) atomicAdd(slot, sdata[0]);
}

__global__ void finalize_kernel(const float* __restrict__ acc, float* __restrict__ out) {
    float l_recon = 0.5f * (acc[0] / (16.f * 2048.f) + acc[1] / (16.f * 2432.f));
    float l_match = 0.5f * (acc[2] / (16.f * 1024.f) + acc[3] / (16.f * 1216.f));
    float l_latent = acc[4] / (16.f * 1024.f);
    float l_man = 0.1f * (acc[5] / (16.f * 2048.f));
    out[0] = l_recon + l_match + l_latent + l_man;
    out[1] = l_recon;
    out[2] = l_match;
    out[3] = l_latent;
    out[4] = l_man;
}

// ================= host =================
extern "C" void kernel_launch(void* const* d_in, const int* in_sizes, int n_in,
                              void* d_out, int out_size, void* d_ws, size_t ws_size,
                              hipStream_t stream) {
    (void)in_sizes; (void)n_in; (void)out_size; (void)ws_size;
    const float* pts = (const float*)d_in[0];
    const float* W1 = (const float*)d_in[1];
    const float* b1 = (const float*)d_in[2];
    const float* g1 = (const float*)d_in[3];
    const float* be1 = (const float*)d_in[4];
    const float* m1 = (const float*)d_in[5];
    const float* v1 = (const float*)d_in[6];
    const float* W2 = (const float*)d_in[7];
    const float* b2 = (const float*)d_in[8];
    const float* W3 = (const float*)d_in[9];
    const float* b3 = (const float*)d_in[10];
    const float* g2 = (const float*)d_in[11];
    const float* be2 = (const float*)d_in[12];
    const float* m2 = (const float*)d_in[13];
    const float* v2 = (const float*)d_in[14];
    const float* W4 = (const float*)d_in[15];
    const float* b4 = (const float*)d_in[16];
    const float* D1W = (const float*)d_in[17];
    const float* D1b = (const float*)d_in[18];
    const float* D2W = (const float*)d_in[19];
    const float* D2b = (const float*)d_in[20];
    const float* D3W = (const float*)d_in[21];
    const float* D3b = (const float*)d_in[22];
    const float* D4W = (const float*)d_in[23];
    const float* D4b = (const float*)d_in[24];

    char* ws = (char*)d_ws;
    size_t off = 0;
    auto alloc = [&](size_t bytes) -> void* {
        void* p = ws + off;
        off += (bytes + 255) & ~(size_t)255;
        return p;
    };
    float* center   = (float*)alloc((size_t)BSZ * NG * 3 * 4);
    int*   knnc     = (int*)  alloc((size_t)BSZ * NG * GS * 4);
    float* rebuild0 = (float*)alloc((size_t)BSZ * 2048 * 3 * 4);
    float* rebuild1 = (float*)alloc((size_t)BSZ * 1024 * 3 * 4);
    float* H1       = (float*)alloc((size_t)BSZ * 2048 * 128 * 4);
    float* H2       = (float*)alloc((size_t)BSZ * 2048 * 256 * 4);
    float* H3       = (float*)alloc((size_t)BSZ * 2048 * 512 * 4);
    float* gmaxb    = (float*)alloc((size_t)BSZ * 256 * 4);
    float* gpart    = (float*)alloc((size_t)BSZ * 512 * 4);
    unsigned* featkey = (unsigned*)alloc((size_t)BSZ * 1024 * 4);
    float* feat     = (float*)alloc((size_t)BSZ * 1024 * 4);
    float* featrec  = (float*)alloc((size_t)BSZ * 1024 * 4);
    float* dh1      = (float*)alloc((size_t)BSZ * 2048 * 4);
    float* dh2      = (float*)alloc((size_t)BSZ * 2048 * 4);
    float* dh3      = (float*)alloc((size_t)BSZ * 2048 * 4);
    float* pred     = (float*)alloc((size_t)BSZ * 6144 * 4);
    int*   idxa     = (int*)  alloc((size_t)BSZ * 64 * NBRK * 4);
    float* gatha    = (float*)alloc((size_t)BSZ * 64 * NBRK * 3 * 4);
    int*   idxb     = (int*)  alloc((size_t)BSZ * 32 * NBRK * 4);
    float* gathb    = (float*)alloc((size_t)BSZ * 32 * NBRK * 3 * 4);
    int*   idxc     = (int*)  alloc((size_t)BSZ * 32 * 32 * 4);
    float* gathc    = (float*)alloc((size_t)BSZ * 1024 * 3 * 4);
    int*   knn32    = (int*)  alloc((size_t)BSZ * 2048 * 32 * 4);
    int*   knn8     = (int*)  alloc((size_t)BSZ * 2048 * 8 * 4);
    float* nrmbuf   = (float*)alloc((size_t)BSZ * 2048 * 3 * 4);
    float* accum    = (float*)alloc(8 * 4);

    hipMemsetAsync(accum, 0, 8 * 4, stream);

    // FPS + grouping
    fps_kernel<<<BSZ, 256, 0, stream>>>(pts, center);
    knn_kernel<<<(BSZ * NG + 255) / 256, 256, 0, stream>>>(center, NG, 0, NG, pts, NPTS, NPTS,
                                                           GS, knnc, BSZ);
    gather_points_kernel<<<(BSZ * 2048 + 255) / 256, 256, 0, stream>>>(pts, NPTS, knnc, NG * GS,
                                                                       0, 2048, rebuild0, BSZ);
    gather_points_kernel<<<(BSZ * 1024 + 255) / 256, 256, 0, stream>>>(pts, NPTS, knnc, NG * GS,
                                                                       2048, 1024, rebuild1, BSZ);

    auto enc = [&](const float* X, int n, float* featout) {
        int M = BSZ * n;
        gemm_kernel<<<dim3(128 / 64, M / 64), 256, 0, stream>>>(
            X, 3, W1, 3, 0, b1, nullptr, g1, be1, m1, v1, H1, 128, nullptr, M, 128, 3, n, 1);
        gemm_kernel<<<dim3(256 / 64, M / 64), 256, 0, stream>>>(
            H1, 128, W2, 128, 0, b2, nullptr, nullptr, nullptr, nullptr, nullptr,
            H2, 256, nullptr, M, 256, 128, n, 0);
        colmax_kernel<<<BSZ, 256, 0, stream>>>(H2, n, gmaxb);
        hipMemsetAsync(gpart, 0, (size_t)BSZ * 512 * 4, stream);
        skinny16_kernel<<<dim3(8, 1), 256, 0, stream>>>(gmaxb, W3, 512, 0, gpart, 256, 512, 1);
        bias_act_kernel<<<(BSZ * 512 + 255) / 256, 256, 0, stream>>>(gpart, b3, BSZ * 512, 512, 0);
        gemm_kernel<<<dim3(512 / 64, M / 64), 256, 0, stream>>>(
            H2, 256, W3, 512, 256, nullptr, gpart, g2, be2, m2, v2, H3, 512, nullptr,
            M, 512, 256, n, 1);
        hipMemsetAsync(featkey, 0, (size_t)BSZ * 1024 * 4, stream);
        gemm_kernel<<<dim3(1024 / 64, M / 64), 256, 0, stream>>>(
            H3, 512, W4, 512, 0, b4, nullptr, nullptr, nullptr, nullptr, nullptr,
            nullptr, 0, featkey, M, 1024, 512, n, 0);
        decode_kernel<<<(BSZ * 1024 + 255) / 256, 256, 0, stream>>>(featkey, featout, BSZ * 1024);
    };

    enc(rebuild0, 2048, feat);

    // decoder (skinny M=16)
    auto dec_layer = [&](const float* A, int K, const float* Wd, const float* bd,
                         float* Cbuf, int N, int relu) {
        hipMemsetAsync(Cbuf, 0, (size_t)BSZ * N * 4, stream);
        int nk = (K >= 1024) ? 4 : 1;
        skinny16_kernel<<<dim3(N / 64, nk), 256, 0, stream>>>(A, Wd, K, 0, Cbuf, K, N, nk);
        bias_act_kernel<<<(BSZ * N + 255) / 256, 256, 0, stream>>>(Cbuf, bd, BSZ * N, N, relu);
    };
    dec_layer(feat, 1024, D1W, D1b, dh1, 2048, 1);
    dec_layer(dh1, 2048, D2W, D2b, dh2, 2048, 1);
    dec_layer(dh2, 2048, D3W, D3b, dh3, 2048, 1);
    dec_layer(dh3, 2048, D4W, D4b, pred, 6144, 0);  // pred = (B,2048,3)

    // l_recon: group0 centers -> 38-NN in pred
    knn_kernel<<<(BSZ * 64 + 255) / 256, 256, 0, stream>>>(center, NG, 0, 64, pred, 2048, 2048,
                                                           NBRK, idxa, BSZ);
    gather_points_kernel<<<(BSZ * 2432 + 255) / 256, 256, 0, stream>>>(pred, 2048, idxa, 64 * NBRK,
                                                                       0, 2432, gatha, BSZ);
    chamfer_min_kernel<<<(BSZ * 2048 + 255) / 256, 256, 0, stream>>>(rebuild0, 2048, gatha, 2432,
                                                                     accum + 0);
    chamfer_min_kernel<<<(BSZ * 2432 + 255) / 256, 256, 0, stream>>>(gatha, 2432, rebuild0, 2048,
                                                                     accum + 1);
    // l_match: group1
    knn_kernel<<<(BSZ * 32 + 255) / 256, 256, 0, stream>>>(center, NG, 64, 32, pred, 2048, 2048,
                                                           NBRK, idxb, BSZ);
    gather_points_kernel<<<(BSZ * 1216 + 255) / 256, 256, 0, stream>>>(pred, 2048, idxb, 32 * NBRK,
                                                                       0, 1216, gathb, BSZ);
    chamfer_min_kernel<<<(BSZ * 1024 + 255) / 256, 256, 0, stream>>>(rebuild1, 1024, gathb, 1216,
                                                                     accum + 2);
    chamfer_min_kernel<<<(BSZ * 1216 + 255) / 256, 256, 0, stream>>>(gathb, 1216, rebuild1, 1024,
                                                                     accum + 3);
    // l_latent: group2 -> encoder on gathered pred points
    knn_kernel<<<(BSZ * 32 + 255) / 256, 256, 0, stream>>>(center, NG, 96, 32, pred, 2048, 2048,
                                                           32, idxc, BSZ);
    gather_points_kernel<<<(BSZ * 1024 + 255) / 256, 256, 0, stream>>>(pred, 2048, idxc, 32 * 32,
                                                                       0, 1024, gathc, BSZ);
    enc(gathc, 1024, featrec);
    latent_kernel<<<(BSZ * 1024 + 255) / 256, 256, 0, stream>>>(feat, featrec, BSZ * 1024,
                                                                accum + 4);
    // l_man: normals + 8-NN cos std
    knn_kernel<<<(BSZ * 2048 + 255) / 256, 256, 0, stream>>>(pred, 2048, 0, 2048, pred, 2048, 2048,
                                                             32, knn32, BSZ);
    normals_kernel<<<(BSZ * 2048 + 255) / 256, 256, 0, stream>>>(pred, knn32, nrmbuf);
    knn_kernel<<<(BSZ * 2048 + 255) / 256, 256, 0, stream>>>(pred, 2048, 0, 2048, pred, 2048, 2048,
                                                             8, knn8, BSZ);
    manifold_kernel<<<(BSZ * 2048 + 255) / 256, 256, 0, stream>>>(nrmbuf, knn8, accum + 5);

    finalize_kernel<<<1, 1, 0, stream>>>(accum, (float*)d_out);
}

// Round 2
// 4473.795 us; speedup vs baseline: 8.8669x; 8.8669x over previous
//
#include <hip/hip_runtime.h>
#include <math.h>

#define BSZ 16
#define NPTS 2048
#define NG 128
#define GS 32
#define NBRK 38

// ---------- helpers ----------
__device__ __forceinline__ unsigned fkey(float x) {
    unsigned u = __float_as_uint(x);
    return (u >> 31) ? ~u : (u | 0x80000000u);
}
__device__ __forceinline__ float fkey_inv(unsigned k) {
    unsigned u = (k >> 31) ? (k ^ 0x80000000u) : ~k;
    return __uint_as_float(u);
}

// ---------- FPS ----------
__global__ void fps_kernel(const float* __restrict__ pts, float* __restrict__ center) {
    int b = blockIdx.x;
    __shared__ float mind[NPTS];
    __shared__ float rv[256];
    __shared__ int   ri[256];
    const float* P = pts + (size_t)b * NPTS * 3;
    for (int i = threadIdx.x; i < NPTS; i += 256) mind[i] = 1e10f;
    __syncthreads();
    int far = 0;
    for (int g = 0; g < NG; ++g) {
        float cx = P[far * 3 + 0], cy = P[far * 3 + 1], cz = P[far * 3 + 2];
        if (threadIdx.x == 0) {
            center[((size_t)b * NG + g) * 3 + 0] = cx;
            center[((size_t)b * NG + g) * 3 + 1] = cy;
            center[((size_t)b * NG + g) * 3 + 2] = cz;
        }
        float best = -1.0f; int bi = 0;
        for (int i = threadIdx.x; i < NPTS; i += 256) {
            float dx = P[i * 3 + 0] - cx;
            float dy = P[i * 3 + 1] - cy;
            float dz = P[i * 3 + 2] - cz;
            float d = dx * dx + dy * dy + dz * dz;
            float md = fminf(mind[i], d);
            mind[i] = md;
            if (md > best) { best = md; bi = i; }   // i ascending -> first max kept
        }
        rv[threadIdx.x] = best; ri[threadIdx.x] = bi;
        __syncthreads();
        for (int s = 128; s >= 1; s >>= 1) {
            if (threadIdx.x < s) {
                float v2 = rv[threadIdx.x + s]; int i2 = ri[threadIdx.x + s];
                if (v2 > rv[threadIdx.x] || (v2 == rv[threadIdx.x] && i2 < ri[threadIdx.x])) {
                    rv[threadIdx.x] = v2; ri[threadIdx.x] = i2;
                }
            }
            __syncthreads();
        }
        far = ri[0];
        __syncthreads();
    }
}

// ---------- KNN v2: one wave per query, LDS distance row, k-round argmin ----------
// Semantics match stable top_k: min distance wins; equal distances -> lower index.
__global__ void knn_wave_kernel(const float* __restrict__ Q, int q_bstride, int q_off, int nq,
                                const float* __restrict__ DB, int db_bstride, int ndb,
                                int k, int* __restrict__ out, int nbatch) {
    __shared__ float dist[4][NPTS];
    int wave = threadIdx.x >> 6;
    int lane = threadIdx.x & 63;
    int qidx = blockIdx.x * 4 + wave;
    bool active = qidx < nbatch * nq;
    float* D = dist[wave];
    int b = 0, qi = 0;
    if (active) { b = qidx / nq; qi = qidx % nq; }
    if (active) {
        const float* q = Q + ((size_t)b * q_bstride + q_off + qi) * 3;
        float qx = q[0], qy = q[1], qz = q[2];
        float qq = qx * qx + qy * qy + qz * qz;
        const float* db = DB + (size_t)b * db_bstride * 3;
        for (int j = lane; j < ndb; j += 64) {
            float bx = db[j * 3 + 0], by = db[j * 3 + 1], bz = db[j * 3 + 2];
            float bb = bx * bx + by * by + bz * bz;
            D[j] = qq + bb - 2.0f * (qx * bx + qy * by + qz * bz);
        }
    }
    __syncthreads();
    int* o = out + (size_t)qidx * k;
    for (int r = 0; r < k; ++r) {
        if (active) {
            float best = 3e38f; int bi = ndb;
            for (int j = lane; j < ndb; j += 64) {
                float v = D[j];
                if (v < best) { best = v; bi = j; }  // ascending j: first min kept
            }
            for (int s = 32; s >= 1; s >>= 1) {
                float ov = __shfl_xor(best, s, 64);
                int   oi = __shfl_xor(bi, s, 64);
                if (ov < best || (ov == best && oi < bi)) { best = ov; bi = oi; }
            }
            if (lane == 0) {
                o[r] = bi;
                D[bi] = 3e38f;
            }
        }
        __syncthreads();
    }
}

// ---------- gather points via index array ----------
__global__ void gather_points_kernel(const float* __restrict__ pts, int db_bstride,
                                     const int* __restrict__ idx, int idx_bstride, int idx_off,
                                     int m, float* __restrict__ out, int nbatch) {
    int t = blockIdx.x * blockDim.x + threadIdx.x;
    if (t >= nbatch * m) return;
    int b = t / m, j = t % m;
    int s = idx[(size_t)b * idx_bstride + idx_off + j];
    const float* p = pts + ((size_t)b * db_bstride + s) * 3;
    out[(size_t)t * 3 + 0] = p[0];
    out[(size_t)t * 3 + 1] = p[1];
    out[(size_t)t * 3 + 2] = p[2];
}

// ---------- tiled GEMM: C[M,N] = A[M,K] @ W[N,K]^T + epilogue ----------
__global__ void gemm_kernel(const float* __restrict__ A, int lda,
                            const float* __restrict__ W, int ldw, int woff,
                            const float* __restrict__ bias,
                            const float* __restrict__ bias2d,
                            const float* __restrict__ bng, const float* __restrict__ bnb,
                            const float* __restrict__ bnm, const float* __restrict__ bnv,
                            float* __restrict__ C, int ldc,
                            unsigned* __restrict__ maxkey,
                            int M, int N, int K, int rows_per_batch, int relu) {
    __shared__ float As[16][64];
    __shared__ float Ws[16][64];
    __shared__ float red[16][64];
    int bx = blockIdx.x, by = blockIdx.y;
    int tid = threadIdx.x;
    int tx = tid % 16, ty = tid / 16;
    int row0 = by * 64, col0 = bx * 64;
    float acc[4][4];
    for (int i = 0; i < 4; ++i) for (int j = 0; j < 4; ++j) acc[i][j] = 0.f;

    for (int k0 = 0; k0 < K; k0 += 16) {
        for (int i = 0; i < 4; ++i) {
            int idx = tid + i * 256;
            int m = idx / 16, kk = idx % 16;
            int gk = k0 + kk;
            As[kk][m] = (gk < K) ? A[(size_t)(row0 + m) * lda + gk] : 0.f;
        }
        for (int i = 0; i < 4; ++i) {
            int idx = tid + i * 256;
            int n = idx / 16, kk = idx % 16;
            int gk = k0 + kk;
            Ws[kk][n] = (gk < K) ? W[(size_t)(col0 + n) * ldw + woff + gk] : 0.f;
        }
        __syncthreads();
#pragma unroll
        for (int kk = 0; kk < 16; ++kk) {
            float a[4], w[4];
#pragma unroll
            for (int i = 0; i < 4; ++i) a[i] = As[kk][ty * 4 + i];
#pragma unroll
            for (int j = 0; j < 4; ++j) w[j] = Ws[kk][tx * 4 + j];
#pragma unroll
            for (int i = 0; i < 4; ++i)
#pragma unroll
                for (int j = 0; j < 4; ++j) acc[i][j] += a[i] * w[j];
        }
        __syncthreads();
    }

    int b = row0 / rows_per_batch;
    if (maxkey) {
        for (int j = 0; j < 4; ++j) {
            int col = col0 + tx * 4 + j;
            float bv = bias ? bias[col] : 0.f;
            float m = acc[0][j] + bv;
            for (int i = 1; i < 4; ++i) m = fmaxf(m, acc[i][j] + bv);
            red[ty][tx * 4 + j] = m;
        }
        __syncthreads();
        if (tid < 64) {
            float m = red[0][tid];
            for (int y = 1; y < 16; ++y) m = fmaxf(m, red[y][tid]);
            atomicMax(&maxkey[(size_t)b * N + col0 + tid], fkey(m));
        }
    } else {
        for (int i = 0; i < 4; ++i) {
            int row = row0 + ty * 4 + i;
            for (int j = 0; j < 4; ++j) {
                int col = col0 + tx * 4 + j;
                float v = acc[i][j];
                if (bias)   v += bias[col];
                if (bias2d) v += bias2d[(size_t)b * N + col];
                if (bng)    v = (v - bnm[col]) * (1.0f / sqrtf(bnv[col] + 1e-5f)) * bng[col] + bnb[col];
                if (relu)   v = fmaxf(v, 0.f);
                C[(size_t)row * ldc + col] = v;
            }
        }
    }
}

// ---------- per-batch column max of H2 (B x n x 256) ----------
__global__ void colmax_kernel(const float* __restrict__ H, int n, float* __restrict__ out) {
    int b = blockIdx.x;
    int c = threadIdx.x;
    const float* p = H + (size_t)b * n * 256 + c;
    float m = -3e38f;
    for (int i = 0; i < n; ++i) m = fmaxf(m, p[(size_t)i * 256]);
    out[b * 256 + c] = m;
}

// ---------- skinny GEMM: C[16,N] += A[16,K] @ W[N,K]^T (C pre-zeroed) ----------
__global__ void skinny16_kernel(const float* __restrict__ A, const float* __restrict__ W,
                                int ldw, int woff, float* __restrict__ C,
                                int K, int N, int nkchunks) {
    int col = blockIdx.x * 64 + (threadIdx.x & 63);
    int ks = threadIdx.x >> 6;
    int chunk = K / nkchunks;
    int sub = chunk >> 2;
    int k0 = blockIdx.y * chunk + ks * sub;
    const float* w = W + (size_t)col * ldw + woff;
    float acc[16];
#pragma unroll
    for (int m = 0; m < 16; ++m) acc[m] = 0.f;
    for (int k = k0; k < k0 + sub; ++k) {
        float wv = w[k];
#pragma unroll
        for (int m = 0; m < 16; ++m) acc[m] += A[(size_t)m * K + k] * wv;
    }
    for (int m = 0; m < 16; ++m) atomicAdd(&C[(size_t)m * N + col], acc[m]);
}

__global__ void bias_act_kernel(float* __restrict__ C, const float* __restrict__ bias,
                                int total, int N, int relu) {
    int t = blockIdx.x * blockDim.x + threadIdx.x;
    if (t >= total) return;
    int n = t % N;
    float v = C[t] + bias[n];
    if (relu) v = fmaxf(v, 0.f);
    C[t] = v;
}

__global__ void decode_kernel(const unsigned* __restrict__ k, float* __restrict__ f, int n) {
    int t = blockIdx.x * blockDim.x + threadIdx.x;
    if (t < n) f[t] = fkey_inv(k[t]);
}

// ---------- chamfer one direction ----------
__global__ void chamfer_min_kernel(const float* __restrict__ A, int na,
                                   const float* __restrict__ Bp, int nb,
                                   float* __restrict__ slot) {
    int t = blockIdx.x * blockDim.x + threadIdx.x;
    float val = 0.f;
    if (t < BSZ * na) {
        int b = t / na;
        const float* a = A + (size_t)t * 3;
        float ax = a[0], ay = a[1], az = a[2];
        float aa = ax * ax + ay * ay + az * az;
        const float* Bb = Bp + (size_t)b * nb * 3;
        float m = 3e38f;
        for (int j = 0; j < nb; ++j) {
            float bx = Bb[j * 3 + 0], by = Bb[j * 3 + 1], bz = Bb[j * 3 + 2];
            float d = aa + bx * bx + by * by + bz * bz - 2.0f * (ax * bx + ay * by + az * bz);
            m = fminf(m, d);
        }
        val = sqrtf(fmaxf(m, 1e-12f));
    }
    __shared__ float sdata[256];
    sdata[threadIdx.x] = val;
    __syncthreads();
    for (int s = 128; s > 0; s >>= 1) {
        if (threadIdx.x < s) sdata[threadIdx.x] += sdata[threadIdx.x + s];
        __syncthreads();
    }
    if (threadIdx.x == 0) atomicAdd(slot, sdata[0]);
}

// ---------- smooth-L1 latent loss sum ----------
__global__ void latent_kernel(const float* __restrict__ f1, const float* __restrict__ f2,
                              int n, float* __restrict__ slot) {
    int t = blockIdx.x * blockDim.x + threadIdx.x;
    float val = 0.f;
    if (t < n) {
        float d = f1[t] - f2[t];
        float ad = fabsf(d);
        val = (ad < 1.f) ? (0.5f * d * d) : (ad - 0.5f);
    }
    __shared__ float sdata[256];
    sdata[threadIdx.x] = val;
    __syncthreads();
    for (int s = 128; s > 0; s >>= 1) {
        if (threadIdx.x < s) sdata[threadIdx.x] += sdata[threadIdx.x + s];
        __syncthreads();
    }
    if (threadIdx.x == 0) atomicAdd(slot, sdata[0]);
}

// ---------- 3x3 symmetric smallest eigenvector (double, analytic) ----------
__device__ void smallest_evec(double cxx, double cxy, double cxz,
                              double cyy, double cyz, double czz, double ev[3]) {
    double p1 = cxy * cxy + cxz * cxz + cyz * cyz;
    double q = (cxx + cyy + czz) / 3.0;
    double p2 = (cxx - q) * (cxx - q) + (cyy - q) * (cyy - q) + (czz - q) * (czz - q) + 2.0 * p1;
    double lam = q;
    if (p2 > 0.0) {
        double p = sqrt(p2 / 6.0);
        double b00 = (cxx - q) / p, b11 = (cyy - q) / p, b22 = (czz - q) / p;
        double b01 = cxy / p, b02 = cxz / p, b12 = cyz / p;
        double detB = b00 * (b11 * b22 - b12 * b12) - b01 * (b01 * b22 - b12 * b02)
                    + b02 * (b01 * b12 - b11 * b02);
        double r = detB * 0.5;
        r = r < -1.0 ? -1.0 : (r > 1.0 ? 1.0 : r);
        double phi = acos(r) / 3.0;
        lam = q + 2.0 * p * cos(phi + 2.0943951023931953);
    }
    double r0x = cxx - lam, r0y = cxy, r0z = cxz;
    double r1x = cxy, r1y = cyy - lam, r1z = cyz;
    double r2x = cxz, r2y = cyz, r2z = czz - lam;
    double c0x = r0y * r1z - r0z * r1y, c0y = r0z * r1x - r0x * r1z, c0z = r0x * r1y - r0y * r1x;
    double c1x = r0y * r2z - r0z * r2y, c1y = r0z * r2x - r0x * r2z, c1z = r0x * r2y - r0y * r2x;
    double c2x = r1y * r2z - r1z * r2y, c2y = r1z * r2x - r1x * r2z, c2z = r1x * r2y - r1y * r2x;
    double n0 = c0x * c0x + c0y * c0y + c0z * c0z;
    double n1 = c1x * c1x + c1y * c1y + c1z * c1z;
    double n2 = c2x * c2x + c2y * c2y + c2z * c2z;
    double bx = c0x, by = c0y, bz = c0z, bn = n0;
    if (n1 > bn) { bx = c1x; by = c1y; bz = c1z; bn = n1; }
    if (n2 > bn) { bx = c2x; by = c2y; bz = c2z; bn = n2; }
    if (bn < 1e-280) { ev[0] = 1.0; ev[1] = 0.0; ev[2] = 0.0; return; }
    double inv = 1.0 / sqrt(bn);
    ev[0] = bx * inv; ev[1] = by * inv; ev[2] = bz * inv;
}

// ---------- normals ----------
__global__ void normals_kernel(const float* __restrict__ pred, const int* __restrict__ knn,
                               float* __restrict__ nrm) {
    int t = blockIdx.x * blockDim.x + threadIdx.x;
    if (t >= BSZ * NPTS) return;
    int b = t / NPTS, i = t % NPTS;
    const float* P = pred + (size_t)b * NPTS * 3;
    const int* id = knn + (size_t)t * 32;
    float px[32], py[32], pz[32];
    double sx = 0, sy = 0, sz = 0;
    for (int k = 0; k < 32; ++k) {
        int j = id[k];
        px[k] = P[j * 3 + 0]; py[k] = P[j * 3 + 1]; pz[k] = P[j * 3 + 2];
        sx += px[k]; sy += py[k]; sz += pz[k];
    }
    double mx = sx / 32.0, my = sy / 32.0, mz = sz / 32.0;
    double cxx = 0, cxy = 0, cxz = 0, cyy = 0, cyz = 0, czz = 0;
    for (int k = 0; k < 32; ++k) {
        double dx = px[k] - mx, dy = py[k] - my, dz = pz[k] - mz;
        cxx += dx * dx; cxy += dx * dy; cxz += dx * dz;
        cyy += dy * dy; cyz += dy * dz; czz += dz * dz;
    }
    cxx /= 32.0; cxy /= 32.0; cxz /= 32.0; cyy /= 32.0; cyz /= 32.0; czz /= 32.0;
    double ev[3];
    smallest_evec(cxx, cxy, cxz, cyy, cyz, czz, ev);
    float qx = P[i * 3 + 0], qy = P[i * 3 + 1], qz = P[i * 3 + 2];
    double proj = 0.0;
    for (int k = 0; k < 32; ++k)
        proj += (px[k] - qx) * ev[0] + (py[k] - qy) * ev[1] + (pz[k] - qz) * ev[2];
    double s = (proj >= 0.0) ? 1.0 : -1.0;
    nrm[(size_t)t * 3 + 0] = (float)(ev[0] * s);
    nrm[(size_t)t * 3 + 1] = (float)(ev[1] * s);
    nrm[(size_t)t * 3 + 2] = (float)(ev[2] * s);
}

// ---------- manifold loss: reads first 8 of the 32-NN list (stable top-k prefix) ----------
__global__ void manifold_kernel(const float* __restrict__ nrm, const int* __restrict__ knn,
                                int kstride, float* __restrict__ slot) {
    int t = blockIdx.x * blockDim.x + threadIdx.x;
    float val = 0.f;
    if (t < BSZ * NPTS) {
        int b = t / NPTS;
        const float* NB = nrm + (size_t)b * NPTS * 3;
        const int* id = knn + (size_t)t * kstride;
        int j0 = id[0];
        float ax = NB[j0 * 3 + 0], ay = NB[j0 * 3 + 1], az = NB[j0 * 3 + 2];
        float an = fmaxf(sqrtf(ax * ax + ay * ay + az * az), 1e-6f);
        float x[8]; float s = 0.f;
        for (int k = 0; k < 8; ++k) {
            int j = id[k];
            float bx = NB[j * 3 + 0], by = NB[j * 3 + 1], bz = NB[j * 3 + 2];
            float bn_ = fmaxf(sqrtf(bx * bx + by * by + bz * bz), 1e-6f);
            float c = (ax * bx + ay * by + az * bz) / (an * bn_);
            x[k] = 1.f - c; s += x[k];
        }
        float mean = s / 8.f;
        float var = 0.f;
        for (int k = 0; k < 8; ++k) { float d = x[k] - mean; var += d * d; }
        val = sqrtf(var / 7.f);
    }
    __shared__ float sdata[256];
    sdata[threadIdx.x] = val;
    __syncthreads();
    for (int s2 = 128; s2 > 0; s2 >>= 1) {
        if (threadIdx.x < s2) sdata[threadIdx.x] += sdata[threadIdx.x + s2];
        __syncthreads();
    }
    if (threadIdx.x == 0) atomicAdd(slot, sdata[0]);
}

__global__ void finalize_kernel(const float* __restrict__ acc, float* __restrict__ out) {
    float l_recon = 0.5f * (acc[0] / (16.f * 2048.f) + acc[1] / (16.f * 2432.f));
    float l_match = 0.5f * (acc[2] / (16.f * 1024.f) + acc[3] / (16.f * 1216.f));
    float l_latent = acc[4] / (16.f * 1024.f);
    float l_man = 0.1f * (acc[5] / (16.f * 2048.f));
    out[0] = l_recon + l_match + l_latent + l_man;
    out[1] = l_recon;
    out[2] = l_match;
    out[3] = l_latent;
    out[4] = l_man;
}

// ================= host =================
extern "C" void kernel_launch(void* const* d_in, const int* in_sizes, int n_in,
                              void* d_out, int out_size, void* d_ws, size_t ws_size,
                              hipStream_t stream) {
    (void)in_sizes; (void)n_in; (void)out_size; (void)ws_size;
    const float* pts = (const float*)d_in[0];
    const float* W1 = (const float*)d_in[1];
    const float* b1 = (const float*)d_in[2];
    const float* g1 = (const float*)d_in[3];
    const float* be1 = (const float*)d_in[4];
    const float* m1 = (const float*)d_in[5];
    const float* v1 = (const float*)d_in[6];
    const float* W2 = (const float*)d_in[7];
    const float* b2 = (const float*)d_in[8];
    const float* W3 = (const float*)d_in[9];
    const float* b3 = (const float*)d_in[10];
    const float* g2 = (const float*)d_in[11];
    const float* be2 = (const float*)d_in[12];
    const float* m2 = (const float*)d_in[13];
    const float* v2 = (const float*)d_in[14];
    const float* W4 = (const float*)d_in[15];
    const float* b4 = (const float*)d_in[16];
    const float* D1W = (const float*)d_in[17];
    const float* D1b = (const float*)d_in[18];
    const float* D2W = (const float*)d_in[19];
    const float* D2b = (const float*)d_in[20];
    const float* D3W = (const float*)d_in[21];
    const float* D3b = (const float*)d_in[22];
    const float* D4W = (const float*)d_in[23];
    const float* D4b = (const float*)d_in[24];

    char* ws = (char*)d_ws;
    size_t off = 0;
    auto alloc = [&](size_t bytes) -> void* {
        void* p = ws + off;
        off += (bytes + 255) & ~(size_t)255;
        return p;
    };
    float* center   = (float*)alloc((size_t)BSZ * NG * 3 * 4);
    int*   knnc     = (int*)  alloc((size_t)BSZ * NG * GS * 4);
    float* rebuild0 = (float*)alloc((size_t)BSZ * 2048 * 3 * 4);
    float* rebuild1 = (float*)alloc((size_t)BSZ * 1024 * 3 * 4);
    float* H1       = (float*)alloc((size_t)BSZ * 2048 * 128 * 4);
    float* H2       = (float*)alloc((size_t)BSZ * 2048 * 256 * 4);
    float* H3       = (float*)alloc((size_t)BSZ * 2048 * 512 * 4);
    float* gmaxb    = (float*)alloc((size_t)BSZ * 256 * 4);
    float* gpart    = (float*)alloc((size_t)BSZ * 512 * 4);
    unsigned* featkey = (unsigned*)alloc((size_t)BSZ * 1024 * 4);
    float* feat     = (float*)alloc((size_t)BSZ * 1024 * 4);
    float* featrec  = (float*)alloc((size_t)BSZ * 1024 * 4);
    float* dh1      = (float*)alloc((size_t)BSZ * 2048 * 4);
    float* dh2      = (float*)alloc((size_t)BSZ * 2048 * 4);
    float* dh3      = (float*)alloc((size_t)BSZ * 2048 * 4);
    float* pred     = (float*)alloc((size_t)BSZ * 6144 * 4);
    int*   idxa     = (int*)  alloc((size_t)BSZ * 64 * NBRK * 4);
    float* gatha    = (float*)alloc((size_t)BSZ * 64 * NBRK * 3 * 4);
    int*   idxb     = (int*)  alloc((size_t)BSZ * 32 * NBRK * 4);
    float* gathb    = (float*)alloc((size_t)BSZ * 32 * NBRK * 3 * 4);
    int*   idxc     = (int*)  alloc((size_t)BSZ * 32 * 32 * 4);
    float* gathc    = (float*)alloc((size_t)BSZ * 1024 * 3 * 4);
    int*   knn32    = (int*)  alloc((size_t)BSZ * 2048 * 32 * 4);
    float* nrmbuf   = (float*)alloc((size_t)BSZ * 2048 * 3 * 4);
    float* accum    = (float*)alloc(8 * 4);

    hipMemsetAsync(accum, 0, 8 * 4, stream);

    auto knn = [&](const float* Q, int q_bstride, int q_off, int nq,
                   const float* DB, int db_bstride, int ndb, int k, int* out) {
        int total = BSZ * nq;
        knn_wave_kernel<<<(total + 3) / 4, 256, 0, stream>>>(Q, q_bstride, q_off, nq,
                                                             DB, db_bstride, ndb, k, out, BSZ);
    };

    // FPS + grouping
    fps_kernel<<<BSZ, 256, 0, stream>>>(pts, center);
    knn(center, NG, 0, NG, pts, NPTS, NPTS, GS, knnc);
    gather_points_kernel<<<(BSZ * 2048 + 255) / 256, 256, 0, stream>>>(pts, NPTS, knnc, NG * GS,
                                                                       0, 2048, rebuild0, BSZ);
    gather_points_kernel<<<(BSZ * 1024 + 255) / 256, 256, 0, stream>>>(pts, NPTS, knnc, NG * GS,
                                                                       2048, 1024, rebuild1, BSZ);

    auto enc = [&](const float* X, int n, float* featout) {
        int M = BSZ * n;
        gemm_kernel<<<dim3(128 / 64, M / 64), 256, 0, stream>>>(
            X, 3, W1, 3, 0, b1, nullptr, g1, be1, m1, v1, H1, 128, nullptr, M, 128, 3, n, 1);
        gemm_kernel<<<dim3(256 / 64, M / 64), 256, 0, stream>>>(
            H1, 128, W2, 128, 0, b2, nullptr, nullptr, nullptr, nullptr, nullptr,
            H2, 256, nullptr, M, 256, 128, n, 0);
        colmax_kernel<<<BSZ, 256, 0, stream>>>(H2, n, gmaxb);
        hipMemsetAsync(gpart, 0, (size_t)BSZ * 512 * 4, stream);
        skinny16_kernel<<<dim3(8, 1), 256, 0, stream>>>(gmaxb, W3, 512, 0, gpart, 256, 512, 1);
        bias_act_kernel<<<(BSZ * 512 + 255) / 256, 256, 0, stream>>>(gpart, b3, BSZ * 512, 512, 0);
        gemm_kernel<<<dim3(512 / 64, M / 64), 256, 0, stream>>>(
            H2, 256, W3, 512, 256, nullptr, gpart, g2, be2, m2, v2, H3, 512, nullptr,
            M, 512, 256, n, 1);
        hipMemsetAsync(featkey, 0, (size_t)BSZ * 1024 * 4, stream);
        gemm_kernel<<<dim3(1024 / 64, M / 64), 256, 0, stream>>>(
            H3, 512, W4, 512, 0, b4, nullptr, nullptr, nullptr, nullptr, nullptr,
            nullptr, 0, featkey, M, 1024, 512, n, 0);
        decode_kernel<<<(BSZ * 1024 + 255) / 256, 256, 0, stream>>>(featkey, featout, BSZ * 1024);
    };

    enc(rebuild0, 2048, feat);

    // decoder (skinny M=16)
    auto dec_layer = [&](const float* A, int K, const float* Wd, const float* bd,
                         float* Cbuf, int N, int relu) {
        hipMemsetAsync(Cbuf, 0, (size_t)BSZ * N * 4, stream);
        int nk = (K >= 1024) ? 4 : 1;
        skinny16_kernel<<<dim3(N / 64, nk), 256, 0, stream>>>(A, Wd, K, 0, Cbuf, K, N, nk);
        bias_act_kernel<<<(BSZ * N + 255) / 256, 256, 0, stream>>>(Cbuf, bd, BSZ * N, N, relu);
    };
    dec_layer(feat, 1024, D1W, D1b, dh1, 2048, 1);
    dec_layer(dh1, 2048, D2W, D2b, dh2, 2048, 1);
    dec_layer(dh2, 2048, D3W, D3b, dh3, 2048, 1);
    dec_layer(dh3, 2048, D4W, D4b, pred, 6144, 0);

    // l_recon
    knn(center, NG, 0, 64, pred, 2048, 2048, NBRK, idxa);
    gather_points_kernel<<<(BSZ * 2432 + 255) / 256, 256, 0, stream>>>(pred, 2048, idxa, 64 * NBRK,
                                                                       0, 2432, gatha, BSZ);
    chamfer_min_kernel<<<(BSZ * 2048 + 255) / 256, 256, 0, stream>>>(rebuild0, 2048, gatha, 2432,
                                                                     accum + 0);
    chamfer_min_kernel<<<(BSZ * 2432 + 255) / 256, 256, 0, stream>>>(gatha, 2432, rebuild0, 2048,
                                                                     accum + 1);
    // l_match
    knn(center, NG, 64, 32, pred, 2048, 2048, NBRK, idxb);
    gather_points_kernel<<<(BSZ * 1216 + 255) / 256, 256, 0, stream>>>(pred, 2048, idxb, 32 * NBRK,
                                                                       0, 1216, gathb, BSZ);
    chamfer_min_kernel<<<(BSZ * 1024 + 255) / 256, 256, 0, stream>>>(rebuild1, 1024, gathb, 1216,
                                                                     accum + 2);
    chamfer_min_kernel<<<(BSZ * 1216 + 255) / 256, 256, 0, stream>>>(gathb, 1216, rebuild1, 1024,
                                                                     accum + 3);
    // l_latent
    knn(center, NG, 96, 32, pred, 2048, 2048, 32, idxc);
    gather_points_kernel<<<(BSZ * 1024 + 255) / 256, 256, 0, stream>>>(pred, 2048, idxc, 32 * 32,
                                                                       0, 1024, gathc, BSZ);
    enc(gathc, 1024, featrec);
    latent_kernel<<<(BSZ * 1024 + 255) / 256, 256, 0, stream>>>(feat, featrec, BSZ * 1024,
                                                                accum + 4);
    // l_man: one self-KNN (k=32); manifold uses first 8 (stable top-k prefix)
    knn(pred, 2048, 0, 2048, pred, 2048, 2048, 32, knn32);
    normals_kernel<<<(BSZ * 2048 + 255) / 256, 256, 0, stream>>>(pred, knn32, nrmbuf);
    manifold_kernel<<<(BSZ * 2048 + 255) / 256, 256, 0, stream>>>(nrmbuf, knn32, 32, accum + 5);

    finalize_kernel<<<1, 1, 0, stream>>>(accum, (float*)d_out);
}

// Round 3
// 2653.225 us; speedup vs baseline: 14.9511x; 1.6862x over previous
//
#include <hip/hip_runtime.h>
#include <math.h>

#define BSZ 16
#define NPTS 2048
#define NG 128
#define GS 32
#define NBRK 38

typedef _Float16 f16;
typedef _Float16 f16x8 __attribute__((ext_vector_type(8)));
typedef float f32x4 __attribute__((ext_vector_type(4)));

// ---------- helpers ----------
__device__ __forceinline__ unsigned fkey(float x) {
    unsigned u = __float_as_uint(x);
    return (u >> 31) ? ~u : (u | 0x80000000u);
}
__device__ __forceinline__ float fkey_inv(unsigned k) {
    unsigned u = (k >> 31) ? (k ^ 0x80000000u) : ~k;
    return __uint_as_float(u);
}

// ---------- FPS ----------
__global__ void fps_kernel(const float* __restrict__ pts, float* __restrict__ center) {
    int b = blockIdx.x;
    __shared__ float mind[NPTS];
    __shared__ float rv[256];
    __shared__ int   ri[256];
    const float* P = pts + (size_t)b * NPTS * 3;
    for (int i = threadIdx.x; i < NPTS; i += 256) mind[i] = 1e10f;
    __syncthreads();
    int far = 0;
    for (int g = 0; g < NG; ++g) {
        float cx = P[far * 3 + 0], cy = P[far * 3 + 1], cz = P[far * 3 + 2];
        if (threadIdx.x == 0) {
            center[((size_t)b * NG + g) * 3 + 0] = cx;
            center[((size_t)b * NG + g) * 3 + 1] = cy;
            center[((size_t)b * NG + g) * 3 + 2] = cz;
        }
        float best = -1.0f; int bi = 0;
        for (int i = threadIdx.x; i < NPTS; i += 256) {
            float dx = P[i * 3 + 0] - cx;
            float dy = P[i * 3 + 1] - cy;
            float dz = P[i * 3 + 2] - cz;
            float d = dx * dx + dy * dy + dz * dz;
            float md = fminf(mind[i], d);
            mind[i] = md;
            if (md > best) { best = md; bi = i; }   // i ascending -> first max kept
        }
        rv[threadIdx.x] = best; ri[threadIdx.x] = bi;
        __syncthreads();
        for (int s = 128; s >= 1; s >>= 1) {
            if (threadIdx.x < s) {
                float v2 = rv[threadIdx.x + s]; int i2 = ri[threadIdx.x + s];
                if (v2 > rv[threadIdx.x] || (v2 == rv[threadIdx.x] && i2 < ri[threadIdx.x])) {
                    rv[threadIdx.x] = v2; ri[threadIdx.x] = i2;
                }
            }
            __syncthreads();
        }
        far = ri[0];
        __syncthreads();
    }
}

// ---------- KNN: one wave per query, LDS distance row, k-round argmin ----------
__global__ void knn_wave_kernel(const float* __restrict__ Q, int q_bstride, int q_off, int nq,
                                const float* __restrict__ DB, int db_bstride, int ndb,
                                int k, int* __restrict__ out, int nbatch) {
    __shared__ float dist[4][NPTS];
    int wave = threadIdx.x >> 6;
    int lane = threadIdx.x & 63;
    int qidx = blockIdx.x * 4 + wave;
    bool active = qidx < nbatch * nq;
    float* D = dist[wave];
    int b = 0, qi = 0;
    if (active) { b = qidx / nq; qi = qidx % nq; }
    if (active) {
        const float* q = Q + ((size_t)b * q_bstride + q_off + qi) * 3;
        float qx = q[0], qy = q[1], qz = q[2];
        float qq = qx * qx + qy * qy + qz * qz;
        const float* db = DB + (size_t)b * db_bstride * 3;
        for (int j = lane; j < ndb; j += 64) {
            float bx = db[j * 3 + 0], by = db[j * 3 + 1], bz = db[j * 3 + 2];
            float bb = bx * bx + by * by + bz * bz;
            D[j] = qq + bb - 2.0f * (qx * bx + qy * by + qz * bz);
        }
    }
    __syncthreads();
    int* o = out + (size_t)qidx * k;
    for (int r = 0; r < k; ++r) {
        if (active) {
            float best = 3e38f; int bi = ndb;
            for (int j = lane; j < ndb; j += 64) {
                float v = D[j];
                if (v < best) { best = v; bi = j; }
            }
            for (int s = 32; s >= 1; s >>= 1) {
                float ov = __shfl_xor(best, s, 64);
                int   oi = __shfl_xor(bi, s, 64);
                if (ov < best || (ov == best && oi < bi)) { best = ov; bi = oi; }
            }
            if (lane == 0) {
                o[r] = bi;
                D[bi] = 3e38f;
            }
        }
        __syncthreads();
    }
}

// ---------- gather points via index array ----------
__global__ void gather_points_kernel(const float* __restrict__ pts, int db_bstride,
                                     const int* __restrict__ idx, int idx_bstride, int idx_off,
                                     int m, float* __restrict__ out, int nbatch) {
    int t = blockIdx.x * blockDim.x + threadIdx.x;
    if (t >= nbatch * m) return;
    int b = t / m, j = t % m;
    int s = idx[(size_t)b * idx_bstride + idx_off + j];
    const float* p = pts + ((size_t)b * db_bstride + s) * 3;
    out[(size_t)t * 3 + 0] = p[0];
    out[(size_t)t * 3 + 1] = p[1];
    out[(size_t)t * 3 + 2] = p[2];
}

// ---------- fp32 -> fp16 weight conversion (strided slice) ----------
__global__ void cvt_w_kernel(const float* __restrict__ in, int ld, int off, int K,
                             f16* __restrict__ out, int total) {
    int t = blockIdx.x * blockDim.x + threadIdx.x;
    if (t >= total) return;
    int n = t / K, k = t % K;
    out[t] = (f16)in[(size_t)n * ld + off + k];
}

// ---------- layer1: H1 = relu(bn(x @ W1^T + b1)) in fp16, fused ----------
__global__ void layer1_kernel(const float* __restrict__ X, const float* __restrict__ W1,
                              const float* __restrict__ b1, const float* __restrict__ g1,
                              const float* __restrict__ be1, const float* __restrict__ m1,
                              const float* __restrict__ v1, f16* __restrict__ H1, int M) {
    __shared__ float w[384], bb[128], sg[128], sb[128], sm[128], sv[128];
    for (int i = threadIdx.x; i < 384; i += 256) w[i] = W1[i];
    if (threadIdx.x < 128) {
        int c = threadIdx.x;
        bb[c] = b1[c]; sg[c] = g1[c]; sb[c] = be1[c]; sm[c] = m1[c]; sv[c] = v1[c];
    }
    __syncthreads();
    int t = blockIdx.x * 256 + threadIdx.x;   // over M*16
    if (t >= M * 16) return;
    int row = t >> 4, cg = (t & 15) * 8;
    float x0 = X[(size_t)row * 3], x1 = X[(size_t)row * 3 + 1], x2 = X[(size_t)row * 3 + 2];
    f16x8 outv;
#pragma unroll
    for (int j = 0; j < 8; ++j) {
        int c = cg + j;
        float tv = x0 * w[c * 3] + x1 * w[c * 3 + 1] + x2 * w[c * 3 + 2] + bb[c];
        float vv = (tv - sm[c]) * rsqrtf(sv[c] + 1e-5f) * sg[c] + sb[c];
        outv[j] = (f16)fmaxf(vv, 0.f);
    }
    *(f16x8*)&H1[(size_t)row * 128 + cg] = outv;
}

// ---------- MFMA GEMM: C[M,N](f16) = A[M,K](f16) @ W[N,K]^T(f16), fp32 acc ----------
// 128x128 block tile, 4 waves (2x2), each wave 64x64 = 4x4 mfma_16x16x32 subtiles.
// Epilogue: bias / bias2d / bn / relu / optional fp16 C store / optional per-batch
// column max into maxkey (monotone-uint atomicMax).
__global__ __launch_bounds__(256) void mfma_gemm_kernel(
        const f16* __restrict__ A, const f16* __restrict__ W, int K, int N,
        const float* __restrict__ bias, const float* __restrict__ bias2d,
        const float* __restrict__ bng, const float* __restrict__ bnb,
        const float* __restrict__ bnm, const float* __restrict__ bnv,
        f16* __restrict__ Cout, unsigned* __restrict__ maxkey,
        int rows_per_batch, int relu) {
    __shared__ f16 Als[128 * 40];   // padded stride 40 f16: only free 2-way conflicts
    __shared__ f16 Bls[128 * 40];
    int tid = threadIdx.x;
    int lane = tid & 63;
    int wave = tid >> 6;
    int wm = wave & 1, wn = wave >> 1;
    int c16 = lane & 15, quad = lane >> 4;
    int row0 = blockIdx.y * 128, col0 = blockIdx.x * 128;

    int sr = tid >> 2;            // 0..63 staging row
    int skc = (tid & 3) * 8;      // staging k-offset

    f32x4 acc[4][4];
#pragma unroll
    for (int i = 0; i < 4; ++i)
#pragma unroll
        for (int j = 0; j < 4; ++j) acc[i][j] = (f32x4){0.f, 0.f, 0.f, 0.f};

    for (int k0 = 0; k0 < K; k0 += 32) {
#pragma unroll
        for (int i = 0; i < 2; ++i) {
            int r2 = sr + i * 64;
            f16x8 av = *(const f16x8*)(A + (size_t)(row0 + r2) * K + k0 + skc);
            *(f16x8*)&Als[r2 * 40 + skc] = av;
            f16x8 bv = *(const f16x8*)(W + (size_t)(col0 + r2) * K + k0 + skc);
            *(f16x8*)&Bls[r2 * 40 + skc] = bv;
        }
        __syncthreads();
        f16x8 af[4], bf[4];
#pragma unroll
        for (int s = 0; s < 4; ++s) {
            af[s] = *(const f16x8*)&Als[(wm * 64 + s * 16 + c16) * 40 + quad * 8];
            bf[s] = *(const f16x8*)&Bls[(wn * 64 + s * 16 + c16) * 40 + quad * 8];
        }
#pragma unroll
        for (int ms = 0; ms < 4; ++ms)
#pragma unroll
            for (int ns = 0; ns < 4; ++ns)
                acc[ms][ns] = __builtin_amdgcn_mfma_f32_16x16x32_f16(af[ms], bf[ns],
                                                                     acc[ms][ns], 0, 0, 0);
        __syncthreads();
    }

    int b = row0 / rows_per_batch;   // 128-row tile lies in one batch (128 | rpb)
#pragma unroll
    for (int ns = 0; ns < 4; ++ns) {
        int col = col0 + wn * 64 + ns * 16 + c16;
        float bv = bias ? bias[col] : 0.f;
        float b2v = bias2d ? bias2d[(size_t)b * N + col] : 0.f;
        float mx = -3e38f;
#pragma unroll
        for (int ms = 0; ms < 4; ++ms) {
#pragma unroll
            for (int j = 0; j < 4; ++j) {
                float v = acc[ms][ns][j] + bv + b2v;
                if (bng) v = (v - bnm[col]) * rsqrtf(bnv[col] + 1e-5f) * bng[col] + bnb[col];
                if (relu) v = fmaxf(v, 0.f);
                if (Cout)
                    Cout[(size_t)(row0 + wm * 64 + ms * 16 + quad * 4 + j) * N + col] = (f16)v;
                mx = fmaxf(mx, v);
            }
        }
        if (maxkey) {
            mx = fmaxf(mx, __shfl_xor(mx, 16, 64));
            mx = fmaxf(mx, __shfl_xor(mx, 32, 64));
            if (quad == 0) atomicMax(&maxkey[(size_t)b * N + col], fkey(mx));
        }
    }
}

// ---------- skinny GEMM: C[16,N] += A[16,K] @ W[N,K]^T (C pre-zeroed) ----------
__global__ void skinny16_kernel(const float* __restrict__ A, const float* __restrict__ W,
                                int ldw, int woff, float* __restrict__ C,
                                int K, int N, int nkchunks) {
    int col = blockIdx.x * 64 + (threadIdx.x & 63);
    int ks = threadIdx.x >> 6;
    int chunk = K / nkchunks;
    int sub = chunk >> 2;
    int k0 = blockIdx.y * chunk + ks * sub;
    const float* w = W + (size_t)col * ldw + woff;
    float acc[16];
#pragma unroll
    for (int m = 0; m < 16; ++m) acc[m] = 0.f;
    for (int k = k0; k < k0 + sub; ++k) {
        float wv = w[k];
#pragma unroll
        for (int m = 0; m < 16; ++m) acc[m] += A[(size_t)m * K + k] * wv;
    }
    for (int m = 0; m < 16; ++m) atomicAdd(&C[(size_t)m * N + col], acc[m]);
}

__global__ void bias_act_kernel(float* __restrict__ C, const float* __restrict__ bias,
                                int total, int N, int relu) {
    int t = blockIdx.x * blockDim.x + threadIdx.x;
    if (t >= total) return;
    int n = t % N;
    float v = C[t] + bias[n];
    if (relu) v = fmaxf(v, 0.f);
    C[t] = v;
}

__global__ void decode_kernel(const unsigned* __restrict__ k, float* __restrict__ f, int n) {
    int t = blockIdx.x * blockDim.x + threadIdx.x;
    if (t < n) f[t] = fkey_inv(k[t]);
}

// ---------- chamfer one direction ----------
__global__ void chamfer_min_kernel(const float* __restrict__ A, int na,
                                   const float* __restrict__ Bp, int nb,
                                   float* __restrict__ slot) {
    int t = blockIdx.x * blockDim.x + threadIdx.x;
    float val = 0.f;
    if (t < BSZ * na) {
        int b = t / na;
        const float* a = A + (size_t)t * 3;
        float ax = a[0], ay = a[1], az = a[2];
        float aa = ax * ax + ay * ay + az * az;
        const float* Bb = Bp + (size_t)b * nb * 3;
        float m = 3e38f;
        for (int j = 0; j < nb; ++j) {
            float bx = Bb[j * 3 + 0], by = Bb[j * 3 + 1], bz = Bb[j * 3 + 2];
            float d = aa + bx * bx + by * by + bz * bz - 2.0f * (ax * bx + ay * by + az * bz);
            m = fminf(m, d);
        }
        val = sqrtf(fmaxf(m, 1e-12f));
    }
    __shared__ float sdata[256];
    sdata[threadIdx.x] = val;
    __syncthreads();
    for (int s = 128; s > 0; s >>= 1) {
        if (threadIdx.x < s) sdata[threadIdx.x] += sdata[threadIdx.x + s];
        __syncthreads();
    }
    if (threadIdx.x == 0) atomicAdd(slot, sdata[0]);
}

// ---------- smooth-L1 latent loss sum ----------
__global__ void latent_kernel(const float* __restrict__ f1, const float* __restrict__ f2,
                              int n, float* __restrict__ slot) {
    int t = blockIdx.x * blockDim.x + threadIdx.x;
    float val = 0.f;
    if (t < n) {
        float d = f1[t] - f2[t];
        float ad = fabsf(d);
        val = (ad < 1.f) ? (0.5f * d * d) : (ad - 0.5f);
    }
    __shared__ float sdata[256];
    sdata[threadIdx.x] = val;
    __syncthreads();
    for (int s = 128; s > 0; s >>= 1) {
        if (threadIdx.x < s) sdata[threadIdx.x] += sdata[threadIdx.x + s];
        __syncthreads();
    }
    if (threadIdx.x == 0) atomicAdd(slot, sdata[0]);
}

// ---------- 3x3 symmetric smallest eigenvector (double, analytic) ----------
__device__ void smallest_evec(double cxx, double cxy, double cxz,
                              double cyy, double cyz, double czz, double ev[3]) {
    double p1 = cxy * cxy + cxz * cxz + cyz * cyz;
    double q = (cxx + cyy + czz) / 3.0;
    double p2 = (cxx - q) * (cxx - q) + (cyy - q) * (cyy - q) + (czz - q) * (czz - q) + 2.0 * p1;
    double lam = q;
    if (p2 > 0.0) {
        double p = sqrt(p2 / 6.0);
        double b00 = (cxx - q) / p, b11 = (cyy - q) / p, b22 = (czz - q) / p;
        double b01 = cxy / p, b02 = cxz / p, b12 = cyz / p;
        double detB = b00 * (b11 * b22 - b12 * b12) - b01 * (b01 * b22 - b12 * b02)
                    + b02 * (b01 * b12 - b11 * b02);
        double r = detB * 0.5;
        r = r < -1.0 ? -1.0 : (r > 1.0 ? 1.0 : r);
        double phi = acos(r) / 3.0;
        lam = q + 2.0 * p * cos(phi + 2.0943951023931953);
    }
    double r0x = cxx - lam, r0y = cxy, r0z = cxz;
    double r1x = cxy, r1y = cyy - lam, r1z = cyz;
    double r2x = cxz, r2y = cyz, r2z = czz - lam;
    double c0x = r0y * r1z - r0z * r1y, c0y = r0z * r1x - r0x * r1z, c0z = r0x * r1y - r0y * r1x;
    double c1x = r0y * r2z - r0z * r2y, c1y = r0z * r2x - r0x * r2z, c1z = r0x * r2y - r0y * r2x;
    double c2x = r1y * r2z - r1z * r2y, c2y = r1z * r2x - r1x * r2z, c2z = r1x * r2y - r1y * r2x;
    double n0 = c0x * c0x + c0y * c0y + c0z * c0z;
    double n1 = c1x * c1x + c1y * c1y + c1z * c1z;
    double n2 = c2x * c2x + c2y * c2y + c2z * c2z;
    double bx = c0x, by = c0y, bz = c0z, bn = n0;
    if (n1 > bn) { bx = c1x; by = c1y; bz = c1z; bn = n1; }
    if (n2 > bn) { bx = c2x; by = c2y; bz = c2z; bn = n2; }
    if (bn < 1e-280) { ev[0] = 1.0; ev[1] = 0.0; ev[2] = 0.0; return; }
    double inv = 1.0 / sqrt(bn);
    ev[0] = bx * inv; ev[1] = by * inv; ev[2] = bz * inv;
}

// ---------- normals ----------
__global__ void normals_kernel(const float* __restrict__ pred, const int* __restrict__ knn,
                               float* __restrict__ nrm) {
    int t = blockIdx.x * blockDim.x + threadIdx.x;
    if (t >= BSZ * NPTS) return;
    int b = t / NPTS, i = t % NPTS;
    const float* P = pred + (size_t)b * NPTS * 3;
    const int* id = knn + (size_t)t * 32;
    float px[32], py[32], pz[32];
    double sx = 0, sy = 0, sz = 0;
    for (int k = 0; k < 32; ++k) {
        int j = id[k];
        px[k] = P[j * 3 + 0]; py[k] = P[j * 3 + 1]; pz[k] = P[j * 3 + 2];
        sx += px[k]; sy += py[k]; sz += pz[k];
    }
    double mx = sx / 32.0, my = sy / 32.0, mz = sz / 32.0;
    double cxx = 0, cxy = 0, cxz = 0, cyy = 0, cyz = 0, czz = 0;
    for (int k = 0; k < 32; ++k) {
        double dx = px[k] - mx, dy = py[k] - my, dz = pz[k] - mz;
        cxx += dx * dx; cxy += dx * dy; cxz += dx * dz;
        cyy += dy * dy; cyz += dy * dz; czz += dz * dz;
    }
    cxx /= 32.0; cxy /= 32.0; cxz /= 32.0; cyy /= 32.0; cyz /= 32.0; czz /= 32.0;
    double ev[3];
    smallest_evec(cxx, cxy, cxz, cyy, cyz, czz, ev);
    float qx = P[i * 3 + 0], qy = P[i * 3 + 1], qz = P[i * 3 + 2];
    double proj = 0.0;
    for (int k = 0; k < 32; ++k)
        proj += (px[k] - qx) * ev[0] + (py[k] - qy) * ev[1] + (pz[k] - qz) * ev[2];
    double s = (proj >= 0.0) ? 1.0 : -1.0;
    nrm[(size_t)t * 3 + 0] = (float)(ev[0] * s);
    nrm[(size_t)t * 3 + 1] = (float)(ev[1] * s);
    nrm[(size_t)t * 3 + 2] = (float)(ev[2] * s);
}

// ---------- manifold loss: reads first 8 of the 32-NN list (stable top-k prefix) ----------
__global__ void manifold_kernel(const float* __restrict__ nrm, const int* __restrict__ knn,
                                int kstride, float* __restrict__ slot) {
    int t = blockIdx.x * blockDim.x + threadIdx.x;
    float val = 0.f;
    if (t < BSZ * NPTS) {
        int b = t / NPTS;
        const float* NB = nrm + (size_t)b * NPTS * 3;
        const int* id = knn + (size_t)t * kstride;
        int j0 = id[0];
        float ax = NB[j0 * 3 + 0], ay = NB[j0 * 3 + 1], az = NB[j0 * 3 + 2];
        float an = fmaxf(sqrtf(ax * ax + ay * ay + az * az), 1e-6f);
        float x[8]; float s = 0.f;
        for (int k = 0; k < 8; ++k) {
            int j = id[k];
            float bx = NB[j * 3 + 0], by = NB[j * 3 + 1], bz = NB[j * 3 + 2];
            float bn_ = fmaxf(sqrtf(bx * bx + by * by + bz * bz), 1e-6f);
            float c = (ax * bx + ay * by + az * bz) / (an * bn_);
            x[k] = 1.f - c; s += x[k];
        }
        float mean = s / 8.f;
        float var = 0.f;
        for (int k = 0; k < 8; ++k) { float d = x[k] - mean; var += d * d; }
        val = sqrtf(var / 7.f);
    }
    __shared__ float sdata[256];
    sdata[threadIdx.x] = val;
    __syncthreads();
    for (int s2 = 128; s2 > 0; s2 >>= 1) {
        if (threadIdx.x < s2) sdata[threadIdx.x] += sdata[threadIdx.x + s2];
        __syncthreads();
    }
    if (threadIdx.x == 0) atomicAdd(slot, sdata[0]);
}

__global__ void finalize_kernel(const float* __restrict__ acc, float* __restrict__ out) {
    float l_recon = 0.5f * (acc[0] / (16.f * 2048.f) + acc[1] / (16.f * 2432.f));
    float l_match = 0.5f * (acc[2] / (16.f * 1024.f) + acc[3] / (16.f * 1216.f));
    float l_latent = acc[4] / (16.f * 1024.f);
    float l_man = 0.1f * (acc[5] / (16.f * 2048.f));
    out[0] = l_recon + l_match + l_latent + l_man;
    out[1] = l_recon;
    out[2] = l_match;
    out[3] = l_latent;
    out[4] = l_man;
}

// ================= host =================
extern "C" void kernel_launch(void* const* d_in, const int* in_sizes, int n_in,
                              void* d_out, int out_size, void* d_ws, size_t ws_size,
                              hipStream_t stream) {
    (void)in_sizes; (void)n_in; (void)out_size; (void)ws_size;
    const float* pts = (const float*)d_in[0];
    const float* W1 = (const float*)d_in[1];
    const float* b1 = (const float*)d_in[2];
    const float* g1 = (const float*)d_in[3];
    const float* be1 = (const float*)d_in[4];
    const float* m1 = (const float*)d_in[5];
    const float* v1 = (const float*)d_in[6];
    const float* W2 = (const float*)d_in[7];
    const float* b2 = (const float*)d_in[8];
    const float* W3 = (const float*)d_in[9];
    const float* b3 = (const float*)d_in[10];
    const float* g2 = (const float*)d_in[11];
    const float* be2 = (const float*)d_in[12];
    const float* m2 = (const float*)d_in[13];
    const float* v2 = (const float*)d_in[14];
    const float* W4 = (const float*)d_in[15];
    const float* b4 = (const float*)d_in[16];
    const float* D1W = (const float*)d_in[17];
    const float* D1b = (const float*)d_in[18];
    const float* D2W = (const float*)d_in[19];
    const float* D2b = (const float*)d_in[20];
    const float* D3W = (const float*)d_in[21];
    const float* D3b = (const float*)d_in[22];
    const float* D4W = (const float*)d_in[23];
    const float* D4b = (const float*)d_in[24];

    char* ws = (char*)d_ws;
    size_t off = 0;
    auto alloc = [&](size_t bytes) -> void* {
        void* p = ws + off;
        off += (bytes + 255) & ~(size_t)255;
        return p;
    };
    float* center   = (float*)alloc((size_t)BSZ * NG * 3 * 4);
    int*   knnc     = (int*)  alloc((size_t)BSZ * NG * GS * 4);
    float* rebuild0 = (float*)alloc((size_t)BSZ * 2048 * 3 * 4);
    float* rebuild1 = (float*)alloc((size_t)BSZ * 1024 * 3 * 4);
    f16*   W2h      = (f16*)  alloc((size_t)256 * 128 * 2);
    f16*   W3h      = (f16*)  alloc((size_t)512 * 256 * 2);
    f16*   W4h      = (f16*)  alloc((size_t)1024 * 512 * 2);
    f16*   H1h      = (f16*)  alloc((size_t)BSZ * 2048 * 128 * 2);
    f16*   H2h      = (f16*)  alloc((size_t)BSZ * 2048 * 256 * 2);
    f16*   H3h      = (f16*)  alloc((size_t)BSZ * 2048 * 512 * 2);
    unsigned* gmaxkey = (unsigned*)alloc((size_t)BSZ * 256 * 4);
    float* gmaxb    = (float*)alloc((size_t)BSZ * 256 * 4);
    float* gpart    = (float*)alloc((size_t)BSZ * 512 * 4);
    unsigned* featkey = (unsigned*)alloc((size_t)BSZ * 1024 * 4);
    float* feat     = (float*)alloc((size_t)BSZ * 1024 * 4);
    float* featrec  = (float*)alloc((size_t)BSZ * 1024 * 4);
    float* dh1      = (float*)alloc((size_t)BSZ * 2048 * 4);
    float* dh2      = (float*)alloc((size_t)BSZ * 2048 * 4);
    float* dh3      = (float*)alloc((size_t)BSZ * 2048 * 4);
    float* pred     = (float*)alloc((size_t)BSZ * 6144 * 4);
    int*   idxa     = (int*)  alloc((size_t)BSZ * 64 * NBRK * 4);
    float* gatha    = (float*)alloc((size_t)BSZ * 64 * NBRK * 3 * 4);
    int*   idxb     = (int*)  alloc((size_t)BSZ * 32 * NBRK * 4);
    float* gathb    = (float*)alloc((size_t)BSZ * 32 * NBRK * 3 * 4);
    int*   idxc     = (int*)  alloc((size_t)BSZ * 32 * 32 * 4);
    float* gathc    = (float*)alloc((size_t)BSZ * 1024 * 3 * 4);
    int*   knn32    = (int*)  alloc((size_t)BSZ * 2048 * 32 * 4);
    float* nrmbuf   = (float*)alloc((size_t)BSZ * 2048 * 3 * 4);
    float* accum    = (float*)alloc(8 * 4);

    hipMemsetAsync(accum, 0, 8 * 4, stream);

    // one-time (per launch) weight conversions to fp16
    cvt_w_kernel<<<(256 * 128 + 255) / 256, 256, 0, stream>>>(W2, 128, 0, 128, W2h, 256 * 128);
    cvt_w_kernel<<<(512 * 256 + 255) / 256, 256, 0, stream>>>(W3, 512, 256, 256, W3h, 512 * 256);
    cvt_w_kernel<<<(1024 * 512 + 255) / 256, 256, 0, stream>>>(W4, 512, 0, 512, W4h, 1024 * 512);

    auto knn = [&](const float* Q, int q_bstride, int q_off, int nq,
                   const float* DB, int db_bstride, int ndb, int k, int* out) {
        int total = BSZ * nq;
        knn_wave_kernel<<<(total + 3) / 4, 256, 0, stream>>>(Q, q_bstride, q_off, nq,
                                                             DB, db_bstride, ndb, k, out, BSZ);
    };

    // FPS + grouping
    fps_kernel<<<BSZ, 256, 0, stream>>>(pts, center);
    knn(center, NG, 0, NG, pts, NPTS, NPTS, GS, knnc);
    gather_points_kernel<<<(BSZ * 2048 + 255) / 256, 256, 0, stream>>>(pts, NPTS, knnc, NG * GS,
                                                                       0, 2048, rebuild0, BSZ);
    gather_points_kernel<<<(BSZ * 1024 + 255) / 256, 256, 0, stream>>>(pts, NPTS, knnc, NG * GS,
                                                                       2048, 1024, rebuild1, BSZ);

    auto enc = [&](const float* X, int n, float* featout) {
        int M = BSZ * n;
        layer1_kernel<<<M / 16, 256, 0, stream>>>(X, W1, b1, g1, be1, m1, v1, H1h, M);
        // W2 + bias, fp16 H2 out, fused per-batch column max -> gmaxkey
        hipMemsetAsync(gmaxkey, 0, (size_t)BSZ * 256 * 4, stream);
        mfma_gemm_kernel<<<dim3(256 / 128, M / 128), 256, 0, stream>>>(
            H1h, W2h, 128, 256, b2, nullptr, nullptr, nullptr, nullptr, nullptr,
            H2h, gmaxkey, n, 0);
        decode_kernel<<<(BSZ * 256 + 255) / 256, 256, 0, stream>>>(gmaxkey, gmaxb, BSZ * 256);
        // gpart = gmax @ W3[:, :256]^T + b3  (fp32 skinny)
        hipMemsetAsync(gpart, 0, (size_t)BSZ * 512 * 4, stream);
        skinny16_kernel<<<dim3(8, 1), 256, 0, stream>>>(gmaxb, W3, 512, 0, gpart, 256, 512, 1);
        bias_act_kernel<<<(BSZ * 512 + 255) / 256, 256, 0, stream>>>(gpart, b3, BSZ * 512, 512, 0);
        // H3 = relu(bn(H2 @ W3[:,256:]^T + gpart))
        mfma_gemm_kernel<<<dim3(512 / 128, M / 128), 256, 0, stream>>>(
            H2h, W3h, 256, 512, nullptr, gpart, g2, be2, m2, v2, H3h, nullptr, n, 1);
        // feat = max over rows of (H3 @ W4^T + b4)
        hipMemsetAsync(featkey, 0, (size_t)BSZ * 1024 * 4, stream);
        mfma_gemm_kernel<<<dim3(1024 / 128, M / 128), 256, 0, stream>>>(
            H3h, W4h, 512, 1024, b4, nullptr, nullptr, nullptr, nullptr, nullptr,
            nullptr, featkey, n, 0);
        decode_kernel<<<(BSZ * 1024 + 255) / 256, 256, 0, stream>>>(featkey, featout, BSZ * 1024);
    };

    enc(rebuild0, 2048, feat);

    // decoder (skinny M=16, fp32)
    auto dec_layer = [&](const float* A, int K, const float* Wd, const float* bd,
                         float* Cbuf, int N, int relu) {
        hipMemsetAsync(Cbuf, 0, (size_t)BSZ * N * 4, stream);
        int nk = (K >= 1024) ? 4 : 1;
        skinny16_kernel<<<dim3(N / 64, nk), 256, 0, stream>>>(A, Wd, K, 0, Cbuf, K, N, nk);
        bias_act_kernel<<<(BSZ * N + 255) / 256, 256, 0, stream>>>(Cbuf, bd, BSZ * N, N, relu);
    };
    dec_layer(feat, 1024, D1W, D1b, dh1, 2048, 1);
    dec_layer(dh1, 2048, D2W, D2b, dh2, 2048, 1);
    dec_layer(dh2, 2048, D3W, D3b, dh3, 2048, 1);
    dec_layer(dh3, 2048, D4W, D4b, pred, 6144, 0);

    // l_recon
    knn(center, NG, 0, 64, pred, 2048, 2048, NBRK, idxa);
    gather_points_kernel<<<(BSZ * 2432 + 255) / 256, 256, 0, stream>>>(pred, 2048, idxa, 64 * NBRK,
                                                                       0, 2432, gatha, BSZ);
    chamfer_min_kernel<<<(BSZ * 2048 + 255) / 256, 256, 0, stream>>>(rebuild0, 2048, gatha, 2432,
                                                                     accum + 0);
    chamfer_min_kernel<<<(BSZ * 2432 + 255) / 256, 256, 0, stream>>>(gatha, 2432, rebuild0, 2048,
                                                                     accum + 1);
    // l_match
    knn(center, NG, 64, 32, pred, 2048, 2048, NBRK, idxb);
    gather_points_kernel<<<(BSZ * 1216 + 255) / 256, 256, 0, stream>>>(pred, 2048, idxb, 32 * NBRK,
                                                                       0, 1216, gathb, BSZ);
    chamfer_min_kernel<<<(BSZ * 1024 + 255) / 256, 256, 0, stream>>>(rebuild1, 1024, gathb, 1216,
                                                                     accum + 2);
    chamfer_min_kernel<<<(BSZ * 1216 + 255) / 256, 256, 0, stream>>>(gathb, 1216, rebuild1, 1024,
                                                                     accum + 3);
    // l_latent
    knn(center, NG, 96, 32, pred, 2048, 2048, 32, idxc);
    gather_points_kernel<<<(BSZ * 1024 + 255) / 256, 256, 0, stream>>>(pred, 2048, idxc, 32 * 32,
                                                                       0, 1024, gathc, BSZ);
    enc(gathc, 1024, featrec);
    latent_kernel<<<(BSZ * 1024 + 255) / 256, 256, 0, stream>>>(feat, featrec, BSZ * 1024,
                                                                accum + 4);
    // l_man: one self-KNN (k=32); manifold uses first 8 (stable top-k prefix)
    knn(pred, 2048, 0, 2048, pred, 2048, 2048, 32, knn32);
    normals_kernel<<<(BSZ * 2048 + 255) / 256, 256, 0, stream>>>(pred, knn32, nrmbuf);
    manifold_kernel<<<(BSZ * 2048 + 255) / 256, 256, 0, stream>>>(nrmbuf, knn32, 32, accum + 5);

    finalize_kernel<<<1, 1, 0, stream>>>(accum, (float*)d_out);
}

// Round 4
// 1774.271 us; speedup vs baseline: 22.3577x; 1.4954x over previous
//
#include <hip/hip_runtime.h>
#include <math.h>

#define BSZ 16
#define NPTS 2048
#define NG 128
#define GS 32
#define NBRK 38

typedef _Float16 f16;
typedef _Float16 f16x8 __attribute__((ext_vector_type(8)));
typedef float f32x4 __attribute__((ext_vector_type(4)));

// ---------- helpers ----------
__device__ __forceinline__ unsigned fkey(float x) {
    unsigned u = __float_as_uint(x);
    return (u >> 31) ? ~u : (u | 0x80000000u);
}
__device__ __forceinline__ float fkey_inv(unsigned k) {
    unsigned u = (k >> 31) ? (k ^ 0x80000000u) : ~k;
    return __uint_as_float(u);
}

// ---------- FPS v2: registers + shuffle reduce ----------
__global__ void fps_kernel(const float* __restrict__ pts, float* __restrict__ center) {
    int b = blockIdx.x;
    const float* P = pts + (size_t)b * NPTS * 3;
    int tid = threadIdx.x;            // 256
    int lane = tid & 63, wave = tid >> 6;
    float px[8], py[8], pz[8], mind[8];
#pragma unroll
    for (int m = 0; m < 8; ++m) {
        int i = tid + 256 * m;        // thread owns {tid + 256m}
        px[m] = P[i * 3 + 0]; py[m] = P[i * 3 + 1]; pz[m] = P[i * 3 + 2];
        mind[m] = 1e10f;
    }
    __shared__ float cw[4];
    __shared__ int   ci[4];
    int far = 0;
    for (int g = 0; g < NG; ++g) {
        float cx = P[far * 3 + 0], cy = P[far * 3 + 1], cz = P[far * 3 + 2];
        if (tid == 0) {
            center[((size_t)b * NG + g) * 3 + 0] = cx;
            center[((size_t)b * NG + g) * 3 + 1] = cy;
            center[((size_t)b * NG + g) * 3 + 2] = cz;
        }
        float best = -1.0f; int bi = 0;
#pragma unroll
        for (int m = 0; m < 8; ++m) {
            float dx = px[m] - cx, dy = py[m] - cy, dz = pz[m] - cz;
            float d = dx * dx + dy * dy + dz * dz;
            float md = fminf(mind[m], d);
            mind[m] = md;
            if (md > best) { best = md; bi = tid + 256 * m; }  // ascending m: first max kept
        }
        // wave reduction: max value, tie -> lower index
#pragma unroll
        for (int s = 1; s < 64; s <<= 1) {
            float ov = __shfl_xor(best, s, 64);
            int   oi = __shfl_xor(bi, s, 64);
            if (ov > best || (ov == best && oi < bi)) { best = ov; bi = oi; }
        }
        if (lane == 0) { cw[wave] = best; ci[wave] = bi; }
        __syncthreads();
        float fb = cw[0]; int fi = ci[0];
#pragma unroll
        for (int w = 1; w < 4; ++w) {
            float ov = cw[w]; int oi = ci[w];
            if (ov > fb || (ov == fb && oi < fi)) { fb = ov; fi = oi; }
        }
        far = fi;
        __syncthreads();
    }
}

// ---------- KNN v3: wave/query, cached per-lane segment minima, no barriers ----------
// Stable top_k semantics: min distance wins, equal distances -> lower index.
// ndb fixed at 2048. LDS row padded every 32 words to break bank collisions.
#define KPAD(j) ((j) + ((j) >> 5))
__global__ void knn_kernel_v3(const float* __restrict__ Q, int q_bstride, int q_off, int nq,
                              const float* __restrict__ DB, int k,
                              int* __restrict__ out, int nbatch) {
    __shared__ float dist[4][NPTS + NPTS / 32];
    int wave = threadIdx.x >> 6;
    int lane = threadIdx.x & 63;
    int qidx = blockIdx.x * 4 + wave;
    if (qidx >= nbatch * nq) return;           // wave-uniform exit; no block barriers used
    float* D = dist[wave];
    int b = qidx / nq, qi = qidx % nq;
    const float* q = Q + ((size_t)b * q_bstride + q_off + qi) * 3;
    float qx = q[0], qy = q[1], qz = q[2];
    float qq = qx * qx + qy * qy + qz * qz;
    const float* db = DB + (size_t)b * NPTS * 3;
    float minv = 3e38f; int mini = 0x7fffffff;
#pragma unroll 4
    for (int m = 0; m < 32; ++m) {
        int j = lane + 64 * m;
        float bx = db[j * 3 + 0], by = db[j * 3 + 1], bz = db[j * 3 + 2];
        float d = qq + bx * bx + by * by + bz * bz - 2.0f * (qx * bx + qy * by + qz * bz);
        D[KPAD(j)] = d;
        if (d < minv) { minv = d; mini = j; }  // ascending m: lowest idx kept on ties
    }
    int* o = out + (size_t)qidx * k;
    for (int r = 0; r < k; ++r) {
        float gv = minv; int gi = mini;
#pragma unroll
        for (int s = 1; s < 64; s <<= 1) {
            float ov = __shfl_xor(gv, s, 64);
            int   oi = __shfl_xor(gi, s, 64);
            if (ov < gv || (ov == gv && oi < gi)) { gv = ov; gi = oi; }
        }
        if (lane == 0) o[r] = gi;
        if (r + 1 == k) break;
        int w = gi & 63;                       // owner lane of extracted element
        if (lane == w) D[KPAD(gi)] = 3e38f;    // invalidate (in-order DS within wave)
        // cooperative rescan of owner's strided set {w + 64m}
        int j2 = w + 64 * (lane & 31);
        float nv = D[KPAD(j2)];
        int ni = j2;
#pragma unroll
        for (int s = 1; s < 32; s <<= 1) {
            float ov = __shfl_xor(nv, s, 64);
            int   oi = __shfl_xor(ni, s, 64);
            if (ov < nv || (ov == nv && oi < ni)) { nv = ov; ni = oi; }
        }
        if (lane == w) { minv = nv; mini = ni; }
    }
}

// ---------- gather points via index array ----------
__global__ void gather_points_kernel(const float* __restrict__ pts, int db_bstride,
                                     const int* __restrict__ idx, int idx_bstride, int idx_off,
                                     int m, float* __restrict__ out, int nbatch) {
    int t = blockIdx.x * blockDim.x + threadIdx.x;
    if (t >= nbatch * m) return;
    int b = t / m, j = t % m;
    int s = idx[(size_t)b * idx_bstride + idx_off + j];
    const float* p = pts + ((size_t)b * db_bstride + s) * 3;
    out[(size_t)t * 3 + 0] = p[0];
    out[(size_t)t * 3 + 1] = p[1];
    out[(size_t)t * 3 + 2] = p[2];
}

// ---------- fp32 -> fp16 weight conversion (strided slice) ----------
__global__ void cvt_w_kernel(const float* __restrict__ in, int ld, int off, int K,
                             f16* __restrict__ out, int total) {
    int t = blockIdx.x * blockDim.x + threadIdx.x;
    if (t >= total) return;
    int n = t / K, k = t % K;
    out[t] = (f16)in[(size_t)n * ld + off + k];
}

// ---------- layer1: H1 = relu(bn(x @ W1^T + b1)) in fp16, fused ----------
__global__ void layer1_kernel(const float* __restrict__ X, const float* __restrict__ W1,
                              const float* __restrict__ b1, const float* __restrict__ g1,
                              const float* __restrict__ be1, const float* __restrict__ m1,
                              const float* __restrict__ v1, f16* __restrict__ H1, int M) {
    __shared__ float w[384], bb[128], sg[128], sb[128], sm[128], sv[128];
    for (int i = threadIdx.x; i < 384; i += 256) w[i] = W1[i];
    if (threadIdx.x < 128) {
        int c = threadIdx.x;
        bb[c] = b1[c]; sg[c] = g1[c]; sb[c] = be1[c]; sm[c] = m1[c]; sv[c] = v1[c];
    }
    __syncthreads();
    int t = blockIdx.x * 256 + threadIdx.x;   // over M*16
    if (t >= M * 16) return;
    int row = t >> 4, cg = (t & 15) * 8;
    float x0 = X[(size_t)row * 3], x1 = X[(size_t)row * 3 + 1], x2 = X[(size_t)row * 3 + 2];
    f16x8 outv;
#pragma unroll
    for (int j = 0; j < 8; ++j) {
        int c = cg + j;
        float tv = x0 * w[c * 3] + x1 * w[c * 3 + 1] + x2 * w[c * 3 + 2] + bb[c];
        float vv = (tv - sm[c]) * rsqrtf(sv[c] + 1e-5f) * sg[c] + sb[c];
        outv[j] = (f16)fmaxf(vv, 0.f);
    }
    *(f16x8*)&H1[(size_t)row * 128 + cg] = outv;
}

// ---------- MFMA GEMM (unchanged from R3) ----------
__global__ __launch_bounds__(256) void mfma_gemm_kernel(
        const f16* __restrict__ A, const f16* __restrict__ W, int K, int N,
        const float* __restrict__ bias, const float* __restrict__ bias2d,
        const float* __restrict__ bng, const float* __restrict__ bnb,
        const float* __restrict__ bnm, const float* __restrict__ bnv,
        f16* __restrict__ Cout, unsigned* __restrict__ maxkey,
        int rows_per_batch, int relu) {
    __shared__ f16 Als[128 * 40];
    __shared__ f16 Bls[128 * 40];
    int tid = threadIdx.x;
    int lane = tid & 63;
    int wave = tid >> 6;
    int wm = wave & 1, wn = wave >> 1;
    int c16 = lane & 15, quad = lane >> 4;
    int row0 = blockIdx.y * 128, col0 = blockIdx.x * 128;
    int sr = tid >> 2;
    int skc = (tid & 3) * 8;

    f32x4 acc[4][4];
#pragma unroll
    for (int i = 0; i < 4; ++i)
#pragma unroll
        for (int j = 0; j < 4; ++j) acc[i][j] = (f32x4){0.f, 0.f, 0.f, 0.f};

    for (int k0 = 0; k0 < K; k0 += 32) {
#pragma unroll
        for (int i = 0; i < 2; ++i) {
            int r2 = sr + i * 64;
            f16x8 av = *(const f16x8*)(A + (size_t)(row0 + r2) * K + k0 + skc);
            *(f16x8*)&Als[r2 * 40 + skc] = av;
            f16x8 bv = *(const f16x8*)(W + (size_t)(col0 + r2) * K + k0 + skc);
            *(f16x8*)&Bls[r2 * 40 + skc] = bv;
        }
        __syncthreads();
        f16x8 af[4], bf[4];
#pragma unroll
        for (int s = 0; s < 4; ++s) {
            af[s] = *(const f16x8*)&Als[(wm * 64 + s * 16 + c16) * 40 + quad * 8];
            bf[s] = *(const f16x8*)&Bls[(wn * 64 + s * 16 + c16) * 40 + quad * 8];
        }
#pragma unroll
        for (int ms = 0; ms < 4; ++ms)
#pragma unroll
            for (int ns = 0; ns < 4; ++ns)
                acc[ms][ns] = __builtin_amdgcn_mfma_f32_16x16x32_f16(af[ms], bf[ns],
                                                                     acc[ms][ns], 0, 0, 0);
        __syncthreads();
    }

    int b = row0 / rows_per_batch;
#pragma unroll
    for (int ns = 0; ns < 4; ++ns) {
        int col = col0 + wn * 64 + ns * 16 + c16;
        float bv = bias ? bias[col] : 0.f;
        float b2v = bias2d ? bias2d[(size_t)b * N + col] : 0.f;
        float mx = -3e38f;
#pragma unroll
        for (int ms = 0; ms < 4; ++ms) {
#pragma unroll
            for (int j = 0; j < 4; ++j) {
                float v = acc[ms][ns][j] + bv + b2v;
                if (bng) v = (v - bnm[col]) * rsqrtf(bnv[col] + 1e-5f) * bng[col] + bnb[col];
                if (relu) v = fmaxf(v, 0.f);
                if (Cout)
                    Cout[(size_t)(row0 + wm * 64 + ms * 16 + quad * 4 + j) * N + col] = (f16)v;
                mx = fmaxf(mx, v);
            }
        }
        if (maxkey) {
            mx = fmaxf(mx, __shfl_xor(mx, 16, 64));
            mx = fmaxf(mx, __shfl_xor(mx, 32, 64));
            if (quad == 0) atomicMax(&maxkey[(size_t)b * N + col], fkey(mx));
        }
    }
}

// ---------- skinny GEMM v2: wave per column, coalesced float4, fused bias/relu ----------
// C[16,N] = A[16,K] @ W[N,K-slice]^T + bias; direct store (no memset/atomics).
__global__ void skinny_v2_kernel(const float* __restrict__ A, const float* __restrict__ W,
                                 int ldw, int woff, const float* __restrict__ bias,
                                 float* __restrict__ C, int K, int N, int relu) {
    int wave = threadIdx.x >> 6, lane = threadIdx.x & 63;
    int col = blockIdx.x * 4 + wave;
    if (col >= N) return;
    const float* w = W + (size_t)col * ldw + woff;
    float acc[16];
#pragma unroll
    for (int m = 0; m < 16; ++m) acc[m] = 0.f;
    for (int k0 = 0; k0 < K; k0 += 256) {
        f32x4 wv = *(const f32x4*)(w + k0 + lane * 4);
#pragma unroll
        for (int m = 0; m < 16; ++m) {
            f32x4 av = *(const f32x4*)(A + (size_t)m * K + k0 + lane * 4);
            acc[m] += av[0] * wv[0] + av[1] * wv[1] + av[2] * wv[2] + av[3] * wv[3];
        }
    }
#pragma unroll
    for (int m = 0; m < 16; ++m)
#pragma unroll
        for (int s = 1; s < 64; s <<= 1) acc[m] += __shfl_xor(acc[m], s, 64);
    if (lane == 0) {
        float bv = bias[col];
#pragma unroll
        for (int m = 0; m < 16; ++m) {
            float v = acc[m] + bv;
            if (relu) v = fmaxf(v, 0.f);
            C[(size_t)m * N + col] = v;
        }
    }
}

__global__ void decode_kernel(const unsigned* __restrict__ k, float* __restrict__ f, int n) {
    int t = blockIdx.x * blockDim.x + threadIdx.x;
    if (t < n) f[t] = fkey_inv(k[t]);
}

// ---------- chamfer one direction ----------
__global__ void chamfer_min_kernel(const float* __restrict__ A, int na,
                                   const float* __restrict__ Bp, int nb,
                                   float* __restrict__ slot) {
    int t = blockIdx.x * blockDim.x + threadIdx.x;
    float val = 0.f;
    if (t < BSZ * na) {
        int b = t / na;
        const float* a = A + (size_t)t * 3;
        float ax = a[0], ay = a[1], az = a[2];
        float aa = ax * ax + ay * ay + az * az;
        const float* Bb = Bp + (size_t)b * nb * 3;
        float m = 3e38f;
        for (int j = 0; j < nb; ++j) {
            float bx = Bb[j * 3 + 0], by = Bb[j * 3 + 1], bz = Bb[j * 3 + 2];
            float d = aa + bx * bx + by * by + bz * bz - 2.0f * (ax * bx + ay * by + az * bz);
            m = fminf(m, d);
        }
        val = sqrtf(fmaxf(m, 1e-12f));
    }
    __shared__ float sdata[256];
    sdata[threadIdx.x] = val;
    __syncthreads();
    for (int s = 128; s > 0; s >>= 1) {
        if (threadIdx.x < s) sdata[threadIdx.x] += sdata[threadIdx.x + s];
        __syncthreads();
    }
    if (threadIdx.x == 0) atomicAdd(slot, sdata[0]);
}

// ---------- smooth-L1 latent loss sum ----------
__global__ void latent_kernel(const float* __restrict__ f1, const float* __restrict__ f2,
                              int n, float* __restrict__ slot) {
    int t = blockIdx.x * blockDim.x + threadIdx.x;
    float val = 0.f;
    if (t < n) {
        float d = f1[t] - f2[t];
        float ad = fabsf(d);
        val = (ad < 1.f) ? (0.5f * d * d) : (ad - 0.5f);
    }
    __shared__ float sdata[256];
    sdata[threadIdx.x] = val;
    __syncthreads();
    for (int s = 128; s > 0; s >>= 1) {
        if (threadIdx.x < s) sdata[threadIdx.x] += sdata[threadIdx.x + s];
        __syncthreads();
    }
    if (threadIdx.x == 0) atomicAdd(slot, sdata[0]);
}

// ---------- 3x3 symmetric smallest eigenvector (double, analytic) ----------
__device__ void smallest_evec(double cxx, double cxy, double cxz,
                              double cyy, double cyz, double czz, double ev[3]) {
    double p1 = cxy * cxy + cxz * cxz + cyz * cyz;
    double q = (cxx + cyy + czz) / 3.0;
    double p2 = (cxx - q) * (cxx - q) + (cyy - q) * (cyy - q) + (czz - q) * (czz - q) + 2.0 * p1;
    double lam = q;
    if (p2 > 0.0) {
        double p = sqrt(p2 / 6.0);
        double b00 = (cxx - q) / p, b11 = (cyy - q) / p, b22 = (czz - q) / p;
        double b01 = cxy / p, b02 = cxz / p, b12 = cyz / p;
        double detB = b00 * (b11 * b22 - b12 * b12) - b01 * (b01 * b22 - b12 * b02)
                    + b02 * (b01 * b12 - b11 * b02);
        double r = detB * 0.5;
        r = r < -1.0 ? -1.0 : (r > 1.0 ? 1.0 : r);
        double phi = acos(r) / 3.0;
        lam = q + 2.0 * p * cos(phi + 2.0943951023931953);
    }
    double r0x = cxx - lam, r0y = cxy, r0z = cxz;
    double r1x = cxy, r1y = cyy - lam, r1z = cyz;
    double r2x = cxz, r2y = cyz, r2z = czz - lam;
    double c0x = r0y * r1z - r0z * r1y, c0y = r0z * r1x - r0x * r1z, c0z = r0x * r1y - r0y * r1x;
    double c1x = r0y * r2z - r0z * r2y, c1y = r0z * r2x - r0x * r2z, c1z = r0x * r2y - r0y * r2x;
    double c2x = r1y * r2z - r1z * r2y, c2y = r1z * r2x - r1x * r2z, c2z = r1x * r2y - r1y * r2x;
    double n0 = c0x * c0x + c0y * c0y + c0z * c0z;
    double n1 = c1x * c1x + c1y * c1y + c1z * c1z;
    double n2 = c2x * c2x + c2y * c2y + c2z * c2z;
    double bx = c0x, by = c0y, bz = c0z, bn = n0;
    if (n1 > bn) { bx = c1x; by = c1y; bz = c1z; bn = n1; }
    if (n2 > bn) { bx = c2x; by = c2y; bz = c2z; bn = n2; }
    if (bn < 1e-280) { ev[0] = 1.0; ev[1] = 0.0; ev[2] = 0.0; return; }
    double inv = 1.0 / sqrt(bn);
    ev[0] = bx * inv; ev[1] = by * inv; ev[2] = bz * inv;
}

// ---------- normals ----------
__global__ void normals_kernel(const float* __restrict__ pred, const int* __restrict__ knn,
                               float* __restrict__ nrm) {
    int t = blockIdx.x * blockDim.x + threadIdx.x;
    if (t >= BSZ * NPTS) return;
    int b = t / NPTS, i = t % NPTS;
    const float* P = pred + (size_t)b * NPTS * 3;
    const int* id = knn + (size_t)t * 32;
    float px[32], py[32], pz[32];
    double sx = 0, sy = 0, sz = 0;
    for (int k = 0; k < 32; ++k) {
        int j = id[k];
        px[k] = P[j * 3 + 0]; py[k] = P[j * 3 + 1]; pz[k] = P[j * 3 + 2];
        sx += px[k]; sy += py[k]; sz += pz[k];
    }
    double mx = sx / 32.0, my = sy / 32.0, mz = sz / 32.0;
    double cxx = 0, cxy = 0, cxz = 0, cyy = 0, cyz = 0, czz = 0;
    for (int k = 0; k < 32; ++k) {
        double dx = px[k] - mx, dy = py[k] - my, dz = pz[k] - mz;
        cxx += dx * dx; cxy += dx * dy; cxz += dx * dz;
        cyy += dy * dy; cyz += dy * dz; czz += dz * dz;
    }
    cxx /= 32.0; cxy /= 32.0; cxz /= 32.0; cyy /= 32.0; cyz /= 32.0; czz /= 32.0;
    double ev[3];
    smallest_evec(cxx, cxy, cxz, cyy, cyz, czz, ev);
    float qx = P[i * 3 + 0], qy = P[i * 3 + 1], qz = P[i * 3 + 2];
    double proj = 0.0;
    for (int k = 0; k < 32; ++k)
        proj += (px[k] - qx) * ev[0] + (py[k] - qy) * ev[1] + (pz[k] - qz) * ev[2];
    double s = (proj >= 0.0) ? 1.0 : -1.0;
    nrm[(size_t)t * 3 + 0] = (float)(ev[0] * s);
    nrm[(size_t)t * 3 + 1] = (float)(ev[1] * s);
    nrm[(size_t)t * 3 + 2] = (float)(ev[2] * s);
}

// ---------- manifold loss: reads first 8 of the 32-NN list ----------
__global__ void manifold_kernel(const float* __restrict__ nrm, const int* __restrict__ knn,
                                int kstride, float* __restrict__ slot) {
    int t = blockIdx.x * blockDim.x + threadIdx.x;
    float val = 0.f;
    if (t < BSZ * NPTS) {
        int b = t / NPTS;
        const float* NB = nrm + (size_t)b * NPTS * 3;
        const int* id = knn + (size_t)t * kstride;
        int j0 = id[0];
        float ax = NB[j0 * 3 + 0], ay = NB[j0 * 3 + 1], az = NB[j0 * 3 + 2];
        float an = fmaxf(sqrtf(ax * ax + ay * ay + az * az), 1e-6f);
        float x[8]; float s = 0.f;
        for (int k = 0; k < 8; ++k) {
            int j = id[k];
            float bx = NB[j * 3 + 0], by = NB[j * 3 + 1], bz = NB[j * 3 + 2];
            float bn_ = fmaxf(sqrtf(bx * bx + by * by + bz * bz), 1e-6f);
            float c = (ax * bx + ay * by + az * bz) / (an * bn_);
            x[k] = 1.f - c; s += x[k];
        }
        float mean = s / 8.f;
        float var = 0.f;
        for (int k = 0; k < 8; ++k) { float d = x[k] - mean; var += d * d; }
        val = sqrtf(var / 7.f);
    }
    __shared__ float sdata[256];
    sdata[threadIdx.x] = val;
    __syncthreads();
    for (int s2 = 128; s2 > 0; s2 >>= 1) {
        if (threadIdx.x < s2) sdata[threadIdx.x] += sdata[threadIdx.x + s2];
        __syncthreads();
    }
    if (threadIdx.x == 0) atomicAdd(slot, sdata[0]);
}

__global__ void finalize_kernel(const float* __restrict__ acc, float* __restrict__ out) {
    float l_recon = 0.5f * (acc[0] / (16.f * 2048.f) + acc[1] / (16.f * 2432.f));
    float l_match = 0.5f * (acc[2] / (16.f * 1024.f) + acc[3] / (16.f * 1216.f));
    float l_latent = acc[4] / (16.f * 1024.f);
    float l_man = 0.1f * (acc[5] / (16.f * 2048.f));
    out[0] = l_recon + l_match + l_latent + l_man;
    out[1] = l_recon;
    out[2] = l_match;
    out[3] = l_latent;
    out[4] = l_man;
}

// ================= host =================
extern "C" void kernel_launch(void* const* d_in, const int* in_sizes, int n_in,
                              void* d_out, int out_size, void* d_ws, size_t ws_size,
                              hipStream_t stream) {
    (void)in_sizes; (void)n_in; (void)out_size; (void)ws_size;
    const float* pts = (const float*)d_in[0];
    const float* W1 = (const float*)d_in[1];
    const float* b1 = (const float*)d_in[2];
    const float* g1 = (const float*)d_in[3];
    const float* be1 = (const float*)d_in[4];
    const float* m1 = (const float*)d_in[5];
    const float* v1 = (const float*)d_in[6];
    const float* W2 = (const float*)d_in[7];
    const float* b2 = (const float*)d_in[8];
    const float* W3 = (const float*)d_in[9];
    const float* b3 = (const float*)d_in[10];
    const float* g2 = (const float*)d_in[11];
    const float* be2 = (const float*)d_in[12];
    const float* m2 = (const float*)d_in[13];
    const float* v2 = (const float*)d_in[14];
    const float* W4 = (const float*)d_in[15];
    const float* b4 = (const float*)d_in[16];
    const float* D1W = (const float*)d_in[17];
    const float* D1b = (const float*)d_in[18];
    const float* D2W = (const float*)d_in[19];
    const float* D2b = (const float*)d_in[20];
    const float* D3W = (const float*)d_in[21];
    const float* D3b = (const float*)d_in[22];
    const float* D4W = (const float*)d_in[23];
    const float* D4b = (const float*)d_in[24];

    char* ws = (char*)d_ws;
    size_t off = 0;
    auto alloc = [&](size_t bytes) -> void* {
        void* p = ws + off;
        off += (bytes + 255) & ~(size_t)255;
        return p;
    };
    float* center   = (float*)alloc((size_t)BSZ * NG * 3 * 4);
    int*   knnc     = (int*)  alloc((size_t)BSZ * NG * GS * 4);
    float* rebuild0 = (float*)alloc((size_t)BSZ * 2048 * 3 * 4);
    float* rebuild1 = (float*)alloc((size_t)BSZ * 1024 * 3 * 4);
    f16*   W2h      = (f16*)  alloc((size_t)256 * 128 * 2);
    f16*   W3h      = (f16*)  alloc((size_t)512 * 256 * 2);
    f16*   W4h      = (f16*)  alloc((size_t)1024 * 512 * 2);
    f16*   H1h      = (f16*)  alloc((size_t)BSZ * 2048 * 128 * 2);
    f16*   H2h      = (f16*)  alloc((size_t)BSZ * 2048 * 256 * 2);
    f16*   H3h      = (f16*)  alloc((size_t)BSZ * 2048 * 512 * 2);
    unsigned* gmaxkey = (unsigned*)alloc((size_t)BSZ * 256 * 4);
    float* gmaxb    = (float*)alloc((size_t)BSZ * 256 * 4);
    float* gpart    = (float*)alloc((size_t)BSZ * 512 * 4);
    unsigned* featkey = (unsigned*)alloc((size_t)BSZ * 1024 * 4);
    float* feat     = (float*)alloc((size_t)BSZ * 1024 * 4);
    float* featrec  = (float*)alloc((size_t)BSZ * 1024 * 4);
    float* dh1      = (float*)alloc((size_t)BSZ * 2048 * 4);
    float* dh2      = (float*)alloc((size_t)BSZ * 2048 * 4);
    float* dh3      = (float*)alloc((size_t)BSZ * 2048 * 4);
    float* pred     = (float*)alloc((size_t)BSZ * 6144 * 4);
    int*   idxa     = (int*)  alloc((size_t)BSZ * 64 * NBRK * 4);
    float* gatha    = (float*)alloc((size_t)BSZ * 64 * NBRK * 3 * 4);
    int*   idxb     = (int*)  alloc((size_t)BSZ * 32 * NBRK * 4);
    float* gathb    = (float*)alloc((size_t)BSZ * 32 * NBRK * 3 * 4);
    int*   idxc     = (int*)  alloc((size_t)BSZ * 32 * 32 * 4);
    float* gathc    = (float*)alloc((size_t)BSZ * 1024 * 3 * 4);
    int*   knn32    = (int*)  alloc((size_t)BSZ * 2048 * 32 * 4);
    float* nrmbuf   = (float*)alloc((size_t)BSZ * 2048 * 3 * 4);
    float* accum    = (float*)alloc(8 * 4);

    hipMemsetAsync(accum, 0, 8 * 4, stream);

    // one-time (per launch) weight conversions to fp16
    cvt_w_kernel<<<(256 * 128 + 255) / 256, 256, 0, stream>>>(W2, 128, 0, 128, W2h, 256 * 128);
    cvt_w_kernel<<<(512 * 256 + 255) / 256, 256, 0, stream>>>(W3, 512, 256, 256, W3h, 512 * 256);
    cvt_w_kernel<<<(1024 * 512 + 255) / 256, 256, 0, stream>>>(W4, 512, 0, 512, W4h, 1024 * 512);

    auto knn = [&](const float* Q, int q_bstride, int q_off, int nq,
                   const float* DB, int k, int* out) {
        int total = BSZ * nq;
        knn_kernel_v3<<<(total + 3) / 4, 256, 0, stream>>>(Q, q_bstride, q_off, nq,
                                                           DB, k, out, BSZ);
    };

    // FPS + grouping
    fps_kernel<<<BSZ, 256, 0, stream>>>(pts, center);
    knn(center, NG, 0, NG, pts, GS, knnc);
    gather_points_kernel<<<(BSZ * 2048 + 255) / 256, 256, 0, stream>>>(pts, NPTS, knnc, NG * GS,
                                                                       0, 2048, rebuild0, BSZ);
    gather_points_kernel<<<(BSZ * 1024 + 255) / 256, 256, 0, stream>>>(pts, NPTS, knnc, NG * GS,
                                                                       2048, 1024, rebuild1, BSZ);

    auto enc = [&](const float* X, int n, float* featout) {
        int M = BSZ * n;
        layer1_kernel<<<M / 16, 256, 0, stream>>>(X, W1, b1, g1, be1, m1, v1, H1h, M);
        hipMemsetAsync(gmaxkey, 0, (size_t)BSZ * 256 * 4, stream);
        mfma_gemm_kernel<<<dim3(256 / 128, M / 128), 256, 0, stream>>>(
            H1h, W2h, 128, 256, b2, nullptr, nullptr, nullptr, nullptr, nullptr,
            H2h, gmaxkey, n, 0);
        decode_kernel<<<(BSZ * 256 + 255) / 256, 256, 0, stream>>>(gmaxkey, gmaxb, BSZ * 256);
        // gpart = gmax @ W3[:, :256]^T + b3
        skinny_v2_kernel<<<(512 + 3) / 4, 256, 0, stream>>>(gmaxb, W3, 512, 0, b3,
                                                            gpart, 256, 512, 0);
        mfma_gemm_kernel<<<dim3(512 / 128, M / 128), 256, 0, stream>>>(
            H2h, W3h, 256, 512, nullptr, gpart, g2, be2, m2, v2, H3h, nullptr, n, 1);
        hipMemsetAsync(featkey, 0, (size_t)BSZ * 1024 * 4, stream);
        mfma_gemm_kernel<<<dim3(1024 / 128, M / 128), 256, 0, stream>>>(
            H3h, W4h, 512, 1024, b4, nullptr, nullptr, nullptr, nullptr, nullptr,
            nullptr, featkey, n, 0);
        decode_kernel<<<(BSZ * 1024 + 255) / 256, 256, 0, stream>>>(featkey, featout, BSZ * 1024);
    };

    enc(rebuild0, 2048, feat);

    // decoder (skinny M=16, fp32, coalesced)
    skinny_v2_kernel<<<2048 / 4, 256, 0, stream>>>(feat, D1W, 1024, 0, D1b, dh1, 1024, 2048, 1);
    skinny_v2_kernel<<<2048 / 4, 256, 0, stream>>>(dh1, D2W, 2048, 0, D2b, dh2, 2048, 2048, 1);
    skinny_v2_kernel<<<2048 / 4, 256, 0, stream>>>(dh2, D3W, 2048, 0, D3b, dh3, 2048, 2048, 1);
    skinny_v2_kernel<<<6144 / 4, 256, 0, stream>>>(dh3, D4W, 2048, 0, D4b, pred, 2048, 6144, 0);

    // l_recon
    knn(center, NG, 0, 64, pred, NBRK, idxa);
    gather_points_kernel<<<(BSZ * 2432 + 255) / 256, 256, 0, stream>>>(pred, 2048, idxa, 64 * NBRK,
                                                                       0, 2432, gatha, BSZ);
    chamfer_min_kernel<<<(BSZ * 2048 + 255) / 256, 256, 0, stream>>>(rebuild0, 2048, gatha, 2432,
                                                                     accum + 0);
    chamfer_min_kernel<<<(BSZ * 2432 + 255) / 256, 256, 0, stream>>>(gatha, 2432, rebuild0, 2048,
                                                                     accum + 1);
    // l_match
    knn(center, NG, 64, 32, pred, NBRK, idxb);
    gather_points_kernel<<<(BSZ * 1216 + 255) / 256, 256, 0, stream>>>(pred, 2048, idxb, 32 * NBRK,
                                                                       0, 1216, gathb, BSZ);
    chamfer_min_kernel<<<(BSZ * 1024 + 255) / 256, 256, 0, stream>>>(rebuild1, 1024, gathb, 1216,
                                                                     accum + 2);
    chamfer_min_kernel<<<(BSZ * 1216 + 255) / 256, 256, 0, stream>>>(gathb, 1216, rebuild1, 1024,
                                                                     accum + 3);
    // l_latent
    knn(center, NG, 96, 32, pred, 32, idxc);
    gather_points_kernel<<<(BSZ * 1024 + 255) / 256, 256, 0, stream>>>(pred, 2048, idxc, 32 * 32,
                                                                       0, 1024, gathc, BSZ);
    enc(gathc, 1024, featrec);
    latent_kernel<<<(BSZ * 1024 + 255) / 256, 256, 0, stream>>>(feat, featrec, BSZ * 1024,
                                                                accum + 4);
    // l_man: one self-KNN (k=32); manifold uses first 8 (stable top-k prefix)
    knn(pred, 2048, 0, 2048, pred, 32, knn32);
    normals_kernel<<<(BSZ * 2048 + 255) / 256, 256, 0, stream>>>(pred, knn32, nrmbuf);
    manifold_kernel<<<(BSZ * 2048 + 255) / 256, 256, 0, stream>>>(nrmbuf, knn32, 32, accum + 5);

    finalize_kernel<<<1, 1, 0, stream>>>(accum, (float*)d_out);
}

// Round 5
// 1435.818 us; speedup vs baseline: 27.6279x; 1.2357x over previous
//
#include <hip/hip_runtime.h>
#include <math.h>

#define BSZ 16
#define NPTS 2048
#define NG 128
#define GS 32
#define NBRK 38

typedef _Float16 f16;
typedef _Float16 f16x8 __attribute__((ext_vector_type(8)));
typedef float f32x4 __attribute__((ext_vector_type(4)));

// ---------- helpers ----------
__device__ __forceinline__ unsigned fkey(float x) {
    unsigned u = __float_as_uint(x);
    return (u >> 31) ? ~u : (u | 0x80000000u);
}
__device__ __forceinline__ float fkey_inv(unsigned k) {
    unsigned u = (k >> 31) ? (k ^ 0x80000000u) : ~k;
    return __uint_as_float(u);
}

// ---------- FPS v2: registers + shuffle reduce ----------
__global__ void fps_kernel(const float* __restrict__ pts, float* __restrict__ center) {
    int b = blockIdx.x;
    const float* P = pts + (size_t)b * NPTS * 3;
    int tid = threadIdx.x;            // 256
    int lane = tid & 63, wave = tid >> 6;
    float px[8], py[8], pz[8], mind[8];
#pragma unroll
    for (int m = 0; m < 8; ++m) {
        int i = tid + 256 * m;
        px[m] = P[i * 3 + 0]; py[m] = P[i * 3 + 1]; pz[m] = P[i * 3 + 2];
        mind[m] = 1e10f;
    }
    __shared__ float cw[4];
    __shared__ int   ci[4];
    int far = 0;
    for (int g = 0; g < NG; ++g) {
        float cx = P[far * 3 + 0], cy = P[far * 3 + 1], cz = P[far * 3 + 2];
        if (tid == 0) {
            center[((size_t)b * NG + g) * 3 + 0] = cx;
            center[((size_t)b * NG + g) * 3 + 1] = cy;
            center[((size_t)b * NG + g) * 3 + 2] = cz;
        }
        float best = -1.0f; int bi = 0;
#pragma unroll
        for (int m = 0; m < 8; ++m) {
            float dx = px[m] - cx, dy = py[m] - cy, dz = pz[m] - cz;
            float d = dx * dx + dy * dy + dz * dz;
            float md = fminf(mind[m], d);
            mind[m] = md;
            if (md > best) { best = md; bi = tid + 256 * m; }
        }
#pragma unroll
        for (int s = 1; s < 64; s <<= 1) {
            float ov = __shfl_xor(best, s, 64);
            int   oi = __shfl_xor(bi, s, 64);
            if (ov > best || (ov == best && oi < bi)) { best = ov; bi = oi; }
        }
        if (lane == 0) { cw[wave] = best; ci[wave] = bi; }
        __syncthreads();
        float fb = cw[0]; int fi = ci[0];
#pragma unroll
        for (int w = 1; w < 4; ++w) {
            float ov = cw[w]; int oi = ci[w];
            if (ov > fb || (ov == fb && oi < fi)) { fb = ov; fi = oi; }
        }
        far = fi;
        __syncthreads();
    }
}

// ---------- KNN v4: register-resident, LDS-free, lazy refill ----------
// Stable top_k semantics: min distance wins, equal distances -> lower index.
// ndb fixed at NPTS=2048 (32 candidates per lane). Wave per query.
// Each lane: d[32] in VGPRs + sorted top-2 (c0,c1) + watermark of last pop.
// Round: butterfly argmin over lanes' c0; owner pops c0<-c1. Lane refills
// (lex-min above watermark over its 32 regs) only when its list empties.
__global__ void knn_kernel_v4(const float* __restrict__ Q, int q_bstride, int q_off, int nq,
                              const float* __restrict__ DB, int k,
                              int* __restrict__ out, int nbatch) {
    const float INF = 3e38f;
    int wave = threadIdx.x >> 6, lane = threadIdx.x & 63;
    int qidx = blockIdx.x * 4 + wave;
    if (qidx >= nbatch * nq) return;     // wave-uniform, no barriers in kernel
    int b = qidx / nq, qi = qidx % nq;
    const float* q = Q + ((size_t)b * q_bstride + q_off + qi) * 3;
    float qx = q[0], qy = q[1], qz = q[2];
    float qq = qx * qx + qy * qy + qz * qz;
    const float* db = DB + (size_t)b * NPTS * 3;

    float d[32];
    float c0v = INF, c1v = INF;
    int c0s = 0, c1s = 0;
#pragma unroll
    for (int m = 0; m < 32; ++m) {
        int j = lane + (m << 6);
        float bx = db[j * 3 + 0], by = db[j * 3 + 1], bz = db[j * 3 + 2];
        float dv = qq + bx * bx + by * by + bz * bz - 2.0f * (qx * bx + qy * by + qz * bz);
        d[m] = dv;
        if (dv < c1v) {                  // strict <: ties keep earlier (lower index)
            if (dv < c0v) { c1v = c0v; c1s = c0s; c0v = dv; c0s = m; }
            else          { c1v = dv; c1s = m; }
        }
    }

    float wv = -INF; int wslot = -1;     // watermark: last popped (value, slot) this lane
    int npop = 0;
    int* o = out + (size_t)qidx * k;

    for (int r = 0; r < k; ++r) {
        bool need = (c0v >= 1e37f) && (npop < 32);
        if (__any(need)) {
            // lex-min over d[] with (d,slot) > (wv,wslot); adjacency tree so
            // strict < prefers lower slot (=lower global index) on ties.
            float tv[16]; int ts[16];
#pragma unroll
            for (int m = 0; m < 16; ++m) {
                float a0 = d[2 * m];
                float a1 = d[2 * m + 1];
                bool q0 = (a0 > wv) || (a0 == wv && (2 * m)     > wslot);
                bool q1 = (a1 > wv) || (a1 == wv && (2 * m + 1) > wslot);
                a0 = q0 ? a0 : INF;
                a1 = q1 ? a1 : INF;
                bool t = a1 < a0;
                tv[m] = t ? a1 : a0;
                ts[m] = t ? 2 * m + 1 : 2 * m;
            }
#pragma unroll
            for (int h = 8; h >= 1; h >>= 1)
#pragma unroll
                for (int m = 0; m < h; ++m) {
                    bool t = tv[2 * m + 1] < tv[2 * m];
                    tv[m] = t ? tv[2 * m + 1] : tv[2 * m];
                    ts[m] = t ? ts[2 * m + 1] : ts[2 * m];
                }
            if (need) { c0v = tv[0]; c0s = ts[0]; }
        }
        float gv = c0v;
        int gi = lane + (c0s << 6);      // global db index
#pragma unroll
        for (int s = 1; s < 64; s <<= 1) {
            float ov = __shfl_xor(gv, s, 64);
            int   oi = __shfl_xor(gi, s, 64);
            if (ov < gv || (ov == gv && oi < gi)) { gv = ov; gi = oi; }
        }
        if (lane == 0) o[r] = gi;
        bool own = ((gi & 63) == lane);
        if (own) {
            wv = c0v; wslot = c0s;
            c0v = c1v; c0s = c1s;
            c1v = INF;
            ++npop;
        }
    }
}

// ---------- gather points via index array ----------
__global__ void gather_points_kernel(const float* __restrict__ pts, int db_bstride,
                                     const int* __restrict__ idx, int idx_bstride, int idx_off,
                                     int m, float* __restrict__ out, int nbatch) {
    int t = blockIdx.x * blockDim.x + threadIdx.x;
    if (t >= nbatch * m) return;
    int b = t / m, j = t % m;
    int s = idx[(size_t)b * idx_bstride + idx_off + j];
    const float* p = pts + ((size_t)b * db_bstride + s) * 3;
    out[(size_t)t * 3 + 0] = p[0];
    out[(size_t)t * 3 + 1] = p[1];
    out[(size_t)t * 3 + 2] = p[2];
}

// ---------- fp32 -> fp16 weight conversion (strided slice) ----------
__global__ void cvt_w_kernel(const float* __restrict__ in, int ld, int off, int K,
                             f16* __restrict__ out, int total) {
    int t = blockIdx.x * blockDim.x + threadIdx.x;
    if (t >= total) return;
    int n = t / K, k = t % K;
    out[t] = (f16)in[(size_t)n * ld + off + k];
}

// ---------- layer1: H1 = relu(bn(x @ W1^T + b1)) in fp16, fused ----------
__global__ void layer1_kernel(const float* __restrict__ X, const float* __restrict__ W1,
                              const float* __restrict__ b1, const float* __restrict__ g1,
                              const float* __restrict__ be1, const float* __restrict__ m1,
                              const float* __restrict__ v1, f16* __restrict__ H1, int M) {
    __shared__ float w[384], bb[128], sg[128], sb[128], sm[128], sv[128];
    for (int i = threadIdx.x; i < 384; i += 256) w[i] = W1[i];
    if (threadIdx.x < 128) {
        int c = threadIdx.x;
        bb[c] = b1[c]; sg[c] = g1[c]; sb[c] = be1[c]; sm[c] = m1[c]; sv[c] = v1[c];
    }
    __syncthreads();
    int t = blockIdx.x * 256 + threadIdx.x;
    if (t >= M * 16) return;
    int row = t >> 4, cg = (t & 15) * 8;
    float x0 = X[(size_t)row * 3], x1 = X[(size_t)row * 3 + 1], x2 = X[(size_t)row * 3 + 2];
    f16x8 outv;
#pragma unroll
    for (int j = 0; j < 8; ++j) {
        int c = cg + j;
        float tv = x0 * w[c * 3] + x1 * w[c * 3 + 1] + x2 * w[c * 3 + 2] + bb[c];
        float vv = (tv - sm[c]) * rsqrtf(sv[c] + 1e-5f) * sg[c] + sb[c];
        outv[j] = (f16)fmaxf(vv, 0.f);
    }
    *(f16x8*)&H1[(size_t)row * 128 + cg] = outv;
}

// ---------- MFMA GEMM ----------
__global__ __launch_bounds__(256) void mfma_gemm_kernel(
        const f16* __restrict__ A, const f16* __restrict__ W, int K, int N,
        const float* __restrict__ bias, const float* __restrict__ bias2d,
        const float* __restrict__ bng, const float* __restrict__ bnb,
        const float* __restrict__ bnm, const float* __restrict__ bnv,
        f16* __restrict__ Cout, unsigned* __restrict__ maxkey,
        int rows_per_batch, int relu) {
    __shared__ f16 Als[128 * 40];
    __shared__ f16 Bls[128 * 40];
    int tid = threadIdx.x;
    int lane = tid & 63;
    int wave = tid >> 6;
    int wm = wave & 1, wn = wave >> 1;
    int c16 = lane & 15, quad = lane >> 4;
    int row0 = blockIdx.y * 128, col0 = blockIdx.x * 128;
    int sr = tid >> 2;
    int skc = (tid & 3) * 8;

    f32x4 acc[4][4];
#pragma unroll
    for (int i = 0; i < 4; ++i)
#pragma unroll
        for (int j = 0; j < 4; ++j) acc[i][j] = (f32x4){0.f, 0.f, 0.f, 0.f};

    for (int k0 = 0; k0 < K; k0 += 32) {
#pragma unroll
        for (int i = 0; i < 2; ++i) {
            int r2 = sr + i * 64;
            f16x8 av = *(const f16x8*)(A + (size_t)(row0 + r2) * K + k0 + skc);
            *(f16x8*)&Als[r2 * 40 + skc] = av;
            f16x8 bv = *(const f16x8*)(W + (size_t)(col0 + r2) * K + k0 + skc);
            *(f16x8*)&Bls[r2 * 40 + skc] = bv;
        }
        __syncthreads();
        f16x8 af[4], bf[4];
#pragma unroll
        for (int s = 0; s < 4; ++s) {
            af[s] = *(const f16x8*)&Als[(wm * 64 + s * 16 + c16) * 40 + quad * 8];
            bf[s] = *(const f16x8*)&Bls[(wn * 64 + s * 16 + c16) * 40 + quad * 8];
        }
#pragma unroll
        for (int ms = 0; ms < 4; ++ms)
#pragma unroll
            for (int ns = 0; ns < 4; ++ns)
                acc[ms][ns] = __builtin_amdgcn_mfma_f32_16x16x32_f16(af[ms], bf[ns],
                                                                     acc[ms][ns], 0, 0, 0);
        __syncthreads();
    }

    int b = row0 / rows_per_batch;
#pragma unroll
    for (int ns = 0; ns < 4; ++ns) {
        int col = col0 + wn * 64 + ns * 16 + c16;
        float bv = bias ? bias[col] : 0.f;
        float b2v = bias2d ? bias2d[(size_t)b * N + col] : 0.f;
        float mx = -3e38f;
#pragma unroll
        for (int ms = 0; ms < 4; ++ms) {
#pragma unroll
            for (int j = 0; j < 4; ++j) {
                float v = acc[ms][ns][j] + bv + b2v;
                if (bng) v = (v - bnm[col]) * rsqrtf(bnv[col] + 1e-5f) * bng[col] + bnb[col];
                if (relu) v = fmaxf(v, 0.f);
                if (Cout)
                    Cout[(size_t)(row0 + wm * 64 + ms * 16 + quad * 4 + j) * N + col] = (f16)v;
                mx = fmaxf(mx, v);
            }
        }
        if (maxkey) {
            mx = fmaxf(mx, __shfl_xor(mx, 16, 64));
            mx = fmaxf(mx, __shfl_xor(mx, 32, 64));
            if (quad == 0) atomicMax(&maxkey[(size_t)b * N + col], fkey(mx));
        }
    }
}

// ---------- skinny GEMM v2: wave per column, coalesced float4 ----------
__global__ void skinny_v2_kernel(const float* __restrict__ A, const float* __restrict__ W,
                                 int ldw, int woff, const float* __restrict__ bias,
                                 float* __restrict__ C, int K, int N, int relu) {
    int wave = threadIdx.x >> 6, lane = threadIdx.x & 63;
    int col = blockIdx.x * 4 + wave;
    if (col >= N) return;
    const float* w = W + (size_t)col * ldw + woff;
    float acc[16];
#pragma unroll
    for (int m = 0; m < 16; ++m) acc[m] = 0.f;
    for (int k0 = 0; k0 < K; k0 += 256) {
        f32x4 wv = *(const f32x4*)(w + k0 + lane * 4);
#pragma unroll
        for (int m = 0; m < 16; ++m) {
            f32x4 av = *(const f32x4*)(A + (size_t)m * K + k0 + lane * 4);
            acc[m] += av[0] * wv[0] + av[1] * wv[1] + av[2] * wv[2] + av[3] * wv[3];
        }
    }
#pragma unroll
    for (int m = 0; m < 16; ++m)
#pragma unroll
        for (int s = 1; s < 64; s <<= 1) acc[m] += __shfl_xor(acc[m], s, 64);
    if (lane == 0) {
        float bv = bias[col];
#pragma unroll
        for (int m = 0; m < 16; ++m) {
            float v = acc[m] + bv;
            if (relu) v = fmaxf(v, 0.f);
            C[(size_t)m * N + col] = v;
        }
    }
}

__global__ void decode_kernel(const unsigned* __restrict__ k, float* __restrict__ f, int n) {
    int t = blockIdx.x * blockDim.x + threadIdx.x;
    if (t < n) f[t] = fkey_inv(k[t]);
}

// ---------- chamfer v2: 8 lanes per A-point, j-strided, shfl-min ----------
__global__ void chamfer_min_kernel(const float* __restrict__ A, int na,
                                   const float* __restrict__ Bp, int nb,
                                   float* __restrict__ slot) {
    int t = blockIdx.x * 256 + threadIdx.x;
    int pt = t >> 3, sl = t & 7;
    float val = 0.f;
    if (pt < BSZ * na) {
        int b = pt / na;
        const float* a = A + (size_t)pt * 3;
        float ax = a[0], ay = a[1], az = a[2];
        float aa = ax * ax + ay * ay + az * az;
        const float* Bb = Bp + (size_t)b * nb * 3;
        float m = 3e38f;
        for (int j = sl; j < nb; j += 8) {
            float bx = Bb[j * 3 + 0], by = Bb[j * 3 + 1], bz = Bb[j * 3 + 2];
            float d = aa + bx * bx + by * by + bz * bz - 2.0f * (ax * bx + ay * by + az * bz);
            m = fminf(m, d);
        }
#pragma unroll
        for (int s = 1; s < 8; s <<= 1) m = fminf(m, __shfl_xor(m, s, 64));
        if (sl == 0) val = sqrtf(fmaxf(m, 1e-12f));
    }
    __shared__ float sdata[256];
    sdata[threadIdx.x] = val;
    __syncthreads();
    for (int s = 128; s > 0; s >>= 1) {
        if (threadIdx.x < s) sdata[threadIdx.x] += sdata[threadIdx.x + s];
        __syncthreads();
    }
    if (threadIdx.x == 0) atomicAdd(slot, sdata[0]);
}

// ---------- smooth-L1 latent loss sum ----------
__global__ void latent_kernel(const float* __restrict__ f1, const float* __restrict__ f2,
                              int n, float* __restrict__ slot) {
    int t = blockIdx.x * blockDim.x + threadIdx.x;
    float val = 0.f;
    if (t < n) {
        float d = f1[t] - f2[t];
        float ad = fabsf(d);
        val = (ad < 1.f) ? (0.5f * d * d) : (ad - 0.5f);
    }
    __shared__ float sdata[256];
    sdata[threadIdx.x] = val;
    __syncthreads();
    for (int s = 128; s > 0; s >>= 1) {
        if (threadIdx.x < s) sdata[threadIdx.x] += sdata[threadIdx.x + s];
        __syncthreads();
    }
    if (threadIdx.x == 0) atomicAdd(slot, sdata[0]);
}

// ---------- 3x3 symmetric smallest eigenvector (double, analytic) ----------
__device__ void smallest_evec(double cxx, double cxy, double cxz,
                              double cyy, double cyz, double czz, double ev[3]) {
    double p1 = cxy * cxy + cxz * cxz + cyz * cyz;
    double q = (cxx + cyy + czz) / 3.0;
    double p2 = (cxx - q) * (cxx - q) + (cyy - q) * (cyy - q) + (czz - q) * (czz - q) + 2.0 * p1;
    double lam = q;
    if (p2 > 0.0) {
        double p = sqrt(p2 / 6.0);
        double b00 = (cxx - q) / p, b11 = (cyy - q) / p, b22 = (czz - q) / p;
        double b01 = cxy / p, b02 = cxz / p, b12 = cyz / p;
        double detB = b00 * (b11 * b22 - b12 * b12) - b01 * (b01 * b22 - b12 * b02)
                    + b02 * (b01 * b12 - b11 * b02);
        double r = detB * 0.5;
        r = r < -1.0 ? -1.0 : (r > 1.0 ? 1.0 : r);
        double phi = acos(r) / 3.0;
        lam = q + 2.0 * p * cos(phi + 2.0943951023931953);
    }
    double r0x = cxx - lam, r0y = cxy, r0z = cxz;
    double r1x = cxy, r1y = cyy - lam, r1z = cyz;
    double r2x = cxz, r2y = cyz, r2z = czz - lam;
    double c0x = r0y * r1z - r0z * r1y, c0y = r0z * r1x - r0x * r1z, c0z = r0x * r1y - r0y * r1x;
    double c1x = r0y * r2z - r0z * r2y, c1y = r0z * r2x - r0x * r2z, c1z = r0x * r2y - r0y * r2x;
    double c2x = r1y * r2z - r1z * r2y, c2y = r1z * r2x - r1x * r2z, c2z = r1x * r2y - r1y * r2x;
    double n0 = c0x * c0x + c0y * c0y + c0z * c0z;
    double n1 = c1x * c1x + c1y * c1y + c1z * c1z;
    double n2 = c2x * c2x + c2y * c2y + c2z * c2z;
    double bx = c0x, by = c0y, bz = c0z, bn = n0;
    if (n1 > bn) { bx = c1x; by = c1y; bz = c1z; bn = n1; }
    if (n2 > bn) { bx = c2x; by = c2y; bz = c2z; bn = n2; }
    if (bn < 1e-280) { ev[0] = 1.0; ev[1] = 0.0; ev[2] = 0.0; return; }
    double inv = 1.0 / sqrt(bn);
    ev[0] = bx * inv; ev[1] = by * inv; ev[2] = bz * inv;
}

// ---------- normals ----------
__global__ void normals_kernel(const float* __restrict__ pred, const int* __restrict__ knn,
                               float* __restrict__ nrm) {
    int t = blockIdx.x * blockDim.x + threadIdx.x;
    if (t >= BSZ * NPTS) return;
    int b = t / NPTS, i = t % NPTS;
    const float* P = pred + (size_t)b * NPTS * 3;
    const int* id = knn + (size_t)t * 32;
    float px[32], py[32], pz[32];
    double sx = 0, sy = 0, sz = 0;
    for (int k = 0; k < 32; ++k) {
        int j = id[k];
        px[k] = P[j * 3 + 0]; py[k] = P[j * 3 + 1]; pz[k] = P[j * 3 + 2];
        sx += px[k]; sy += py[k]; sz += pz[k];
    }
    double mx = sx / 32.0, my = sy / 32.0, mz = sz / 32.0;
    double cxx = 0, cxy = 0, cxz = 0, cyy = 0, cyz = 0, czz = 0;
    for (int k = 0; k < 32; ++k) {
        double dx = px[k] - mx, dy = py[k] - my, dz = pz[k] - mz;
        cxx += dx * dx; cxy += dx * dy; cxz += dx * dz;
        cyy += dy * dy; cyz += dy * dz; czz += dz * dz;
    }
    cxx /= 32.0; cxy /= 32.0; cxz /= 32.0; cyy /= 32.0; cyz /= 32.0; czz /= 32.0;
    double ev[3];
    smallest_evec(cxx, cxy, cxz, cyy, cyz, czz, ev);
    float qx = P[i * 3 + 0], qy = P[i * 3 + 1], qz = P[i * 3 + 2];
    double proj = 0.0;
    for (int k = 0; k < 32; ++k)
        proj += (px[k] - qx) * ev[0] + (py[k] - qy) * ev[1] + (pz[k] - qz) * ev[2];
    double s = (proj >= 0.0) ? 1.0 : -1.0;
    nrm[(size_t)t * 3 + 0] = (float)(ev[0] * s);
    nrm[(size_t)t * 3 + 1] = (float)(ev[1] * s);
    nrm[(size_t)t * 3 + 2] = (float)(ev[2] * s);
}

// ---------- manifold loss: reads first 8 of the 32-NN list ----------
__global__ void manifold_kernel(const float* __restrict__ nrm, const int* __restrict__ knn,
                                int kstride, float* __restrict__ slot) {
    int t = blockIdx.x * blockDim.x + threadIdx.x;
    float val = 0.f;
    if (t < BSZ * NPTS) {
        int b = t / NPTS;
        const float* NB = nrm + (size_t)b * NPTS * 3;
        const int* id = knn + (size_t)t * kstride;
        int j0 = id[0];
        float ax = NB[j0 * 3 + 0], ay = NB[j0 * 3 + 1], az = NB[j0 * 3 + 2];
        float an = fmaxf(sqrtf(ax * ax + ay * ay + az * az), 1e-6f);
        float x[8]; float s = 0.f;
        for (int k = 0; k < 8; ++k) {
            int j = id[k];
            float bx = NB[j * 3 + 0], by = NB[j * 3 + 1], bz = NB[j * 3 + 2];
            float bn_ = fmaxf(sqrtf(bx * bx + by * by + bz * bz), 1e-6f);
            float c = (ax * bx + ay * by + az * bz) / (an * bn_);
            x[k] = 1.f - c; s += x[k];
        }
        float mean = s / 8.f;
        float var = 0.f;
        for (int k = 0; k < 8; ++k) { float d = x[k] - mean; var += d * d; }
        val = sqrtf(var / 7.f);
    }
    __shared__ float sdata[256];
    sdata[threadIdx.x] = val;
    __syncthreads();
    for (int s2 = 128; s2 > 0; s2 >>= 1) {
        if (threadIdx.x < s2) sdata[threadIdx.x] += sdata[threadIdx.x + s2];
        __syncthreads();
    }
    if (threadIdx.x == 0) atomicAdd(slot, sdata[0]);
}

__global__ void finalize_kernel(const float* __restrict__ acc, float* __restrict__ out) {
    float l_recon = 0.5f * (acc[0] / (16.f * 2048.f) + acc[1] / (16.f * 2432.f));
    float l_match = 0.5f * (acc[2] / (16.f * 1024.f) + acc[3] / (16.f * 1216.f));
    float l_latent = acc[4] / (16.f * 1024.f);
    float l_man = 0.1f * (acc[5] / (16.f * 2048.f));
    out[0] = l_recon + l_match + l_latent + l_man;
    out[1] = l_recon;
    out[2] = l_match;
    out[3] = l_latent;
    out[4] = l_man;
}

// ================= host =================
extern "C" void kernel_launch(void* const* d_in, const int* in_sizes, int n_in,
                              void* d_out, int out_size, void* d_ws, size_t ws_size,
                              hipStream_t stream) {
    (void)in_sizes; (void)n_in; (void)out_size; (void)ws_size;
    const float* pts = (const float*)d_in[0];
    const float* W1 = (const float*)d_in[1];
    const float* b1 = (const float*)d_in[2];
    const float* g1 = (const float*)d_in[3];
    const float* be1 = (const float*)d_in[4];
    const float* m1 = (const float*)d_in[5];
    const float* v1 = (const float*)d_in[6];
    const float* W2 = (const float*)d_in[7];
    const float* b2 = (const float*)d_in[8];
    const float* W3 = (const float*)d_in[9];
    const float* b3 = (const float*)d_in[10];
    const float* g2 = (const float*)d_in[11];
    const float* be2 = (const float*)d_in[12];
    const float* m2 = (const float*)d_in[13];
    const float* v2 = (const float*)d_in[14];
    const float* W4 = (const float*)d_in[15];
    const float* b4 = (const float*)d_in[16];
    const float* D1W = (const float*)d_in[17];
    const float* D1b = (const float*)d_in[18];
    const float* D2W = (const float*)d_in[19];
    const float* D2b = (const float*)d_in[20];
    const float* D3W = (const float*)d_in[21];
    const float* D3b = (const float*)d_in[22];
    const float* D4W = (const float*)d_in[23];
    const float* D4b = (const float*)d_in[24];

    char* ws = (char*)d_ws;
    size_t off = 0;
    auto alloc = [&](size_t bytes) -> void* {
        void* p = ws + off;
        off += (bytes + 255) & ~(size_t)255;
        return p;
    };
    float* center   = (float*)alloc((size_t)BSZ * NG * 3 * 4);
    int*   knnc     = (int*)  alloc((size_t)BSZ * NG * GS * 4);
    float* rebuild0 = (float*)alloc((size_t)BSZ * 2048 * 3 * 4);
    float* rebuild1 = (float*)alloc((size_t)BSZ * 1024 * 3 * 4);
    f16*   W2h      = (f16*)  alloc((size_t)256 * 128 * 2);
    f16*   W3h      = (f16*)  alloc((size_t)512 * 256 * 2);
    f16*   W4h      = (f16*)  alloc((size_t)1024 * 512 * 2);
    f16*   H1h      = (f16*)  alloc((size_t)BSZ * 2048 * 128 * 2);
    f16*   H2h      = (f16*)  alloc((size_t)BSZ * 2048 * 256 * 2);
    f16*   H3h      = (f16*)  alloc((size_t)BSZ * 2048 * 512 * 2);
    unsigned* gmaxkey = (unsigned*)alloc((size_t)BSZ * 256 * 4);
    float* gmaxb    = (float*)alloc((size_t)BSZ * 256 * 4);
    float* gpart    = (float*)alloc((size_t)BSZ * 512 * 4);
    unsigned* featkey = (unsigned*)alloc((size_t)BSZ * 1024 * 4);
    float* feat     = (float*)alloc((size_t)BSZ * 1024 * 4);
    float* featrec  = (float*)alloc((size_t)BSZ * 1024 * 4);
    float* dh1      = (float*)alloc((size_t)BSZ * 2048 * 4);
    float* dh2      = (float*)alloc((size_t)BSZ * 2048 * 4);
    float* dh3      = (float*)alloc((size_t)BSZ * 2048 * 4);
    float* pred     = (float*)alloc((size_t)BSZ * 6144 * 4);
    int*   idxa     = (int*)  alloc((size_t)BSZ * 64 * NBRK * 4);
    float* gatha    = (float*)alloc((size_t)BSZ * 64 * NBRK * 3 * 4);
    int*   idxb     = (int*)  alloc((size_t)BSZ * 32 * NBRK * 4);
    float* gathb    = (float*)alloc((size_t)BSZ * 32 * NBRK * 3 * 4);
    int*   idxc     = (int*)  alloc((size_t)BSZ * 32 * 32 * 4);
    float* gathc    = (float*)alloc((size_t)BSZ * 1024 * 3 * 4);
    int*   knn32    = (int*)  alloc((size_t)BSZ * 2048 * 32 * 4);
    float* nrmbuf   = (float*)alloc((size_t)BSZ * 2048 * 3 * 4);
    float* accum    = (float*)alloc(8 * 4);

    hipMemsetAsync(accum, 0, 8 * 4, stream);

    cvt_w_kernel<<<(256 * 128 + 255) / 256, 256, 0, stream>>>(W2, 128, 0, 128, W2h, 256 * 128);
    cvt_w_kernel<<<(512 * 256 + 255) / 256, 256, 0, stream>>>(W3, 512, 256, 256, W3h, 512 * 256);
    cvt_w_kernel<<<(1024 * 512 + 255) / 256, 256, 0, stream>>>(W4, 512, 0, 512, W4h, 1024 * 512);

    auto knn = [&](const float* Q, int q_bstride, int q_off, int nq,
                   const float* DB, int k, int* out) {
        int total = BSZ * nq;
        knn_kernel_v4<<<(total + 3) / 4, 256, 0, stream>>>(Q, q_bstride, q_off, nq,
                                                           DB, k, out, BSZ);
    };

    // FPS + grouping
    fps_kernel<<<BSZ, 256, 0, stream>>>(pts, center);
    knn(center, NG, 0, NG, pts, GS, knnc);
    gather_points_kernel<<<(BSZ * 2048 + 255) / 256, 256, 0, stream>>>(pts, NPTS, knnc, NG * GS,
                                                                       0, 2048, rebuild0, BSZ);
    gather_points_kernel<<<(BSZ * 1024 + 255) / 256, 256, 0, stream>>>(pts, NPTS, knnc, NG * GS,
                                                                       2048, 1024, rebuild1, BSZ);

    auto enc = [&](const float* X, int n, float* featout) {
        int M = BSZ * n;
        layer1_kernel<<<M / 16, 256, 0, stream>>>(X, W1, b1, g1, be1, m1, v1, H1h, M);
        hipMemsetAsync(gmaxkey, 0, (size_t)BSZ * 256 * 4, stream);
        mfma_gemm_kernel<<<dim3(256 / 128, M / 128), 256, 0, stream>>>(
            H1h, W2h, 128, 256, b2, nullptr, nullptr, nullptr, nullptr, nullptr,
            H2h, gmaxkey, n, 0);
        decode_kernel<<<(BSZ * 256 + 255) / 256, 256, 0, stream>>>(gmaxkey, gmaxb, BSZ * 256);
        skinny_v2_kernel<<<(512 + 3) / 4, 256, 0, stream>>>(gmaxb, W3, 512, 0, b3,
                                                            gpart, 256, 512, 0);
        mfma_gemm_kernel<<<dim3(512 / 128, M / 128), 256, 0, stream>>>(
            H2h, W3h, 256, 512, nullptr, gpart, g2, be2, m2, v2, H3h, nullptr, n, 1);
        hipMemsetAsync(featkey, 0, (size_t)BSZ * 1024 * 4, stream);
        mfma_gemm_kernel<<<dim3(1024 / 128, M / 128), 256, 0, stream>>>(
            H3h, W4h, 512, 1024, b4, nullptr, nullptr, nullptr, nullptr, nullptr,
            nullptr, featkey, n, 0);
        decode_kernel<<<(BSZ * 1024 + 255) / 256, 256, 0, stream>>>(featkey, featout, BSZ * 1024);
    };

    enc(rebuild0, 2048, feat);

    // decoder (skinny M=16, fp32, coalesced)
    skinny_v2_kernel<<<2048 / 4, 256, 0, stream>>>(feat, D1W, 1024, 0, D1b, dh1, 1024, 2048, 1);
    skinny_v2_kernel<<<2048 / 4, 256, 0, stream>>>(dh1, D2W, 2048, 0, D2b, dh2, 2048, 2048, 1);
    skinny_v2_kernel<<<2048 / 4, 256, 0, stream>>>(dh2, D3W, 2048, 0, D3b, dh3, 2048, 2048, 1);
    skinny_v2_kernel<<<6144 / 4, 256, 0, stream>>>(dh3, D4W, 2048, 0, D4b, pred, 2048, 6144, 0);

    // l_recon
    knn(center, NG, 0, 64, pred, NBRK, idxa);
    gather_points_kernel<<<(BSZ * 2432 + 255) / 256, 256, 0, stream>>>(pred, 2048, idxa, 64 * NBRK,
                                                                       0, 2432, gatha, BSZ);
    chamfer_min_kernel<<<(BSZ * 2048 * 8 + 255) / 256, 256, 0, stream>>>(rebuild0, 2048,
                                                                         gatha, 2432, accum + 0);
    chamfer_min_kernel<<<(BSZ * 2432 * 8 + 255) / 256, 256, 0, stream>>>(gatha, 2432,
                                                                         rebuild0, 2048, accum + 1);
    // l_match
    knn(center, NG, 64, 32, pred, NBRK, idxb);
    gather_points_kernel<<<(BSZ * 1216 + 255) / 256, 256, 0, stream>>>(pred, 2048, idxb, 32 * NBRK,
                                                                       0, 1216, gathb, BSZ);
    chamfer_min_kernel<<<(BSZ * 1024 * 8 + 255) / 256, 256, 0, stream>>>(rebuild1, 1024,
                                                                         gathb, 1216, accum + 2);
    chamfer_min_kernel<<<(BSZ * 1216 * 8 + 255) / 256, 256, 0, stream>>>(gathb, 1216,
                                                                         rebuild1, 1024, accum + 3);
    // l_latent
    knn(center, NG, 96, 32, pred, 32, idxc);
    gather_points_kernel<<<(BSZ * 1024 + 255) / 256, 256, 0, stream>>>(pred, 2048, idxc, 32 * 32,
                                                                       0, 1024, gathc, BSZ);
    enc(gathc, 1024, featrec);
    latent_kernel<<<(BSZ * 1024 + 255) / 256, 256, 0, stream>>>(feat, featrec, BSZ * 1024,
                                                                accum + 4);
    // l_man: one self-KNN (k=32); manifold uses first 8 (stable top-k prefix)
    knn(pred, 2048, 0, 2048, pred, 32, knn32);
    normals_kernel<<<(BSZ * 2048 + 255) / 256, 256, 0, stream>>>(pred, knn32, nrmbuf);
    manifold_kernel<<<(BSZ * 2048 + 255) / 256, 256, 0, stream>>>(nrmbuf, knn32, 32, accum + 5);

    finalize_kernel<<<1, 1, 0, stream>>>(accum, (float*)d_out);
}

// Round 6
// 1193.171 us; speedup vs baseline: 33.2464x; 1.2034x over previous
//
#include <hip/hip_runtime.h>
#include <math.h>

#define BSZ 16
#define NPTS 2048
#define NG 128
#define GS 32
#define NBRK 38

typedef _Float16 f16;
typedef _Float16 f16x8 __attribute__((ext_vector_type(8)));
typedef float f32x4 __attribute__((ext_vector_type(4)));

// ---------- helpers ----------
__device__ __forceinline__ unsigned fkey(float x) {
    unsigned u = __float_as_uint(x);
    return (u >> 31) ? ~u : (u | 0x80000000u);
}
__device__ __forceinline__ float fkey_inv(unsigned k) {
    unsigned u = (k >> 31) ? (k ^ 0x80000000u) : ~k;
    return __uint_as_float(u);
}

// ---------- FPS v2: registers + shuffle reduce ----------
__global__ void fps_kernel(const float* __restrict__ pts, float* __restrict__ center) {
    int b = blockIdx.x;
    const float* P = pts + (size_t)b * NPTS * 3;
    int tid = threadIdx.x;            // 256
    int lane = tid & 63, wave = tid >> 6;
    float px[8], py[8], pz[8], mind[8];
#pragma unroll
    for (int m = 0; m < 8; ++m) {
        int i = tid + 256 * m;
        px[m] = P[i * 3 + 0]; py[m] = P[i * 3 + 1]; pz[m] = P[i * 3 + 2];
        mind[m] = 1e10f;
    }
    __shared__ float cw[4];
    __shared__ int   ci[4];
    int far = 0;
    for (int g = 0; g < NG; ++g) {
        float cx = P[far * 3 + 0], cy = P[far * 3 + 1], cz = P[far * 3 + 2];
        if (tid == 0) {
            center[((size_t)b * NG + g) * 3 + 0] = cx;
            center[((size_t)b * NG + g) * 3 + 1] = cy;
            center[((size_t)b * NG + g) * 3 + 2] = cz;
        }
        float best = -1.0f; int bi = 0;
#pragma unroll
        for (int m = 0; m < 8; ++m) {
            float dx = px[m] - cx, dy = py[m] - cy, dz = pz[m] - cz;
            float d = dx * dx + dy * dy + dz * dz;
            float md = fminf(mind[m], d);
            mind[m] = md;
            if (md > best) { best = md; bi = tid + 256 * m; }
        }
#pragma unroll
        for (int s = 1; s < 64; s <<= 1) {
            float ov = __shfl_xor(best, s, 64);
            int   oi = __shfl_xor(bi, s, 64);
            if (ov > best || (ov == best && oi < bi)) { best = ov; bi = oi; }
        }
        if (lane == 0) { cw[wave] = best; ci[wave] = bi; }
        __syncthreads();
        float fb = cw[0]; int fi = ci[0];
#pragma unroll
        for (int w = 1; w < 4; ++w) {
            float ov = cw[w]; int oi = ci[w];
            if (ov > fb || (ov == fb && oi < fi)) { fb = ov; fi = oi; }
        }
        far = fi;
        __syncthreads();
    }
}

// ---------- KNN v5: register-resident, top-4 lane cache, packed-u64 butterfly ----------
// Stable top_k semantics: min distance wins, equal distances -> lower index.
// ndb fixed at NPTS=2048 (32 candidates per lane). Wave per query, no barriers.
// Top-4 cache makes refills ~never happen (P(lane gets >=4 of 32 pops) ~ 0.2%).
__global__ void knn_kernel_v5(const float* __restrict__ Q, int q_bstride, int q_off, int nq,
                              const float* __restrict__ DB, int k,
                              int* __restrict__ out, int nbatch) {
    const float INF = 3e38f;
    int wave = threadIdx.x >> 6, lane = threadIdx.x & 63;
    int qidx = blockIdx.x * 4 + wave;
    if (qidx >= nbatch * nq) return;     // wave-uniform
    int b = qidx / nq, qi = qidx % nq;
    const float* q = Q + ((size_t)b * q_bstride + q_off + qi) * 3;
    float qx = q[0], qy = q[1], qz = q[2];
    float qq = qx * qx + qy * qy + qz * qz;
    const float* db = DB + (size_t)b * NPTS * 3;

    float d[32];
    float c0v = INF, c1v = INF, c2v = INF, c3v = INF;
    int c0s = 0, c1s = 0, c2s = 0, c3s = 0;
#pragma unroll
    for (int m = 0; m < 32; ++m) {
        int j = lane + (m << 6);
        float bx = db[j * 3 + 0], by = db[j * 3 + 1], bz = db[j * 3 + 2];
        float dv = qq + bx * bx + by * by + bz * bz - 2.0f * (qx * bx + qy * by + qz * bz);
        d[m] = dv;
        if (dv < c3v) {                  // strict <: ties keep earlier (lower index)
            if (dv < c2v) {
                c3v = c2v; c3s = c2s;
                if (dv < c1v) {
                    c2v = c1v; c2s = c1s;
                    if (dv < c0v) { c1v = c0v; c1s = c0s; c0v = dv; c0s = m; }
                    else          { c1v = dv; c1s = m; }
                } else { c2v = dv; c2s = m; }
            } else { c3v = dv; c3s = m; }
        }
    }

    float wv = -INF; int wslot = -1;     // watermark: last popped (value, slot) this lane
    int npop = 0;
    int* o = out + (size_t)qidx * k;

    for (int r = 0; r < k; ++r) {
        bool need = (c0v >= 1e37f) && (npop < 32);
        if (__any(need)) {
            // lex-min over d[] with (d,slot) > (wv,wslot); adjacency tree keeps
            // lower slot on ties (strict <, left preference).
            float tv[16]; int ts[16];
#pragma unroll
            for (int m = 0; m < 16; ++m) {
                float a0 = d[2 * m];
                float a1 = d[2 * m + 1];
                bool q0 = (a0 > wv) || (a0 == wv && (2 * m)     > wslot);
                bool q1 = (a1 > wv) || (a1 == wv && (2 * m + 1) > wslot);
                a0 = q0 ? a0 : INF;
                a1 = q1 ? a1 : INF;
                bool t = a1 < a0;
                tv[m] = t ? a1 : a0;
                ts[m] = t ? 2 * m + 1 : 2 * m;
            }
#pragma unroll
            for (int h = 8; h >= 1; h >>= 1)
#pragma unroll
                for (int m = 0; m < h; ++m) {
                    bool t = tv[2 * m + 1] < tv[2 * m];
                    tv[m] = t ? tv[2 * m + 1] : tv[2 * m];
                    ts[m] = t ? ts[2 * m + 1] : ts[2 * m];
                }
            if (need) { c0v = tv[0]; c0s = ts[0]; }
        }
        // packed (fkey(dist) << 32) | global_index : u64 min == lex-min (stable)
        unsigned long long key = ((unsigned long long)fkey(c0v) << 32)
                               | (unsigned)(lane + (c0s << 6));
#pragma unroll
        for (int s = 1; s < 64; s <<= 1) {
            unsigned long long ok = __shfl_xor(key, s, 64);
            key = ok < key ? ok : key;
        }
        int gi = (int)(unsigned)key;
        if (lane == 0) o[r] = gi;
        if ((gi & 63) == lane) {
            wv = c0v; wslot = c0s;
            c0v = c1v; c0s = c1s;
            c1v = c2v; c1s = c2s;
            c2v = c3v; c2s = c3s;
            c3v = INF;
            ++npop;
        }
    }
}

// ---------- gather points via index array ----------
__global__ void gather_points_kernel(const float* __restrict__ pts, int db_bstride,
                                     const int* __restrict__ idx, int idx_bstride, int idx_off,
                                     int m, float* __restrict__ out, int nbatch) {
    int t = blockIdx.x * blockDim.x + threadIdx.x;
    if (t >= nbatch * m) return;
    int b = t / m, j = t % m;
    int s = idx[(size_t)b * idx_bstride + idx_off + j];
    const float* p = pts + ((size_t)b * db_bstride + s) * 3;
    out[(size_t)t * 3 + 0] = p[0];
    out[(size_t)t * 3 + 1] = p[1];
    out[(size_t)t * 3 + 2] = p[2];
}

// ---------- fp32 -> fp16 weight conversion (strided slice) ----------
__global__ void cvt_w_kernel(const float* __restrict__ in, int ld, int off, int K,
                             f16* __restrict__ out, int total) {
    int t = blockIdx.x * blockDim.x + threadIdx.x;
    if (t >= total) return;
    int n = t / K, k = t % K;
    out[t] = (f16)in[(size_t)n * ld + off + k];
}

// ---------- layer1: H1 = relu(bn(x @ W1^T + b1)) in fp16, fused ----------
__global__ void layer1_kernel(const float* __restrict__ X, const float* __restrict__ W1,
                              const float* __restrict__ b1, const float* __restrict__ g1,
                              const float* __restrict__ be1, const float* __restrict__ m1,
                              const float* __restrict__ v1, f16* __restrict__ H1, int M) {
    __shared__ float w[384], bb[128], sg[128], sb[128], sm[128], sv[128];
    for (int i = threadIdx.x; i < 384; i += 256) w[i] = W1[i];
    if (threadIdx.x < 128) {
        int c = threadIdx.x;
        bb[c] = b1[c]; sg[c] = g1[c]; sb[c] = be1[c]; sm[c] = m1[c]; sv[c] = v1[c];
    }
    __syncthreads();
    int t = blockIdx.x * 256 + threadIdx.x;
    if (t >= M * 16) return;
    int row = t >> 4, cg = (t & 15) * 8;
    float x0 = X[(size_t)row * 3], x1 = X[(size_t)row * 3 + 1], x2 = X[(size_t)row * 3 + 2];
    f16x8 outv;
#pragma unroll
    for (int j = 0; j < 8; ++j) {
        int c = cg + j;
        float tv = x0 * w[c * 3] + x1 * w[c * 3 + 1] + x2 * w[c * 3 + 2] + bb[c];
        float vv = (tv - sm[c]) * rsqrtf(sv[c] + 1e-5f) * sg[c] + sb[c];
        outv[j] = (f16)fmaxf(vv, 0.f);
    }
    *(f16x8*)&H1[(size_t)row * 128 + cg] = outv;
}

// ---------- MFMA GEMM ----------
__global__ __launch_bounds__(256) void mfma_gemm_kernel(
        const f16* __restrict__ A, const f16* __restrict__ W, int K, int N,
        const float* __restrict__ bias, const float* __restrict__ bias2d,
        const float* __restrict__ bng, const float* __restrict__ bnb,
        const float* __restrict__ bnm, const float* __restrict__ bnv,
        f16* __restrict__ Cout, unsigned* __restrict__ maxkey,
        int rows_per_batch, int relu) {
    __shared__ f16 Als[128 * 40];
    __shared__ f16 Bls[128 * 40];
    int tid = threadIdx.x;
    int lane = tid & 63;
    int wave = tid >> 6;
    int wm = wave & 1, wn = wave >> 1;
    int c16 = lane & 15, quad = lane >> 4;
    int row0 = blockIdx.y * 128, col0 = blockIdx.x * 128;
    int sr = tid >> 2;
    int skc = (tid & 3) * 8;

    f32x4 acc[4][4];
#pragma unroll
    for (int i = 0; i < 4; ++i)
#pragma unroll
        for (int j = 0; j < 4; ++j) acc[i][j] = (f32x4){0.f, 0.f, 0.f, 0.f};

    for (int k0 = 0; k0 < K; k0 += 32) {
#pragma unroll
        for (int i = 0; i < 2; ++i) {
            int r2 = sr + i * 64;
            f16x8 av = *(const f16x8*)(A + (size_t)(row0 + r2) * K + k0 + skc);
            *(f16x8*)&Als[r2 * 40 + skc] = av;
            f16x8 bv = *(const f16x8*)(W + (size_t)(col0 + r2) * K + k0 + skc);
            *(f16x8*)&Bls[r2 * 40 + skc] = bv;
        }
        __syncthreads();
        f16x8 af[4], bf[4];
#pragma unroll
        for (int s = 0; s < 4; ++s) {
            af[s] = *(const f16x8*)&Als[(wm * 64 + s * 16 + c16) * 40 + quad * 8];
            bf[s] = *(const f16x8*)&Bls[(wn * 64 + s * 16 + c16) * 40 + quad * 8];
        }
#pragma unroll
        for (int ms = 0; ms < 4; ++ms)
#pragma unroll
            for (int ns = 0; ns < 4; ++ns)
                acc[ms][ns] = __builtin_amdgcn_mfma_f32_16x16x32_f16(af[ms], bf[ns],
                                                                     acc[ms][ns], 0, 0, 0);
        __syncthreads();
    }

    int b = row0 / rows_per_batch;
#pragma unroll
    for (int ns = 0; ns < 4; ++ns) {
        int col = col0 + wn * 64 + ns * 16 + c16;
        float bv = bias ? bias[col] : 0.f;
        float b2v = bias2d ? bias2d[(size_t)b * N + col] : 0.f;
        float mx = -3e38f;
#pragma unroll
        for (int ms = 0; ms < 4; ++ms) {
#pragma unroll
            for (int j = 0; j < 4; ++j) {
                float v = acc[ms][ns][j] + bv + b2v;
                if (bng) v = (v - bnm[col]) * rsqrtf(bnv[col] + 1e-5f) * bng[col] + bnb[col];
                if (relu) v = fmaxf(v, 0.f);
                if (Cout)
                    Cout[(size_t)(row0 + wm * 64 + ms * 16 + quad * 4 + j) * N + col] = (f16)v;
                mx = fmaxf(mx, v);
            }
        }
        if (maxkey) {
            mx = fmaxf(mx, __shfl_xor(mx, 16, 64));
            mx = fmaxf(mx, __shfl_xor(mx, 32, 64));
            if (quad == 0) atomicMax(&maxkey[(size_t)b * N + col], fkey(mx));
        }
    }
}

// ---------- skinny GEMM v2: wave per column, coalesced float4 ----------
__global__ void skinny_v2_kernel(const float* __restrict__ A, const float* __restrict__ W,
                                 int ldw, int woff, const float* __restrict__ bias,
                                 float* __restrict__ C, int K, int N, int relu) {
    int wave = threadIdx.x >> 6, lane = threadIdx.x & 63;
    int col = blockIdx.x * 4 + wave;
    if (col >= N) return;
    const float* w = W + (size_t)col * ldw + woff;
    float acc[16];
#pragma unroll
    for (int m = 0; m < 16; ++m) acc[m] = 0.f;
    for (int k0 = 0; k0 < K; k0 += 256) {
        f32x4 wv = *(const f32x4*)(w + k0 + lane * 4);
#pragma unroll
        for (int m = 0; m < 16; ++m) {
            f32x4 av = *(const f32x4*)(A + (size_t)m * K + k0 + lane * 4);
            acc[m] += av[0] * wv[0] + av[1] * wv[1] + av[2] * wv[2] + av[3] * wv[3];
        }
    }
#pragma unroll
    for (int m = 0; m < 16; ++m)
#pragma unroll
        for (int s = 1; s < 64; s <<= 1) acc[m] += __shfl_xor(acc[m], s, 64);
    if (lane == 0) {
        float bv = bias[col];
#pragma unroll
        for (int m = 0; m < 16; ++m) {
            float v = acc[m] + bv;
            if (relu) v = fmaxf(v, 0.f);
            C[(size_t)m * N + col] = v;
        }
    }
}

__global__ void decode_kernel(const unsigned* __restrict__ k, float* __restrict__ f, int n) {
    int t = blockIdx.x * blockDim.x + threadIdx.x;
    if (t < n) f[t] = fkey_inv(k[t]);
}

// ---------- chamfer v2: 8 lanes per A-point, j-strided, shfl-min ----------
__global__ void chamfer_min_kernel(const float* __restrict__ A, int na,
                                   const float* __restrict__ Bp, int nb,
                                   float* __restrict__ slot) {
    int t = blockIdx.x * 256 + threadIdx.x;
    int pt = t >> 3, sl = t & 7;
    float val = 0.f;
    if (pt < BSZ * na) {
        int b = pt / na;
        const float* a = A + (size_t)pt * 3;
        float ax = a[0], ay = a[1], az = a[2];
        float aa = ax * ax + ay * ay + az * az;
        const float* Bb = Bp + (size_t)b * nb * 3;
        float m = 3e38f;
        for (int j = sl; j < nb; j += 8) {
            float bx = Bb[j * 3 + 0], by = Bb[j * 3 + 1], bz = Bb[j * 3 + 2];
            float d = aa + bx * bx + by * by + bz * bz - 2.0f * (ax * bx + ay * by + az * bz);
            m = fminf(m, d);
        }
#pragma unroll
        for (int s = 1; s < 8; s <<= 1) m = fminf(m, __shfl_xor(m, s, 64));
        if (sl == 0) val = sqrtf(fmaxf(m, 1e-12f));
    }
    __shared__ float sdata[256];
    sdata[threadIdx.x] = val;
    __syncthreads();
    for (int s = 128; s > 0; s >>= 1) {
        if (threadIdx.x < s) sdata[threadIdx.x] += sdata[threadIdx.x + s];
        __syncthreads();
    }
    if (threadIdx.x == 0) atomicAdd(slot, sdata[0]);
}

// ---------- smooth-L1 latent loss sum ----------
__global__ void latent_kernel(const float* __restrict__ f1, const float* __restrict__ f2,
                              int n, float* __restrict__ slot) {
    int t = blockIdx.x * blockDim.x + threadIdx.x;
    float val = 0.f;
    if (t < n) {
        float d = f1[t] - f2[t];
        float ad = fabsf(d);
        val = (ad < 1.f) ? (0.5f * d * d) : (ad - 0.5f);
    }
    __shared__ float sdata[256];
    sdata[threadIdx.x] = val;
    __syncthreads();
    for (int s = 128; s > 0; s >>= 1) {
        if (threadIdx.x < s) sdata[threadIdx.x] += sdata[threadIdx.x + s];
        __syncthreads();
    }
    if (threadIdx.x == 0) atomicAdd(slot, sdata[0]);
}

// ---------- 3x3 symmetric smallest eigenvector (double, analytic) ----------
__device__ void smallest_evec(double cxx, double cxy, double cxz,
                              double cyy, double cyz, double czz, double ev[3]) {
    double p1 = cxy * cxy + cxz * cxz + cyz * cyz;
    double q = (cxx + cyy + czz) / 3.0;
    double p2 = (cxx - q) * (cxx - q) + (cyy - q) * (cyy - q) + (czz - q) * (czz - q) + 2.0 * p1;
    double lam = q;
    if (p2 > 0.0) {
        double p = sqrt(p2 / 6.0);
        double b00 = (cxx - q) / p, b11 = (cyy - q) / p, b22 = (czz - q) / p;
        double b01 = cxy / p, b02 = cxz / p, b12 = cyz / p;
        double detB = b00 * (b11 * b22 - b12 * b12) - b01 * (b01 * b22 - b12 * b02)
                    + b02 * (b01 * b12 - b11 * b02);
        double r = detB * 0.5;
        r = r < -1.0 ? -1.0 : (r > 1.0 ? 1.0 : r);
        double phi = acos(r) / 3.0;
        lam = q + 2.0 * p * cos(phi + 2.0943951023931953);
    }
    double r0x = cxx - lam, r0y = cxy, r0z = cxz;
    double r1x = cxy, r1y = cyy - lam, r1z = cyz;
    double r2x = cxz, r2y = cyz, r2z = czz - lam;
    double c0x = r0y * r1z - r0z * r1y, c0y = r0z * r1x - r0x * r1z, c0z = r0x * r1y - r0y * r1x;
    double c1x = r0y * r2z - r0z * r2y, c1y = r0z * r2x - r0x * r2z, c1z = r0x * r2y - r0y * r2x;
    double c2x = r1y * r2z - r1z * r2y, c2y = r1z * r2x - r1x * r2z, c2z = r1x * r2y - r1y * r2x;
    double n0 = c0x * c0x + c0y * c0y + c0z * c0z;
    double n1 = c1x * c1x + c1y * c1y + c1z * c1z;
    double n2 = c2x * c2x + c2y * c2y + c2z * c2z;
    double bx = c0x, by = c0y, bz = c0z, bn = n0;
    if (n1 > bn) { bx = c1x; by = c1y; bz = c1z; bn = n1; }
    if (n2 > bn) { bx = c2x; by = c2y; bz = c2z; bn = n2; }
    if (bn < 1e-280) { ev[0] = 1.0; ev[1] = 0.0; ev[2] = 0.0; return; }
    double inv = 1.0 / sqrt(bn);
    ev[0] = bx * inv; ev[1] = by * inv; ev[2] = bz * inv;
}

// ---------- normals ----------
__global__ void normals_kernel(const float* __restrict__ pred, const int* __restrict__ knn,
                               float* __restrict__ nrm) {
    int t = blockIdx.x * blockDim.x + threadIdx.x;
    if (t >= BSZ * NPTS) return;
    int b = t / NPTS, i = t % NPTS;
    const float* P = pred + (size_t)b * NPTS * 3;
    const int* id = knn + (size_t)t * 32;
    float px[32], py[32], pz[32];
    double sx = 0, sy = 0, sz = 0;
    for (int k = 0; k < 32; ++k) {
        int j = id[k];
        px[k] = P[j * 3 + 0]; py[k] = P[j * 3 + 1]; pz[k] = P[j * 3 + 2];
        sx += px[k]; sy += py[k]; sz += pz[k];
    }
    double mx = sx / 32.0, my = sy / 32.0, mz = sz / 32.0;
    double cxx = 0, cxy = 0, cxz = 0, cyy = 0, cyz = 0, czz = 0;
    for (int k = 0; k < 32; ++k) {
        double dx = px[k] - mx, dy = py[k] - my, dz = pz[k] - mz;
        cxx += dx * dx; cxy += dx * dy; cxz += dx * dz;
        cyy += dy * dy; cyz += dy * dz; czz += dz * dz;
    }
    cxx /= 32.0; cxy /= 32.0; cxz /= 32.0; cyy /= 32.0; cyz /= 32.0; czz /= 32.0;
    double ev[3];
    smallest_evec(cxx, cxy, cxz, cyy, cyz, czz, ev);
    float qx = P[i * 3 + 0], qy = P[i * 3 + 1], qz = P[i * 3 + 2];
    double proj = 0.0;
    for (int k = 0; k < 32; ++k)
        proj += (px[k] - qx) * ev[0] + (py[k] - qy) * ev[1] + (pz[k] - qz) * ev[2];
    double s = (proj >= 0.0) ? 1.0 : -1.0;
    nrm[(size_t)t * 3 + 0] = (float)(ev[0] * s);
    nrm[(size_t)t * 3 + 1] = (float)(ev[1] * s);
    nrm[(size_t)t * 3 + 2] = (float)(ev[2] * s);
}

// ---------- manifold loss: reads first 8 of the 32-NN list ----------
__global__ void manifold_kernel(const float* __restrict__ nrm, const int* __restrict__ knn,
                                int kstride, float* __restrict__ slot) {
    int t = blockIdx.x * blockDim.x + threadIdx.x;
    float val = 0.f;
    if (t < BSZ * NPTS) {
        int b = t / NPTS;
        const float* NB = nrm + (size_t)b * NPTS * 3;
        const int* id = knn + (size_t)t * kstride;
        int j0 = id[0];
        float ax = NB[j0 * 3 + 0], ay = NB[j0 * 3 + 1], az = NB[j0 * 3 + 2];
        float an = fmaxf(sqrtf(ax * ax + ay * ay + az * az), 1e-6f);
        float x[8]; float s = 0.f;
        for (int k = 0; k < 8; ++k) {
            int j = id[k];
            float bx = NB[j * 3 + 0], by = NB[j * 3 + 1], bz = NB[j * 3 + 2];
            float bn_ = fmaxf(sqrtf(bx * bx + by * by + bz * bz), 1e-6f);
            float c = (ax * bx + ay * by + az * bz) / (an * bn_);
            x[k] = 1.f - c; s += x[k];
        }
        float mean = s / 8.f;
        float var = 0.f;
        for (int k = 0; k < 8; ++k) { float d = x[k] - mean; var += d * d; }
        val = sqrtf(var / 7.f);
    }
    __shared__ float sdata[256];
    sdata[threadIdx.x] = val;
    __syncthreads();
    for (int s2 = 128; s2 > 0; s2 >>= 1) {
        if (threadIdx.x < s2) sdata[threadIdx.x] += sdata[threadIdx.x + s2];
        __syncthreads();
    }
    if (threadIdx.x == 0) atomicAdd(slot, sdata[0]);
}

__global__ void finalize_kernel(const float* __restrict__ acc, float* __restrict__ out) {
    float l_recon = 0.5f * (acc[0] / (16.f * 2048.f) + acc[1] / (16.f * 2432.f));
    float l_match = 0.5f * (acc[2] / (16.f * 1024.f) + acc[3] / (16.f * 1216.f));
    float l_latent = acc[4] / (16.f * 1024.f);
    float l_man = 0.1f * (acc[5] / (16.f * 2048.f));
    out[0] = l_recon + l_match + l_latent + l_man;
    out[1] = l_recon;
    out[2] = l_match;
    out[3] = l_latent;
    out[4] = l_man;
}

// ================= host =================
extern "C" void kernel_launch(void* const* d_in, const int* in_sizes, int n_in,
                              void* d_out, int out_size, void* d_ws, size_t ws_size,
                              hipStream_t stream) {
    (void)in_sizes; (void)n_in; (void)out_size; (void)ws_size;
    const float* pts = (const float*)d_in[0];
    const float* W1 = (const float*)d_in[1];
    const float* b1 = (const float*)d_in[2];
    const float* g1 = (const float*)d_in[3];
    const float* be1 = (const float*)d_in[4];
    const float* m1 = (const float*)d_in[5];
    const float* v1 = (const float*)d_in[6];
    const float* W2 = (const float*)d_in[7];
    const float* b2 = (const float*)d_in[8];
    const float* W3 = (const float*)d_in[9];
    const float* b3 = (const float*)d_in[10];
    const float* g2 = (const float*)d_in[11];
    const float* be2 = (const float*)d_in[12];
    const float* m2 = (const float*)d_in[13];
    const float* v2 = (const float*)d_in[14];
    const float* W4 = (const float*)d_in[15];
    const float* b4 = (const float*)d_in[16];
    const float* D1W = (const float*)d_in[17];
    const float* D1b = (const float*)d_in[18];
    const float* D2W = (const float*)d_in[19];
    const float* D2b = (const float*)d_in[20];
    const float* D3W = (const float*)d_in[21];
    const float* D3b = (const float*)d_in[22];
    const float* D4W = (const float*)d_in[23];
    const float* D4b = (const float*)d_in[24];

    char* ws = (char*)d_ws;
    size_t off = 0;
    auto alloc = [&](size_t bytes) -> void* {
        void* p = ws + off;
        off += (bytes + 255) & ~(size_t)255;
        return p;
    };
    float* center   = (float*)alloc((size_t)BSZ * NG * 3 * 4);
    int*   knnc     = (int*)  alloc((size_t)BSZ * NG * GS * 4);
    float* rebuild0 = (float*)alloc((size_t)BSZ * 2048 * 3 * 4);
    float* rebuild1 = (float*)alloc((size_t)BSZ * 1024 * 3 * 4);
    f16*   W2h      = (f16*)  alloc((size_t)256 * 128 * 2);
    f16*   W3h      = (f16*)  alloc((size_t)512 * 256 * 2);
    f16*   W4h      = (f16*)  alloc((size_t)1024 * 512 * 2);
    f16*   H1h      = (f16*)  alloc((size_t)BSZ * 2048 * 128 * 2);
    f16*   H2h      = (f16*)  alloc((size_t)BSZ * 2048 * 256 * 2);
    f16*   H3h      = (f16*)  alloc((size_t)BSZ * 2048 * 512 * 2);
    unsigned* gmaxkey = (unsigned*)alloc((size_t)BSZ * 256 * 4);
    float* gmaxb    = (float*)alloc((size_t)BSZ * 256 * 4);
    float* gpart    = (float*)alloc((size_t)BSZ * 512 * 4);
    unsigned* featkey = (unsigned*)alloc((size_t)BSZ * 1024 * 4);
    float* feat     = (float*)alloc((size_t)BSZ * 1024 * 4);
    float* featrec  = (float*)alloc((size_t)BSZ * 1024 * 4);
    float* dh1      = (float*)alloc((size_t)BSZ * 2048 * 4);
    float* dh2      = (float*)alloc((size_t)BSZ * 2048 * 4);
    float* dh3      = (float*)alloc((size_t)BSZ * 2048 * 4);
    float* pred     = (float*)alloc((size_t)BSZ * 6144 * 4);
    int*   idxa     = (int*)  alloc((size_t)BSZ * 64 * NBRK * 4);
    float* gatha    = (float*)alloc((size_t)BSZ * 64 * NBRK * 3 * 4);
    int*   idxb     = (int*)  alloc((size_t)BSZ * 32 * NBRK * 4);
    float* gathb    = (float*)alloc((size_t)BSZ * 32 * NBRK * 3 * 4);
    int*   idxc     = (int*)  alloc((size_t)BSZ * 32 * 32 * 4);
    float* gathc    = (float*)alloc((size_t)BSZ * 1024 * 3 * 4);
    int*   knn32    = (int*)  alloc((size_t)BSZ * 2048 * 32 * 4);
    float* nrmbuf   = (float*)alloc((size_t)BSZ * 2048 * 3 * 4);
    float* accum    = (float*)alloc(8 * 4);

    hipMemsetAsync(accum, 0, 8 * 4, stream);

    cvt_w_kernel<<<(256 * 128 + 255) / 256, 256, 0, stream>>>(W2, 128, 0, 128, W2h, 256 * 128);
    cvt_w_kernel<<<(512 * 256 + 255) / 256, 256, 0, stream>>>(W3, 512, 256, 256, W3h, 512 * 256);
    cvt_w_kernel<<<(1024 * 512 + 255) / 256, 256, 0, stream>>>(W4, 512, 0, 512, W4h, 1024 * 512);

    auto knn = [&](const float* Q, int q_bstride, int q_off, int nq,
                   const float* DB, int k, int* out) {
        int total = BSZ * nq;
        knn_kernel_v5<<<(total + 3) / 4, 256, 0, stream>>>(Q, q_bstride, q_off, nq,
                                                           DB, k, out, BSZ);
    };

    // FPS + grouping
    fps_kernel<<<BSZ, 256, 0, stream>>>(pts, center);
    knn(center, NG, 0, NG, pts, GS, knnc);
    gather_points_kernel<<<(BSZ * 2048 + 255) / 256, 256, 0, stream>>>(pts, NPTS, knnc, NG * GS,
                                                                       0, 2048, rebuild0, BSZ);
    gather_points_kernel<<<(BSZ * 1024 + 255) / 256, 256, 0, stream>>>(pts, NPTS, knnc, NG * GS,
                                                                       2048, 1024, rebuild1, BSZ);

    auto enc = [&](const float* X, int n, float* featout) {
        int M = BSZ * n;
        layer1_kernel<<<M / 16, 256, 0, stream>>>(X, W1, b1, g1, be1, m1, v1, H1h, M);
        hipMemsetAsync(gmaxkey, 0, (size_t)BSZ * 256 * 4, stream);
        mfma_gemm_kernel<<<dim3(256 / 128, M / 128), 256, 0, stream>>>(
            H1h, W2h, 128, 256, b2, nullptr, nullptr, nullptr, nullptr, nullptr,
            H2h, gmaxkey, n, 0);
        decode_kernel<<<(BSZ * 256 + 255) / 256, 256, 0, stream>>>(gmaxkey, gmaxb, BSZ * 256);
        skinny_v2_kernel<<<(512 + 3) / 4, 256, 0, stream>>>(gmaxb, W3, 512, 0, b3,
                                                            gpart, 256, 512, 0);
        mfma_gemm_kernel<<<dim3(512 / 128, M / 128), 256, 0, stream>>>(
            H2h, W3h, 256, 512, nullptr, gpart, g2, be2, m2, v2, H3h, nullptr, n, 1);
        hipMemsetAsync(featkey, 0, (size_t)BSZ * 1024 * 4, stream);
        mfma_gemm_kernel<<<dim3(1024 / 128, M / 128), 256, 0, stream>>>(
            H3h, W4h, 512, 1024, b4, nullptr, nullptr, nullptr, nullptr, nullptr,
            nullptr, featkey, n, 0);
        decode_kernel<<<(BSZ * 1024 + 255) / 256, 256, 0, stream>>>(featkey, featout, BSZ * 1024);
    };

    enc(rebuild0, 2048, feat);

    // decoder (skinny M=16, fp32, coalesced)
    skinny_v2_kernel<<<2048 / 4, 256, 0, stream>>>(feat, D1W, 1024, 0, D1b, dh1, 1024, 2048, 1);
    skinny_v2_kernel<<<2048 / 4, 256, 0, stream>>>(dh1, D2W, 2048, 0, D2b, dh2, 2048, 2048, 1);
    skinny_v2_kernel<<<2048 / 4, 256, 0, stream>>>(dh2, D3W, 2048, 0, D3b, dh3, 2048, 2048, 1);
    skinny_v2_kernel<<<6144 / 4, 256, 0, stream>>>(dh3, D4W, 2048, 0, D4b, pred, 2048, 6144, 0);

    // l_recon
    knn(center, NG, 0, 64, pred, NBRK, idxa);
    gather_points_kernel<<<(BSZ * 2432 + 255) / 256, 256, 0, stream>>>(pred, 2048, idxa, 64 * NBRK,
                                                                       0, 2432, gatha, BSZ);
    chamfer_min_kernel<<<(BSZ * 2048 * 8 + 255) / 256, 256, 0, stream>>>(rebuild0, 2048,
                                                                         gatha, 2432, accum + 0);
    chamfer_min_kernel<<<(BSZ * 2432 * 8 + 255) / 256, 256, 0, stream>>>(gatha, 2432,
                                                                         rebuild0, 2048, accum + 1);
    // l_match
    knn(center, NG, 64, 32, pred, NBRK, idxb);
    gather_points_kernel<<<(BSZ * 1216 + 255) / 256, 256, 0, stream>>>(pred, 2048, idxb, 32 * NBRK,
                                                                       0, 1216, gathb, BSZ);
    chamfer_min_kernel<<<(BSZ * 1024 * 8 + 255) / 256, 256, 0, stream>>>(rebuild1, 1024,
                                                                         gathb, 1216, accum + 2);
    chamfer_min_kernel<<<(BSZ * 1216 * 8 + 255) / 256, 256, 0, stream>>>(gathb, 1216,
                                                                         rebuild1, 1024, accum + 3);
    // l_latent
    knn(center, NG, 96, 32, pred, 32, idxc);
    gather_points_kernel<<<(BSZ * 1024 + 255) / 256, 256, 0, stream>>>(pred, 2048, idxc, 32 * 32,
                                                                       0, 1024, gathc, BSZ);
    enc(gathc, 1024, featrec);
    latent_kernel<<<(BSZ * 1024 + 255) / 256, 256, 0, stream>>>(feat, featrec, BSZ * 1024,
                                                                accum + 4);
    // l_man: one self-KNN (k=32); manifold uses first 8 (stable top-k prefix)
    knn(pred, 2048, 0, 2048, pred, 32, knn32);
    normals_kernel<<<(BSZ * 2048 + 255) / 256, 256, 0, stream>>>(pred, knn32, nrmbuf);
    manifold_kernel<<<(BSZ * 2048 + 255) / 256, 256, 0, stream>>>(nrmbuf, knn32, 32, accum + 5);

    finalize_kernel<<<1, 1, 0, stream>>>(accum, (float*)d_out);
}

// Round 7
// 980.857 us; speedup vs baseline: 40.4429x; 1.2165x over previous
//
#include <hip/hip_runtime.h>
#include <math.h>

#define BSZ 16
#define NPTS 2048
#define NG 128
#define GS 32
#define NBRK 38

typedef _Float16 f16;
typedef _Float16 f16x8 __attribute__((ext_vector_type(8)));
typedef float f32x4 __attribute__((ext_vector_type(4)));

// ---------- helpers ----------
__device__ __forceinline__ unsigned fkey(float x) {
    unsigned u = __float_as_uint(x);
    return (u >> 31) ? ~u : (u | 0x80000000u);
}
__device__ __forceinline__ float fkey_inv(unsigned k) {
    unsigned u = (k >> 31) ? (k ^ 0x80000000u) : ~k;
    return __uint_as_float(u);
}

// 64-lane min via DPP (no LDS/DS pipe): row_shr 1/2/4/8 prefix + row_bcast 15/31,
// then readlane 63 broadcasts the full-wave min. gfx9-lineage DPP (CDNA keeps it).
__device__ __forceinline__ unsigned wave_min_u32(unsigned v) {
    unsigned t;
    t = (unsigned)__builtin_amdgcn_update_dpp(-1, (int)v, 0x111, 0xF, 0xF, false);
    v = v < t ? v : t;
    t = (unsigned)__builtin_amdgcn_update_dpp(-1, (int)v, 0x112, 0xF, 0xF, false);
    v = v < t ? v : t;
    t = (unsigned)__builtin_amdgcn_update_dpp(-1, (int)v, 0x114, 0xF, 0xF, false);
    v = v < t ? v : t;
    t = (unsigned)__builtin_amdgcn_update_dpp(-1, (int)v, 0x118, 0xF, 0xF, false);
    v = v < t ? v : t;
    t = (unsigned)__builtin_amdgcn_update_dpp(-1, (int)v, 0x142, 0xA, 0xF, false);
    v = v < t ? v : t;
    t = (unsigned)__builtin_amdgcn_update_dpp(-1, (int)v, 0x143, 0xC, 0xF, false);
    v = v < t ? v : t;
    return (unsigned)__builtin_amdgcn_readlane((int)v, 63);
}

// ---------- FPS v2: registers + shuffle reduce (exact; small cost) ----------
__global__ void fps_kernel(const float* __restrict__ pts, float* __restrict__ center) {
    int b = blockIdx.x;
    const float* P = pts + (size_t)b * NPTS * 3;
    int tid = threadIdx.x;            // 256
    int lane = tid & 63, wave = tid >> 6;
    float px[8], py[8], pz[8], mind[8];
#pragma unroll
    for (int m = 0; m < 8; ++m) {
        int i = tid + 256 * m;
        px[m] = P[i * 3 + 0]; py[m] = P[i * 3 + 1]; pz[m] = P[i * 3 + 2];
        mind[m] = 1e10f;
    }
    __shared__ float cw[4];
    __shared__ int   ci[4];
    int far = 0;
    for (int g = 0; g < NG; ++g) {
        float cx = P[far * 3 + 0], cy = P[far * 3 + 1], cz = P[far * 3 + 2];
        if (tid == 0) {
            center[((size_t)b * NG + g) * 3 + 0] = cx;
            center[((size_t)b * NG + g) * 3 + 1] = cy;
            center[((size_t)b * NG + g) * 3 + 2] = cz;
        }
        float best = -1.0f; int bi = 0;
#pragma unroll
        for (int m = 0; m < 8; ++m) {
            float dx = px[m] - cx, dy = py[m] - cy, dz = pz[m] - cz;
            float d = dx * dx + dy * dy + dz * dz;
            float md = fminf(mind[m], d);
            mind[m] = md;
            if (md > best) { best = md; bi = tid + 256 * m; }
        }
#pragma unroll
        for (int s = 1; s < 64; s <<= 1) {
            float ov = __shfl_xor(best, s, 64);
            int   oi = __shfl_xor(bi, s, 64);
            if (ov > best || (ov == best && oi < bi)) { best = ov; bi = oi; }
        }
        if (lane == 0) { cw[wave] = best; ci[wave] = bi; }
        __syncthreads();
        float fb = cw[0]; int fi = ci[0];
#pragma unroll
        for (int w = 1; w < 4; ++w) {
            float ov = cw[w]; int oi = ci[w];
            if (ov > fb || (ov == fb && oi < fi)) { fb = ov; fi = oi; }
        }
        far = fi;
        __syncthreads();
    }
}

// ---------- KNN v7: 32-bit packed keys + DPP wave-min, zero DS ops ----------
// key = (quantized_dist << 11) | idx ; u32 order == (d, idx) lex order up to the
// 1/8192 distance quantum (idx breaks quantized ties; matches stable top_k
// except between points closer than 1.2e-4 in squared distance -- negligible).
// Per-lane top-4 key cache + watermark refill (rare); wave per query; no barriers.
__global__ void knn_kernel_v7(const float* __restrict__ Q, int q_bstride, int q_off, int nq,
                              const float* __restrict__ DB, int k,
                              int* __restrict__ out, int nbatch) {
    const unsigned KINF = 0xFFFFFFFFu;
    int wave = threadIdx.x >> 6, lane = threadIdx.x & 63;
    int qidx = blockIdx.x * 4 + wave;
    if (qidx >= nbatch * nq) return;     // wave-uniform
    int b = qidx / nq, qi = qidx % nq;
    const float* q = Q + ((size_t)b * q_bstride + q_off + qi) * 3;
    float qx = q[0], qy = q[1], qz = q[2];
    float qq = qx * qx + qy * qy + qz * qz;
    const float* db = DB + (size_t)b * NPTS * 3;

    unsigned key[32];
    unsigned c0 = KINF, c1 = KINF, c2 = KINF, c3 = KINF;
#pragma unroll
    for (int m = 0; m < 32; ++m) {
        int j = lane + (m << 6);
        float bx = db[j * 3 + 0], by = db[j * 3 + 1], bz = db[j * 3 + 2];
        float dv = qq + bx * bx + by * by + bz * bz - 2.0f * (qx * bx + qy * by + qz * bz);
        unsigned qd = (unsigned)fminf(fmaxf(dv, 0.f) * 8192.0f, 2097151.f);
        unsigned kk = (qd << 11) | (unsigned)j;
        key[m] = kk;
        if (kk < c3) {
            if (kk < c2) {
                c3 = c2;
                if (kk < c1) {
                    c2 = c1;
                    if (kk < c0) { c1 = c0; c0 = kk; } else c1 = kk;
                } else c2 = kk;
            } else c3 = kk;
        }
    }
    unsigned hw = c3;        // high-water: largest key ever cached (init: 4th best)
    int ncached = 4;
    int* o = out + (size_t)qidx * k;

    for (int r = 0; r < k; ++r) {
        bool need = (c0 == KINF) && (ncached < 32);
        if (__any(need)) {
            unsigned best = KINF;
#pragma unroll
            for (int m = 0; m < 32; ++m) {
                unsigned v = key[m];
                best = (v > hw && v < best) ? v : best;
            }
            if (need) {
                c0 = best;
                hw = best;
                ncached = (best == KINF) ? 32 : ncached + 1;
            }
        }
        unsigned g = wave_min_u32(c0);
        if (lane == 0) o[r] = (int)(g & 0x7FFu);
        if (((g & 0x7FFu) & 63u) == (unsigned)lane) {  // owner pops its c0 (== g)
            c0 = c1; c1 = c2; c2 = c3; c3 = KINF;
        }
    }
}

// ---------- gather points via index array ----------
__global__ void gather_points_kernel(const float* __restrict__ pts, int db_bstride,
                                     const int* __restrict__ idx, int idx_bstride, int idx_off,
                                     int m, float* __restrict__ out, int nbatch) {
    int t = blockIdx.x * blockDim.x + threadIdx.x;
    if (t >= nbatch * m) return;
    int b = t / m, j = t % m;
    int s = idx[(size_t)b * idx_bstride + idx_off + j];
    const float* p = pts + ((size_t)b * db_bstride + s) * 3;
    out[(size_t)t * 3 + 0] = p[0];
    out[(size_t)t * 3 + 1] = p[1];
    out[(size_t)t * 3 + 2] = p[2];
}

// ---------- fp32 -> fp16 weight conversion (strided slice) ----------
__global__ void cvt_w_kernel(const float* __restrict__ in, int ld, int off, int K,
                             f16* __restrict__ out, int total) {
    int t = blockIdx.x * blockDim.x + threadIdx.x;
    if (t >= total) return;
    int n = t / K, k = t % K;
    out[t] = (f16)in[(size_t)n * ld + off + k];
}

// ---------- layer1: H1 = relu(bn(x @ W1^T + b1)) in fp16, fused ----------
__global__ void layer1_kernel(const float* __restrict__ X, const float* __restrict__ W1,
                              const float* __restrict__ b1, const float* __restrict__ g1,
                              const float* __restrict__ be1, const float* __restrict__ m1,
                              const float* __restrict__ v1, f16* __restrict__ H1, int M) {
    __shared__ float w[384], bb[128], sg[128], sb[128], sm[128], sv[128];
    for (int i = threadIdx.x; i < 384; i += 256) w[i] = W1[i];
    if (threadIdx.x < 128) {
        int c = threadIdx.x;
        bb[c] = b1[c]; sg[c] = g1[c]; sb[c] = be1[c]; sm[c] = m1[c]; sv[c] = v1[c];
    }
    __syncthreads();
    int t = blockIdx.x * 256 + threadIdx.x;
    if (t >= M * 16) return;
    int row = t >> 4, cg = (t & 15) * 8;
    float x0 = X[(size_t)row * 3], x1 = X[(size_t)row * 3 + 1], x2 = X[(size_t)row * 3 + 2];
    f16x8 outv;
#pragma unroll
    for (int j = 0; j < 8; ++j) {
        int c = cg + j;
        float tv = x0 * w[c * 3] + x1 * w[c * 3 + 1] + x2 * w[c * 3 + 2] + bb[c];
        float vv = (tv - sm[c]) * rsqrtf(sv[c] + 1e-5f) * sg[c] + sb[c];
        outv[j] = (f16)fmaxf(vv, 0.f);
    }
    *(f16x8*)&H1[(size_t)row * 128 + cg] = outv;
}

// ---------- MFMA GEMM ----------
__global__ __launch_bounds__(256) void mfma_gemm_kernel(
        const f16* __restrict__ A, const f16* __restrict__ W, int K, int N,
        const float* __restrict__ bias, const float* __restrict__ bias2d,
        const float* __restrict__ bng, const float* __restrict__ bnb,
        const float* __restrict__ bnm, const float* __restrict__ bnv,
        f16* __restrict__ Cout, unsigned* __restrict__ maxkey,
        int rows_per_batch, int relu) {
    __shared__ f16 Als[128 * 40];
    __shared__ f16 Bls[128 * 40];
    int tid = threadIdx.x;
    int lane = tid & 63;
    int wave = tid >> 6;
    int wm = wave & 1, wn = wave >> 1;
    int c16 = lane & 15, quad = lane >> 4;
    int row0 = blockIdx.y * 128, col0 = blockIdx.x * 128;
    int sr = tid >> 2;
    int skc = (tid & 3) * 8;

    f32x4 acc[4][4];
#pragma unroll
    for (int i = 0; i < 4; ++i)
#pragma unroll
        for (int j = 0; j < 4; ++j) acc[i][j] = (f32x4){0.f, 0.f, 0.f, 0.f};

    for (int k0 = 0; k0 < K; k0 += 32) {
#pragma unroll
        for (int i = 0; i < 2; ++i) {
            int r2 = sr + i * 64;
            f16x8 av = *(const f16x8*)(A + (size_t)(row0 + r2) * K + k0 + skc);
            *(f16x8*)&Als[r2 * 40 + skc] = av;
            f16x8 bv = *(const f16x8*)(W + (size_t)(col0 + r2) * K + k0 + skc);
            *(f16x8*)&Bls[r2 * 40 + skc] = bv;
        }
        __syncthreads();
        f16x8 af[4], bf[4];
#pragma unroll
        for (int s = 0; s < 4; ++s) {
            af[s] = *(const f16x8*)&Als[(wm * 64 + s * 16 + c16) * 40 + quad * 8];
            bf[s] = *(const f16x8*)&Bls[(wn * 64 + s * 16 + c16) * 40 + quad * 8];
        }
#pragma unroll
        for (int ms = 0; ms < 4; ++ms)
#pragma unroll
            for (int ns = 0; ns < 4; ++ns)
                acc[ms][ns] = __builtin_amdgcn_mfma_f32_16x16x32_f16(af[ms], bf[ns],
                                                                     acc[ms][ns], 0, 0, 0);
        __syncthreads();
    }

    int b = row0 / rows_per_batch;
#pragma unroll
    for (int ns = 0; ns < 4; ++ns) {
        int col = col0 + wn * 64 + ns * 16 + c16;
        float bv = bias ? bias[col] : 0.f;
        float b2v = bias2d ? bias2d[(size_t)b * N + col] : 0.f;
        float mx = -3e38f;
#pragma unroll
        for (int ms = 0; ms < 4; ++ms) {
#pragma unroll
            for (int j = 0; j < 4; ++j) {
                float v = acc[ms][ns][j] + bv + b2v;
                if (bng) v = (v - bnm[col]) * rsqrtf(bnv[col] + 1e-5f) * bng[col] + bnb[col];
                if (relu) v = fmaxf(v, 0.f);
                if (Cout)
                    Cout[(size_t)(row0 + wm * 64 + ms * 16 + quad * 4 + j) * N + col] = (f16)v;
                mx = fmaxf(mx, v);
            }
        }
        if (maxkey) {
            mx = fmaxf(mx, __shfl_xor(mx, 16, 64));
            mx = fmaxf(mx, __shfl_xor(mx, 32, 64));
            if (quad == 0) atomicMax(&maxkey[(size_t)b * N + col], fkey(mx));
        }
    }
}

// ---------- skinny GEMM v2: wave per column, coalesced float4 ----------
__global__ void skinny_v2_kernel(const float* __restrict__ A, const float* __restrict__ W,
                                 int ldw, int woff, const float* __restrict__ bias,
                                 float* __restrict__ C, int K, int N, int relu) {
    int wave = threadIdx.x >> 6, lane = threadIdx.x & 63;
    int col = blockIdx.x * 4 + wave;
    if (col >= N) return;
    const float* w = W + (size_t)col * ldw + woff;
    float acc[16];
#pragma unroll
    for (int m = 0; m < 16; ++m) acc[m] = 0.f;
    for (int k0 = 0; k0 < K; k0 += 256) {
        f32x4 wv = *(const f32x4*)(w + k0 + lane * 4);
#pragma unroll
        for (int m = 0; m < 16; ++m) {
            f32x4 av = *(const f32x4*)(A + (size_t)m * K + k0 + lane * 4);
            acc[m] += av[0] * wv[0] + av[1] * wv[1] + av[2] * wv[2] + av[3] * wv[3];
        }
    }
#pragma unroll
    for (int m = 0; m < 16; ++m)
#pragma unroll
        for (int s = 1; s < 64; s <<= 1) acc[m] += __shfl_xor(acc[m], s, 64);
    if (lane == 0) {
        float bv = bias[col];
#pragma unroll
        for (int m = 0; m < 16; ++m) {
            float v = acc[m] + bv;
            if (relu) v = fmaxf(v, 0.f);
            C[(size_t)m * N + col] = v;
        }
    }
}

__global__ void decode_kernel(const unsigned* __restrict__ k, float* __restrict__ f, int n) {
    int t = blockIdx.x * blockDim.x + threadIdx.x;
    if (t < n) f[t] = fkey_inv(k[t]);
}

// ---------- chamfer v2: 8 lanes per A-point, j-strided, shfl-min ----------
__global__ void chamfer_min_kernel(const float* __restrict__ A, int na,
                                   const float* __restrict__ Bp, int nb,
                                   float* __restrict__ slot) {
    int t = blockIdx.x * 256 + threadIdx.x;
    int pt = t >> 3, sl = t & 7;
    float val = 0.f;
    if (pt < BSZ * na) {
        int b = pt / na;
        const float* a = A + (size_t)pt * 3;
        float ax = a[0], ay = a[1], az = a[2];
        float aa = ax * ax + ay * ay + az * az;
        const float* Bb = Bp + (size_t)b * nb * 3;
        float m = 3e38f;
        for (int j = sl; j < nb; j += 8) {
            float bx = Bb[j * 3 + 0], by = Bb[j * 3 + 1], bz = Bb[j * 3 + 2];
            float d = aa + bx * bx + by * by + bz * bz - 2.0f * (ax * bx + ay * by + az * bz);
            m = fminf(m, d);
        }
#pragma unroll
        for (int s = 1; s < 8; s <<= 1) m = fminf(m, __shfl_xor(m, s, 64));
        if (sl == 0) val = sqrtf(fmaxf(m, 1e-12f));
    }
    __shared__ float sdata[256];
    sdata[threadIdx.x] = val;
    __syncthreads();
    for (int s = 128; s > 0; s >>= 1) {
        if (threadIdx.x < s) sdata[threadIdx.x] += sdata[threadIdx.x + s];
        __syncthreads();
    }
    if (threadIdx.x == 0) atomicAdd(slot, sdata[0]);
}

// ---------- smooth-L1 latent loss sum ----------
__global__ void latent_kernel(const float* __restrict__ f1, const float* __restrict__ f2,
                              int n, float* __restrict__ slot) {
    int t = blockIdx.x * blockDim.x + threadIdx.x;
    float val = 0.f;
    if (t < n) {
        float d = f1[t] - f2[t];
        float ad = fabsf(d);
        val = (ad < 1.f) ? (0.5f * d * d) : (ad - 0.5f);
    }
    __shared__ float sdata[256];
    sdata[threadIdx.x] = val;
    __syncthreads();
    for (int s = 128; s > 0; s >>= 1) {
        if (threadIdx.x < s) sdata[threadIdx.x] += sdata[threadIdx.x + s];
        __syncthreads();
    }
    if (threadIdx.x == 0) atomicAdd(slot, sdata[0]);
}

// ---------- 3x3 symmetric smallest eigenvector (double, analytic) ----------
__device__ void smallest_evec(double cxx, double cxy, double cxz,
                              double cyy, double cyz, double czz, double ev[3]) {
    double p1 = cxy * cxy + cxz * cxz + cyz * cyz;
    double q = (cxx + cyy + czz) / 3.0;
    double p2 = (cxx - q) * (cxx - q) + (cyy - q) * (cyy - q) + (czz - q) * (czz - q) + 2.0 * p1;
    double lam = q;
    if (p2 > 0.0) {
        double p = sqrt(p2 / 6.0);
        double b00 = (cxx - q) / p, b11 = (cyy - q) / p, b22 = (czz - q) / p;
        double b01 = cxy / p, b02 = cxz / p, b12 = cyz / p;
        double detB = b00 * (b11 * b22 - b12 * b12) - b01 * (b01 * b22 - b12 * b02)
                    + b02 * (b01 * b12 - b11 * b02);
        double r = detB * 0.5;
        r = r < -1.0 ? -1.0 : (r > 1.0 ? 1.0 : r);
        double phi = acos(r) / 3.0;
        lam = q + 2.0 * p * cos(phi + 2.0943951023931953);
    }
    double r0x = cxx - lam, r0y = cxy, r0z = cxz;
    double r1x = cxy, r1y = cyy - lam, r1z = cyz;
    double r2x = cxz, r2y = cyz, r2z = czz - lam;
    double c0x = r0y * r1z - r0z * r1y, c0y = r0z * r1x - r0x * r1z, c0z = r0x * r1y - r0y * r1x;
    double c1x = r0y * r2z - r0z * r2y, c1y = r0z * r2x - r0x * r2z, c1z = r0x * r2y - r0y * r2x;
    double c2x = r1y * r2z - r1z * r2y, c2y = r1z * r2x - r1x * r2z, c2z = r1x * r2y - r1y * r2x;
    double n0 = c0x * c0x + c0y * c0y + c0z * c0z;
    double n1 = c1x * c1x + c1y * c1y + c1z * c1z;
    double n2 = c2x * c2x + c2y * c2y + c2z * c2z;
    double bx = c0x, by = c0y, bz = c0z, bn = n0;
    if (n1 > bn) { bx = c1x; by = c1y; bz = c1z; bn = n1; }
    if (n2 > bn) { bx = c2x; by = c2y; bz = c2z; bn = n2; }
    if (bn < 1e-280) { ev[0] = 1.0; ev[1] = 0.0; ev[2] = 0.0; return; }
    double inv = 1.0 / sqrt(bn);
    ev[0] = bx * inv; ev[1] = by * inv; ev[2] = bz * inv;
}

// ---------- normals ----------
__global__ void normals_kernel(const float* __restrict__ pred, const int* __restrict__ knn,
                               float* __restrict__ nrm) {
    int t = blockIdx.x * blockDim.x + threadIdx.x;
    if (t >= BSZ * NPTS) return;
    int b = t / NPTS, i = t % NPTS;
    const float* P = pred + (size_t)b * NPTS * 3;
    const int* id = knn + (size_t)t * 32;
    float px[32], py[32], pz[32];
    double sx = 0, sy = 0, sz = 0;
    for (int k = 0; k < 32; ++k) {
        int j = id[k];
        px[k] = P[j * 3 + 0]; py[k] = P[j * 3 + 1]; pz[k] = P[j * 3 + 2];
        sx += px[k]; sy += py[k]; sz += pz[k];
    }
    double mx = sx / 32.0, my = sy / 32.0, mz = sz / 32.0;
    double cxx = 0, cxy = 0, cxz = 0, cyy = 0, cyz = 0, czz = 0;
    for (int k = 0; k < 32; ++k) {
        double dx = px[k] - mx, dy = py[k] - my, dz = pz[k] - mz;
        cxx += dx * dx; cxy += dx * dy; cxz += dx * dz;
        cyy += dy * dy; cyz += dy * dz; czz += dz * dz;
    }
    cxx /= 32.0; cxy /= 32.0; cxz /= 32.0; cyy /= 32.0; cyz /= 32.0; czz /= 32.0;
    double ev[3];
    smallest_evec(cxx, cxy, cxz, cyy, cyz, czz, ev);
    float qx = P[i * 3 + 0], qy = P[i * 3 + 1], qz = P[i * 3 + 2];
    double proj = 0.0;
    for (int k = 0; k < 32; ++k)
        proj += (px[k] - qx) * ev[0] + (py[k] - qy) * ev[1] + (pz[k] - qz) * ev[2];
    double s = (proj >= 0.0) ? 1.0 : -1.0;
    nrm[(size_t)t * 3 + 0] = (float)(ev[0] * s);
    nrm[(size_t)t * 3 + 1] = (float)(ev[1] * s);
    nrm[(size_t)t * 3 + 2] = (float)(ev[2] * s);
}

// ---------- manifold loss: reads first 8 of the 32-NN list ----------
__global__ void manifold_kernel(const float* __restrict__ nrm, const int* __restrict__ knn,
                                int kstride, float* __restrict__ slot) {
    int t = blockIdx.x * blockDim.x + threadIdx.x;
    float val = 0.f;
    if (t < BSZ * NPTS) {
        int b = t / NPTS;
        const float* NB = nrm + (size_t)b * NPTS * 3;
        const int* id = knn + (size_t)t * kstride;
        int j0 = id[0];
        float ax = NB[j0 * 3 + 0], ay = NB[j0 * 3 + 1], az = NB[j0 * 3 + 2];
        float an = fmaxf(sqrtf(ax * ax + ay * ay + az * az), 1e-6f);
        float x[8]; float s = 0.f;
        for (int k = 0; k < 8; ++k) {
            int j = id[k];
            float bx = NB[j * 3 + 0], by = NB[j * 3 + 1], bz = NB[j * 3 + 2];
            float bn_ = fmaxf(sqrtf(bx * bx + by * by + bz * bz), 1e-6f);
            float c = (ax * bx + ay * by + az * bz) / (an * bn_);
            x[k] = 1.f - c; s += x[k];
        }
        float mean = s / 8.f;
        float var = 0.f;
        for (int k = 0; k < 8; ++k) { float d = x[k] - mean; var += d * d; }
        val = sqrtf(var / 7.f);
    }
    __shared__ float sdata[256];
    sdata[threadIdx.x] = val;
    __syncthreads();
    for (int s2 = 128; s2 > 0; s2 >>= 1) {
        if (threadIdx.x < s2) sdata[threadIdx.x] += sdata[threadIdx.x + s2];
        __syncthreads();
    }
    if (threadIdx.x == 0) atomicAdd(slot, sdata[0]);
}

__global__ void finalize_kernel(const float* __restrict__ acc, float* __restrict__ out) {
    float l_recon = 0.5f * (acc[0] / (16.f * 2048.f) + acc[1] / (16.f * 2432.f));
    float l_match = 0.5f * (acc[2] / (16.f * 1024.f) + acc[3] / (16.f * 1216.f));
    float l_latent = acc[4] / (16.f * 1024.f);
    float l_man = 0.1f * (acc[5] / (16.f * 2048.f));
    out[0] = l_recon + l_match + l_latent + l_man;
    out[1] = l_recon;
    out[2] = l_match;
    out[3] = l_latent;
    out[4] = l_man;
}

// ================= host =================
extern "C" void kernel_launch(void* const* d_in, const int* in_sizes, int n_in,
                              void* d_out, int out_size, void* d_ws, size_t ws_size,
                              hipStream_t stream) {
    (void)in_sizes; (void)n_in; (void)out_size; (void)ws_size;
    const float* pts = (const float*)d_in[0];
    const float* W1 = (const float*)d_in[1];
    const float* b1 = (const float*)d_in[2];
    const float* g1 = (const float*)d_in[3];
    const float* be1 = (const float*)d_in[4];
    const float* m1 = (const float*)d_in[5];
    const float* v1 = (const float*)d_in[6];
    const float* W2 = (const float*)d_in[7];
    const float* b2 = (const float*)d_in[8];
    const float* W3 = (const float*)d_in[9];
    const float* b3 = (const float*)d_in[10];
    const float* g2 = (const float*)d_in[11];
    const float* be2 = (const float*)d_in[12];
    const float* m2 = (const float*)d_in[13];
    const float* v2 = (const float*)d_in[14];
    const float* W4 = (const float*)d_in[15];
    const float* b4 = (const float*)d_in[16];
    const float* D1W = (const float*)d_in[17];
    const float* D1b = (const float*)d_in[18];
    const float* D2W = (const float*)d_in[19];
    const float* D2b = (const float*)d_in[20];
    const float* D3W = (const float*)d_in[21];
    const float* D3b = (const float*)d_in[22];
    const float* D4W = (const float*)d_in[23];
    const float* D4b = (const float*)d_in[24];

    char* ws = (char*)d_ws;
    size_t off = 0;
    auto alloc = [&](size_t bytes) -> void* {
        void* p = ws + off;
        off += (bytes + 255) & ~(size_t)255;
        return p;
    };
    float* center   = (float*)alloc((size_t)BSZ * NG * 3 * 4);
    int*   knnc     = (int*)  alloc((size_t)BSZ * NG * GS * 4);
    float* rebuild0 = (float*)alloc((size_t)BSZ * 2048 * 3 * 4);
    float* rebuild1 = (float*)alloc((size_t)BSZ * 1024 * 3 * 4);
    f16*   W2h      = (f16*)  alloc((size_t)256 * 128 * 2);
    f16*   W3h      = (f16*)  alloc((size_t)512 * 256 * 2);
    f16*   W4h      = (f16*)  alloc((size_t)1024 * 512 * 2);
    f16*   H1h      = (f16*)  alloc((size_t)BSZ * 2048 * 128 * 2);
    f16*   H2h      = (f16*)  alloc((size_t)BSZ * 2048 * 256 * 2);
    f16*   H3h      = (f16*)  alloc((size_t)BSZ * 2048 * 512 * 2);
    unsigned* gmaxkey = (unsigned*)alloc((size_t)BSZ * 256 * 4);
    float* gmaxb    = (float*)alloc((size_t)BSZ * 256 * 4);
    float* gpart    = (float*)alloc((size_t)BSZ * 512 * 4);
    unsigned* featkey = (unsigned*)alloc((size_t)BSZ * 1024 * 4);
    float* feat     = (float*)alloc((size_t)BSZ * 1024 * 4);
    float* featrec  = (float*)alloc((size_t)BSZ * 1024 * 4);
    float* dh1      = (float*)alloc((size_t)BSZ * 2048 * 4);
    float* dh2      = (float*)alloc((size_t)BSZ * 2048 * 4);
    float* dh3      = (float*)alloc((size_t)BSZ * 2048 * 4);
    float* pred     = (float*)alloc((size_t)BSZ * 6144 * 4);
    int*   idxa     = (int*)  alloc((size_t)BSZ * 64 * NBRK * 4);
    float* gatha    = (float*)alloc((size_t)BSZ * 64 * NBRK * 3 * 4);
    int*   idxb     = (int*)  alloc((size_t)BSZ * 32 * NBRK * 4);
    float* gathb    = (float*)alloc((size_t)BSZ * 32 * NBRK * 3 * 4);
    int*   idxc     = (int*)  alloc((size_t)BSZ * 32 * 32 * 4);
    float* gathc    = (float*)alloc((size_t)BSZ * 1024 * 3 * 4);
    int*   knn32    = (int*)  alloc((size_t)BSZ * 2048 * 32 * 4);
    float* nrmbuf   = (float*)alloc((size_t)BSZ * 2048 * 3 * 4);
    float* accum    = (float*)alloc(8 * 4);

    hipMemsetAsync(accum, 0, 8 * 4, stream);

    cvt_w_kernel<<<(256 * 128 + 255) / 256, 256, 0, stream>>>(W2, 128, 0, 128, W2h, 256 * 128);
    cvt_w_kernel<<<(512 * 256 + 255) / 256, 256, 0, stream>>>(W3, 512, 256, 256, W3h, 512 * 256);
    cvt_w_kernel<<<(1024 * 512 + 255) / 256, 256, 0, stream>>>(W4, 512, 0, 512, W4h, 1024 * 512);

    auto knn = [&](const float* Q, int q_bstride, int q_off, int nq,
                   const float* DB, int k, int* out) {
        int total = BSZ * nq;
        knn_kernel_v7<<<(total + 3) / 4, 256, 0, stream>>>(Q, q_bstride, q_off, nq,
                                                           DB, k, out, BSZ);
    };

    // FPS + grouping
    fps_kernel<<<BSZ, 256, 0, stream>>>(pts, center);
    knn(center, NG, 0, NG, pts, GS, knnc);
    gather_points_kernel<<<(BSZ * 2048 + 255) / 256, 256, 0, stream>>>(pts, NPTS, knnc, NG * GS,
                                                                       0, 2048, rebuild0, BSZ);
    gather_points_kernel<<<(BSZ * 1024 + 255) / 256, 256, 0, stream>>>(pts, NPTS, knnc, NG * GS,
                                                                       2048, 1024, rebuild1, BSZ);

    auto enc = [&](const float* X, int n, float* featout) {
        int M = BSZ * n;
        layer1_kernel<<<M / 16, 256, 0, stream>>>(X, W1, b1, g1, be1, m1, v1, H1h, M);
        hipMemsetAsync(gmaxkey, 0, (size_t)BSZ * 256 * 4, stream);
        mfma_gemm_kernel<<<dim3(256 / 128, M / 128), 256, 0, stream>>>(
            H1h, W2h, 128, 256, b2, nullptr, nullptr, nullptr, nullptr, nullptr,
            H2h, gmaxkey, n, 0);
        decode_kernel<<<(BSZ * 256 + 255) / 256, 256, 0, stream>>>(gmaxkey, gmaxb, BSZ * 256);
        skinny_v2_kernel<<<(512 + 3) / 4, 256, 0, stream>>>(gmaxb, W3, 512, 0, b3,
                                                            gpart, 256, 512, 0);
        mfma_gemm_kernel<<<dim3(512 / 128, M / 128), 256, 0, stream>>>(
            H2h, W3h, 256, 512, nullptr, gpart, g2, be2, m2, v2, H3h, nullptr, n, 1);
        hipMemsetAsync(featkey, 0, (size_t)BSZ * 1024 * 4, stream);
        mfma_gemm_kernel<<<dim3(1024 / 128, M / 128), 256, 0, stream>>>(
            H3h, W4h, 512, 1024, b4, nullptr, nullptr, nullptr, nullptr, nullptr,
            nullptr, featkey, n, 0);
        decode_kernel<<<(BSZ * 1024 + 255) / 256, 256, 0, stream>>>(featkey, featout, BSZ * 1024);
    };

    enc(rebuild0, 2048, feat);

    // decoder (skinny M=16, fp32, coalesced)
    skinny_v2_kernel<<<2048 / 4, 256, 0, stream>>>(feat, D1W, 1024, 0, D1b, dh1, 1024, 2048, 1);
    skinny_v2_kernel<<<2048 / 4, 256, 0, stream>>>(dh1, D2W, 2048, 0, D2b, dh2, 2048, 2048, 1);
    skinny_v2_kernel<<<2048 / 4, 256, 0, stream>>>(dh2, D3W, 2048, 0, D3b, dh3, 2048, 2048, 1);
    skinny_v2_kernel<<<6144 / 4, 256, 0, stream>>>(dh3, D4W, 2048, 0, D4b, pred, 2048, 6144, 0);

    // l_recon
    knn(center, NG, 0, 64, pred, NBRK, idxa);
    gather_points_kernel<<<(BSZ * 2432 + 255) / 256, 256, 0, stream>>>(pred, 2048, idxa, 64 * NBRK,
                                                                       0, 2432, gatha, BSZ);
    chamfer_min_kernel<<<(BSZ * 2048 * 8 + 255) / 256, 256, 0, stream>>>(rebuild0, 2048,
                                                                         gatha, 2432, accum + 0);
    chamfer_min_kernel<<<(BSZ * 2432 * 8 + 255) / 256, 256, 0, stream>>>(gatha, 2432,
                                                                         rebuild0, 2048, accum + 1);
    // l_match
    knn(center, NG, 64, 32, pred, NBRK, idxb);
    gather_points_kernel<<<(BSZ * 1216 + 255) / 256, 256, 0, stream>>>(pred, 2048, idxb, 32 * NBRK,
                                                                       0, 1216, gathb, BSZ);
    chamfer_min_kernel<<<(BSZ * 1024 * 8 + 255) / 256, 256, 0, stream>>>(rebuild1, 1024,
                                                                         gathb, 1216, accum + 2);
    chamfer_min_kernel<<<(BSZ * 1216 * 8 + 255) / 256, 256, 0, stream>>>(gathb, 1216,
                                                                         rebuild1, 1024, accum + 3);
    // l_latent
    knn(center, NG, 96, 32, pred, 32, idxc);
    gather_points_kernel<<<(BSZ * 1024 + 255) / 256, 256, 0, stream>>>(pred, 2048, idxc, 32 * 32,
                                                                       0, 1024, gathc, BSZ);
    enc(gathc, 1024, featrec);
    latent_kernel<<<(BSZ * 1024 + 255) / 256, 256, 0, stream>>>(feat, featrec, BSZ * 1024,
                                                                accum + 4);
    // l_man: one self-KNN (k=32); manifold uses first 8 (stable top-k prefix)
    knn(pred, 2048, 0, 2048, pred, 32, knn32);
    normals_kernel<<<(BSZ * 2048 + 255) / 256, 256, 0, stream>>>(pred, knn32, nrmbuf);
    manifold_kernel<<<(BSZ * 2048 + 255) / 256, 256, 0, stream>>>(nrmbuf, knn32, 32, accum + 5);

    finalize_kernel<<<1, 1, 0, stream>>>(accum, (float*)d_out);
}